// Round 1
// baseline (2147.545 us; speedup 1.0000x reference)
//
#include <hip/hip_runtime.h>
#include <cstdint>
#include <cstddef>

// ============================================================================
// CHMLearner forward, all-f32 implementation.
// Pipeline: resize(8/32) -> conv3x3(1024->256) x6 -> norms -> 9x corr GEMM
//  -> interpolate4d->16^4 (+relu) -> 6D conv (chm6d, fused sigmoid+max9)
//  -> interpolate4d->32^4 -> fast4d(5^4)+bias+softplus -> mutual_nn_filter.
// ============================================================================

#define DEVFN __device__ __forceinline__

constexpr size_t WSZ = 2359296;  // floats per transposed conv weight [1024][9][256]

// workspace layout (floats). Total = 21,121,536 floats = 84.5 MB
constexpr size_t OFF_WT    = 0;                       // 3*WSZ
constexpr size_t OFF_SRC8  = OFF_WT + 3*WSZ;          // 4*1024*8*8
constexpr size_t OFF_TRG8  = OFF_SRC8 + 262144;
constexpr size_t OFF_SRC32 = OFF_TRG8 + 262144;       // 4*1024*32*32
constexpr size_t OFF_TRG32 = OFF_SRC32 + 4194304;
constexpr size_t OFF_SF8   = OFF_TRG32 + 4194304;     // conv outputs [4][256][s][s]
constexpr size_t OFF_TF8   = OFF_SF8 + 65536;
constexpr size_t OFF_SF16  = OFF_TF8 + 65536;
constexpr size_t OFF_TF16  = OFF_SF16 + 262144;
constexpr size_t OFF_SF32  = OFF_TF16 + 262144;
constexpr size_t OFF_TF32  = OFF_SF32 + 1048576;
constexpr size_t OFF_INVS  = OFF_TF32 + 1048576;      // [scale][b][pos] 256+1024+4096
constexpr size_t OFF_INVT  = OFF_INVS + 5376;
constexpr size_t OFF_SMAX  = OFF_INVT + 5376;         // 4096
constexpr size_t OFF_TMAX  = OFF_SMAX + 4096;
constexpr size_t OFF_CORR6 = OFF_TMAX + 4096;         // [4][9][16][16][16][16]
constexpr size_t WS_FLOATS = OFF_CORR6 + 2359296;

// aliases into regions that are dead by the time they're used:
constexpr size_t OFF_MAXED = OFF_SRC8;                // [4][16^4] after chm6d
constexpr size_t OFF_INT32 = OFF_TRG32;               // [4][32^4] upsampled

// per-pair raw-correlation regions [4][ss^2][ts^2]; pairs 0..7 live in the
// dead WT region (3,030,016 <= 3*WSZ), pair 8 in dead src32 (exactly 4*1024*1024).
__device__ constexpr size_t PAIR_OFF[9] = {
  OFF_WT + 0,       OFF_WT + 16384,   OFF_WT + 81920,
  OFF_WT + 344064,  OFF_WT + 409600,  OFF_WT + 671744,
  OFF_WT + 1720320, OFF_WT + 1982464, OFF_SRC32 };
__device__ constexpr int SSARR[3] = {8, 16, 32};
__device__ constexpr int PAIR_START[9] = {0,4,20,84,100,164,420,484,740}; // 1764 total

// ---------------------------------------------------------------------------
// 1) transpose conv weights: WT[scale][ci][k][co] = w[co][ci][k]
__global__ void k_wtrans(const float* __restrict__ w0, const float* __restrict__ w1,
                         const float* __restrict__ w2, float* __restrict__ ws){
  size_t id = (size_t)blockIdx.x*256 + threadIdx.x;
  if (id >= 3*WSZ) return;
  int scale = (int)(id / WSZ); size_t r = id % WSZ;
  int co = (int)(r & 255); int kk = (int)((r >> 8) % 9); int ci = (int)((r >> 8) / 9);
  const float* w = (scale==0) ? w0 : (scale==1 ? w1 : w2);
  ws[OFF_WT + id] = w[((size_t)co*1024 + ci)*9 + kk];
}

// ---------------------------------------------------------------------------
// 2) bilinear align-corners resize 16->8 and 16->32 for both feature maps
__global__ void k_resize(const float* __restrict__ src, const float* __restrict__ trg,
                         float* __restrict__ ws){
  size_t id = (size_t)blockIdx.x*256 + threadIdx.x;
  const float* in; float* out; int Hout; size_t rem;
  if (id < 2u*262144) {
    Hout = 8;  in = (id < 262144) ? src : trg;
    out = ws + ((id < 262144) ? OFF_SRC8 : OFF_TRG8); rem = id % 262144;
  } else {
    size_t id2 = id - 2u*262144; if (id2 >= 2u*4194304) return;
    Hout = 32; in = (id2 < 4194304) ? src : trg;
    out = ws + ((id2 < 4194304) ? OFF_SRC32 : OFF_TRG32); rem = id2 % 4194304;
  }
  int hw = Hout*Hout;
  int n = (int)(rem / hw); int pr = (int)(rem % hw);
  int oy = pr / Hout, ox = pr % Hout;
  float cy = (float)(oy*15)/(float)(Hout-1), cx = (float)(ox*15)/(float)(Hout-1);
  int y0 = (int)cy; if (y0>15) y0=15; int y1 = (y0+1<16)?y0+1:15; float fy = cy - (float)y0;
  int x0 = (int)cx; if (x0>15) x0=15; int x1 = (x0+1<16)?x0+1:15; float fx = cx - (float)x0;
  const float* p = in + (size_t)n*256;
  float v = (1.f-fy)*((1.f-fx)*p[y0*16+x0] + fx*p[y0*16+x1])
          +       fy*((1.f-fx)*p[y1*16+x0] + fx*p[y1*16+x1]);
  out[rem] = v;
}

// ---------------------------------------------------------------------------
// 3) conv3x3 1024->256, same zero-pad. One launch, 168 heterogeneous blocks.
//    Block: 512 thr = 256 co x 2 row-halves; 8x8 position tile; LDS input tile.
__global__ __launch_bounds__(512) void k_conv(const float* __restrict__ src16,
                                              const float* __restrict__ trg16,
                                              float* __restrict__ ws){
  int bx = blockIdx.x;
  int S, tsr, b, tile, scale;
  if (bx < 128)      { S=32; scale=2; int r=bx;     tsr=r>>6; r&=63; b=r>>4; tile=r&15; }
  else if (bx < 160) { S=16; scale=1; int r=bx-128; tsr=r>>4; r&=15; b=r>>2; tile=r&3; }
  else               { S=8;  scale=0; int r=bx-160; tsr=r>>2; b=r&3; tile=0; }
  int tiles = S >> 3;
  int ty0 = (tile/tiles)*8, tx0 = (tile%tiles)*8;
  const float* inb; float* outb;
  if (scale==2)      { inb = ws + (tsr?OFF_TRG32:OFF_SRC32); outb = ws + (tsr?OFF_TF32:OFF_SF32); }
  else if (scale==1) { inb = tsr? trg16 : src16;             outb = ws + (tsr?OFF_TF16:OFF_SF16); }
  else               { inb = ws + (tsr?OFF_TRG8:OFF_SRC8);   outb = ws + (tsr?OFF_TF8:OFF_SF8); }
  const float* wt = ws + OFF_WT + (size_t)scale*WSZ;
  inb += (size_t)b*1024*S*S;

  const int t = threadIdx.x;
  const int co = t & 255;
  const int oybase = (t >> 8) << 2;     // 0 or 4 (wave-uniform)

  __shared__ __align__(16) float sIn[4][10][12];   // 4 ci-planes, zero-padded 10x10(+2 pad)
  float acc[32];
  #pragma unroll
  for (int i=0;i<32;i++) acc[i]=0.f;

  #pragma unroll 1
  for (int ci0=0; ci0<1024; ci0+=4){
    __syncthreads();
    if (t < 480) {
      int p = t/120, rem = t%120, iy = rem/12, ix = rem%12;
      int gy = ty0+iy-1, gx = tx0+ix-1;
      float v = 0.f;
      if (ix<10 && gy>=0 && gy<S && gx>=0 && gx<S)
        v = inb[(size_t)(ci0+p)*S*S + gy*S + gx];
      sIn[p][iy][ix] = v;
    }
    __syncthreads();
    #pragma unroll 1
    for (int p=0; p<4; p++){
      const float* wr = wt + (size_t)(ci0+p)*9*256 + co;
      float w[9];
      #pragma unroll
      for (int k=0;k<9;k++) w[k] = wr[(size_t)k*256];
      #pragma unroll
      for (int lr=0; lr<4; lr++){
        #pragma unroll
        for (int dy=0; dy<3; dy++){
          const int iy = oybase + lr + dy;      // padded input row
          const float* rp = &sIn[p][0][0] + iy*12;
          float4 r0 = *reinterpret_cast<const float4*>(rp);
          float4 r1 = *reinterpret_cast<const float4*>(rp+4);
          float4 r2 = *reinterpret_cast<const float4*>(rp+8);
          float r[12] = {r0.x,r0.y,r0.z,r0.w,r1.x,r1.y,r1.z,r1.w,r2.x,r2.y,r2.z,r2.w};
          #pragma unroll
          for (int dx=0; dx<3; dx++){
            const float wv = w[dy*3+dx];
            #pragma unroll
            for (int ox=0; ox<8; ox++)
              acc[lr*8+ox] = fmaf(r[ox+dx], wv, acc[lr*8+ox]);
          }
        }
      }
    }
  }
  float* ob = outb + ((size_t)b*256 + co)*S*S;
  #pragma unroll
  for (int lr=0; lr<4; lr++){
    int oy = ty0 + oybase + lr;
    #pragma unroll
    for (int ox=0; ox<8; ox++)
      ob[oy*S + tx0+ox] = acc[lr*8+ox];
  }
}

// ---------------------------------------------------------------------------
// 4) inverse feature norms per position: 1/||f[:,pos]||
__global__ void k_invnorm(float* __restrict__ ws){
  int id = blockIdx.x*256 + threadIdx.x;
  if (id >= 10752) return;
  int tsr = id / 5376, r = id % 5376;
  int P, q; size_t fbase;
  if (r < 256)     { P=64;   q=r;      fbase = tsr ? OFF_TF8  : OFF_SF8; }
  else if (r<1280) { P=256;  q=r-256;  fbase = tsr ? OFF_TF16 : OFF_SF16; }
  else             { P=1024; q=r-1280; fbase = tsr ? OFF_TF32 : OFF_SF32; }
  int b = q / P, pos = q % P;
  const float* f = ws + fbase + (size_t)b*256*P + pos;
  float s = 0.f;
  for (int ch=0; ch<256; ch++){ float v = f[(size_t)ch*P]; s = fmaf(v,v,s); }
  ws[(tsr ? OFF_INVT : OFF_INVS) + r] = 1.f/sqrtf(s);
}

// ---------------------------------------------------------------------------
// 5) all 9 normalized-correlation GEMMs in one launch. 64x64 tiles, K=256.
__global__ __launch_bounds__(256) void k_corr(float* __restrict__ ws){
  int bx = blockIdx.x;
  int p = (bx>=4)+(bx>=20)+(bx>=84)+(bx>=100)+(bx>=164)+(bx>=420)+(bx>=484)+(bx>=740);
  int si = p/3, ti = p%3;
  int M = SSARR[si]*SSARR[si], N = SSARR[ti]*SSARR[ti];
  int ntN = N >> 6;
  int rem = bx - PAIR_START[p];
  int b = rem & 3; rem >>= 2;
  int nt = rem % ntN, mt = rem / ntN;
  int m0 = mt*64, n0 = nt*64;
  const float* A  = ws + (si==0?OFF_SF8: si==1?OFF_SF16:OFF_SF32) + (size_t)b*256*M;
  const float* Bp = ws + (ti==0?OFF_TF8: ti==1?OFF_TF16:OFF_TF32) + (size_t)b*256*N;
  const float* iS = ws + OFF_INVS + (si==0?0: si==1?256:1280) + (size_t)b*M;
  const float* iT = ws + OFF_INVT + (ti==0?0: ti==1?256:1280) + (size_t)b*N;
  float* C = ws + PAIR_OFF[p] + (size_t)b*M*N;
  __shared__ __align__(16) float As[16][64];
  __shared__ __align__(16) float Bs[16][64];
  int t = threadIdx.x, tm = t>>4, tn = t&15;
  float acc[4][4] = {};
  #pragma unroll 1
  for (int k0=0; k0<256; k0+=16){
    __syncthreads();
    #pragma unroll
    for (int i=0;i<4;i++){
      int idx = t + i*256; int k = idx>>6, m = idx&63;
      As[k][m] = A [(size_t)(k0+k)*M + m0+m];
      Bs[k][m] = Bp[(size_t)(k0+k)*N + n0+m];
    }
    __syncthreads();
    #pragma unroll
    for (int k=0;k<16;k++){
      float4 av = *reinterpret_cast<const float4*>(&As[k][tm*4]);
      float4 bv = *reinterpret_cast<const float4*>(&Bs[k][tn*4]);
      float a4[4]={av.x,av.y,av.z,av.w}, b4[4]={bv.x,bv.y,bv.z,bv.w};
      #pragma unroll
      for (int i=0;i<4;i++)
        #pragma unroll
        for (int j=0;j<4;j++)
          acc[i][j] = fmaf(a4[i], b4[j], acc[i][j]);
    }
  }
  #pragma unroll
  for (int i=0;i<4;i++){
    float sv = iS[m0+tm*4+i];
    #pragma unroll
    for (int j=0;j<4;j++)
      C[(size_t)(m0+tm*4+i)*N + n0+tn*4+j] = acc[i][j]*sv*iT[n0+tn*4+j];
  }
}

// ---------------------------------------------------------------------------
DEVFN void cw_coord(int i, int n, int OH, int& i0, int& i1, float& f){
  float c = (float)(i*(n-1))/(float)(OH-1);
  int a = (int)c; if (a > n-1) a = n-1;
  i0 = a; i1 = (a+1 < n) ? a+1 : n-1; f = c - (float)a;
}

// 6) interpolate4d each pair's correlation to [16,16,16,16], + relu
__global__ void k_interp_pairs(float* __restrict__ ws){
  int bx = blockIdx.x;
  int p = bx >> 10;
  int local = ((bx & 1023) << 8) | threadIdx.x;     // 0..262143
  int si = p/3, ti = p%3;
  int h1 = SSARR[si], t1 = SSARR[ti];
  int px = local & 15, py = (local>>4)&15, ox = (local>>8)&15, oy = (local>>12)&15, b = local>>16;
  int y0,y1,x0,x1,u0,u1,v0,v1; float fy,fx,fu,fv;
  cw_coord(oy,h1,16,y0,y1,fy); cw_coord(ox,h1,16,x0,x1,fx);
  cw_coord(py,t1,16,u0,u1,fu); cw_coord(px,t1,16,v0,v1,fv);
  const float* in = ws + PAIR_OFF[p] + (size_t)b*h1*h1*t1*t1;
  int ys[2]={y0,y1}, xs[2]={x0,x1}, us[2]={u0,u1}, vs[2]={v0,v1};
  float wy[2]={1.f-fy,fy}, wx[2]={1.f-fx,fx}, wu[2]={1.f-fu,fu}, wv[2]={1.f-fv,fv};
  float s = 0.f;
  #pragma unroll
  for (int ia=0; ia<2; ia++)
    #pragma unroll
    for (int ic=0; ic<2; ic++){
      float wyx = wy[ia]*wx[ic];
      const float* base = in + ((size_t)ys[ia]*h1 + xs[ic])*t1*t1;
      #pragma unroll
      for (int id_=0; id_<2; id_++)
        #pragma unroll
        for (int ie=0; ie<2; ie++)
          s += wyx*wu[id_]*wv[ie]*base[(size_t)us[id_]*t1 + vs[ie]];
    }
  ws[OFF_CORR6 + ((size_t)b*9 + p)*65536 + (local & 65535)] = fmaxf(s, 0.f);
}

// ---------------------------------------------------------------------------
// 7) direct 6D conv (3,3,5,5,5,5) zero-pad + sigmoid + max over 9 scale pairs.
//    Block per (b, sy, sx); threads = (ty,tx); 9 accumulators.
__global__ __launch_bounds__(256) void k_chm6d(float* __restrict__ ws,
                                               const float* __restrict__ k6){
  const int b = blockIdx.y;
  const int sy = blockIdx.x >> 4, sx = blockIdx.x & 15;
  const int t = threadIdx.x, ty = t >> 4, tx = t & 15;
  __shared__ __align__(16) float sK[625*12];   // [tap(a,c,d,e)][kk padded to 12]
  __shared__ float sP[9][20][20];
  for (int i=t; i<5625; i+=256){ int kk=i/625, tap=i%625; sK[tap*12+kk]=k6[i]; }
  float acc[9];
  #pragma unroll
  for (int i=0;i<9;i++) acc[i]=0.f;
  const float* c6 = ws + OFF_CORR6 + (size_t)b*9*65536;
  #pragma unroll 1
  for (int a=0; a<5; a++){
    int Y = sy+a-2; if (Y<0 || Y>15) continue;
    #pragma unroll 1
    for (int c=0; c<5; c++){
      int X = sx+c-2; if (X<0 || X>15) continue;
      __syncthreads();
      for (int idx=t; idx<3600; idx+=256){
        int pr = idx/400, rem = idx%400, yy = rem/20, xx = rem%20;
        int qy = yy-2, qx = xx-2;
        float v = 0.f;
        if (qy>=0 && qy<16 && qx>=0 && qx<16)
          v = c6[(size_t)pr*65536 + (size_t)(Y*16+X)*256 + qy*16+qx];
        sP[pr][yy][xx] = v;
      }
      __syncthreads();
      int tapbase = a*125 + c*25;
      #pragma unroll 1
      for (int d=0; d<5; d++){
        #pragma unroll 1
        for (int e=0; e<5; e++){
          const float* wp = &sK[(tapbase + d*5 + e)*12];
          float w[9];
          #pragma unroll
          for (int kk=0;kk<9;kk++) w[kk] = wp[kk];
          #pragma unroll
          for (int pi=0; pi<3; pi++)
            #pragma unroll
            for (int pj=0; pj<3; pj++){
              float v = sP[pi*3+pj][ty+d][tx+e];
              #pragma unroll
              for (int ki=0; ki<3; ki++){
                int sio = pi-ki+1; if (sio<0 || sio>2) continue;
                #pragma unroll
                for (int kj=0; kj<3; kj++){
                  int sjo = pj-kj+1; if (sjo<0 || sjo>2) continue;
                  acc[sio*3+sjo] = fmaf(v, w[ki*3+kj], acc[sio*3+sjo]);
                }
              }
            }
        }
      }
    }
  }
  float m = acc[0];
  #pragma unroll
  for (int i=1;i<9;i++) m = fmaxf(m, acc[i]);
  float sig = 1.f/(1.f + expf(-m));   // max(sigmoid) == sigmoid(max)
  ws[OFF_MAXED + ((size_t)b*256 + blockIdx.x)*256 + t] = sig;
}

// ---------------------------------------------------------------------------
// 8) interpolate4d 16^4 -> 32^4
__global__ void k_interp32(float* __restrict__ ws){
  int id = blockIdx.x*256 + threadIdx.x;       // 4*32^4 exact
  int px = id & 31, py = (id>>5)&31, ox = (id>>10)&31, oy = (id>>15)&31, b = id>>20;
  int y0,y1,x0,x1,u0,u1,v0,v1; float fy,fx,fu,fv;
  cw_coord(oy,16,32,y0,y1,fy); cw_coord(ox,16,32,x0,x1,fx);
  cw_coord(py,16,32,u0,u1,fu); cw_coord(px,16,32,v0,v1,fv);
  const float* in = ws + OFF_MAXED + (size_t)b*65536;
  int ys[2]={y0,y1}, xs[2]={x0,x1}, us[2]={u0,u1}, vs[2]={v0,v1};
  float wy[2]={1.f-fy,fy}, wx[2]={1.f-fx,fx}, wu[2]={1.f-fu,fu}, wv[2]={1.f-fv,fv};
  float s = 0.f;
  #pragma unroll
  for (int ia=0; ia<2; ia++)
    #pragma unroll
    for (int ic=0; ic<2; ic++){
      float wyx = wy[ia]*wx[ic];
      const float* base = in + ((size_t)ys[ia]*16 + xs[ic])*256;
      #pragma unroll
      for (int id_=0; id_<2; id_++)
        #pragma unroll
        for (int ie=0; ie<2; ie++)
          s += wyx*wu[id_]*wv[ie]*base[(size_t)us[id_]*16 + vs[ie]];
    }
  ws[OFF_INT32 + id] = s;
}

// ---------------------------------------------------------------------------
// 9) fast4d: 4D conv 5^4 zero-pad + bias + softplus -> d_out [4][1024][1024]
__global__ __launch_bounds__(256) void k_fast4d(float* __restrict__ ws,
                                                const float* __restrict__ k4,
                                                const float* __restrict__ b4,
                                                float* __restrict__ out){
  const int b = blockIdx.y;
  const int sy = blockIdx.x >> 5, sx = blockIdx.x & 31;
  const int t = threadIdx.x;
  const int ty = t >> 3, tx0 = (t & 7) << 2;
  __shared__ float sK[625];
  __shared__ __align__(16) float sQ[36*36];
  for (int i=t; i<625; i+=256) sK[i] = k4[i];
  float acc[4] = {0.f,0.f,0.f,0.f};
  const float* in = ws + OFF_INT32 + (size_t)b*1048576;
  #pragma unroll 1
  for (int a=0; a<5; a++){
    int Y = sy+a-2; if (Y<0 || Y>31) continue;
    #pragma unroll 1
    for (int c=0; c<5; c++){
      int X = sx+c-2; if (X<0 || X>31) continue;
      __syncthreads();
      for (int idx=t; idx<1296; idx+=256){
        int yy = idx/36, xx = idx%36, qy = yy-2, qx = xx-2;
        float v = 0.f;
        if (qy>=0 && qy<32 && qx>=0 && qx<32)
          v = in[(size_t)(Y*32+X)*1024 + qy*32+qx];
        sQ[idx] = v;
      }
      __syncthreads();
      const float* kb = &sK[a*125 + c*25];
      #pragma unroll 1
      for (int d=0; d<5; d++){
        const float* row = &sQ[(ty+d)*36 + tx0];
        float4 q0 = *reinterpret_cast<const float4*>(row);
        float4 q1 = *reinterpret_cast<const float4*>(row+4);
        float r[8] = {q0.x,q0.y,q0.z,q0.w,q1.x,q1.y,q1.z,q1.w};
        #pragma unroll
        for (int e=0; e<5; e++){
          float wv = kb[d*5+e];
          #pragma unroll
          for (int i=0;i<4;i++) acc[i] = fmaf(r[i+e], wv, acc[i]);
        }
      }
    }
  }
  float bias = b4[0];
  #pragma unroll
  for (int i=0;i<4;i++){
    float x = acc[i] + bias;
    float sp = fmaxf(x,0.f) + log1pf(expf(-fabsf(x)));   // softplus
    out[((size_t)b*1024 + blockIdx.x)*1024 + ty*32 + tx0 + i] = sp;
  }
}

// ---------------------------------------------------------------------------
// 10-12) mutual_nn_filter
__global__ void k_rowmax(const float* __restrict__ cm, float* __restrict__ ws){
  int row = blockIdx.x;                          // b*1024 + s
  const float* r = cm + (size_t)row*1024;
  int t = threadIdx.x;
  float m = -1e30f;
  for (int i=t; i<1024; i+=256) m = fmaxf(m, r[i]);
  __shared__ float red[256];
  red[t] = m; __syncthreads();
  for (int off=128; off; off>>=1){
    if (t < off) red[t] = fmaxf(red[t], red[t+off]);
    __syncthreads();
  }
  if (!t) ws[OFF_SMAX + row] = red[0];
}

__global__ void k_colmax(const float* __restrict__ cm, float* __restrict__ ws){
  int id = blockIdx.x*256 + threadIdx.x;         // 4096
  int b = id >> 10, c = id & 1023;
  const float* base = cm + (size_t)b*1048576 + c;
  float m = -1e30f;
  for (int s=0; s<1024; s++) m = fmaxf(m, base[(size_t)s*1024]);
  ws[OFF_TMAX + id] = m;
}

__global__ void k_mutual(float* __restrict__ cm, const float* __restrict__ ws){
  int id = blockIdx.x*256 + threadIdx.x;         // 4,194,304
  int b = id >> 20, r = (id>>10)&1023, c = id&1023;
  float v  = cm[id];
  float sm = ws[OFF_SMAX + (b<<10) + r];
  float tm = ws[OFF_TMAX + (b<<10) + c];
  sm = (sm==0.f) ? 1e-30f : sm;
  tm = (tm==0.f) ? 1e-30f : tm;
  cm[id] = v * (v/sm) * (v/tm);
}

// ---------------------------------------------------------------------------
extern "C" void kernel_launch(void* const* d_in, const int* in_sizes, int n_in,
                              void* d_out, int out_size, void* d_ws, size_t ws_size,
                              hipStream_t stream){
  const float* src = (const float*)d_in[0];
  const float* trg = (const float*)d_in[1];
  const float* w0  = (const float*)d_in[2];
  const float* w1  = (const float*)d_in[3];
  const float* w2  = (const float*)d_in[4];
  const float* k6  = (const float*)d_in[5];
  const float* k4  = (const float*)d_in[6];
  const float* b4  = (const float*)d_in[7];
  float* ws  = (float*)d_ws;    // needs WS_FLOATS*4 = ~84.5 MB
  float* out = (float*)d_out;
  (void)in_sizes; (void)n_in; (void)out_size; (void)ws_size;

  k_wtrans      <<<27648, 256, 0, stream>>>(w0, w1, w2, ws);
  k_resize      <<<34816, 256, 0, stream>>>(src, trg, ws);
  k_conv        <<<168,   512, 0, stream>>>(src, trg, ws);
  k_invnorm     <<<42,    256, 0, stream>>>(ws);
  k_corr        <<<1764,  256, 0, stream>>>(ws);
  k_interp_pairs<<<9216,  256, 0, stream>>>(ws);
  k_chm6d       <<<dim3(256,4),  256, 0, stream>>>(ws, k6);
  k_interp32    <<<16384, 256, 0, stream>>>(ws);
  k_fast4d      <<<dim3(1024,4), 256, 0, stream>>>(ws, k4, b4, out);
  k_rowmax      <<<4096,  256, 0, stream>>>(out, ws);
  k_colmax      <<<16,    256, 0, stream>>>(out, ws);
  k_mutual      <<<16384, 256, 0, stream>>>(out, ws);
}

// Round 2
// 1341.941 us; speedup vs baseline: 1.6003x; 1.6003x over previous
//
#include <hip/hip_runtime.h>
#include <cstdint>
#include <cstddef>

// ============================================================================
// CHMLearner forward. Conv3x3 (1024->256) now bf16 MFMA implicit GEMM.
// Pipeline: pack W/in(bf16) -> conv MFMA x(3 scales x src/trg) -> norms ->
//  9x corr GEMM -> interp4d->16^4(+relu) -> chm6d(+sigmoid+max9) ->
//  interp4d->32^4 -> fast4d+bias+softplus -> mutual_nn_filter.
// ============================================================================

#define DEVFN __device__ __forceinline__

typedef __attribute__((ext_vector_type(8))) short short8v;
typedef __attribute__((ext_vector_type(4))) float f32x4;

// workspace layout (float units). Total 15,141,376 floats = 60.6 MB
constexpr size_t OFF_WB    = 0;           // bf16 packed weights, 3*2,359,296 bf16
constexpr size_t OFF_P8    = 3538944;     // bf16 padded ch-last features
constexpr size_t OFF_P16   = 3948544;
constexpr size_t OFF_P32   = 5275648;
constexpr size_t OFF_SF8   = 10010624;    // conv outputs f32 [b][256][S*S]
constexpr size_t OFF_TF8   = 10076160;
constexpr size_t OFF_SF16  = 10141696;
constexpr size_t OFF_TF16  = 10403840;
constexpr size_t OFF_SF32  = 10665984;
constexpr size_t OFF_TF32  = 11714560;
constexpr size_t OFF_INVS  = 12763136;
constexpr size_t OFF_INVT  = 12768512;
constexpr size_t OFF_SMAX  = 12773888;
constexpr size_t OFF_TMAX  = 12777984;
constexpr size_t OFF_CORR6 = 12782080;    // [4][9][16^4]
constexpr size_t WS_FLOATS = OFF_CORR6 + 2359296;

// aliases into [OFF_WB, OFF_WB+10,010,624) — dead after conv:
__device__ constexpr size_t PAIR_OFF[9] = {   // raw per-pair corr [4][ss^2][ts^2]
  OFF_WB + 0,       OFF_WB + 16384,   OFF_WB + 81920,
  OFF_WB + 344064,  OFF_WB + 409600,  OFF_WB + 671744,
  OFF_WB + 1720320, OFF_WB + 1982464, OFF_WB + 3031040 };
constexpr size_t OFF_MAXED = OFF_WB;              // [4][16^4] after chm6d
constexpr size_t OFF_INT32 = OFF_WB + 262144;     // [4][32^4] upsampled

__device__ constexpr int SSARR[3] = {8, 16, 32};
__device__ constexpr int PAIR_START[9] = {0,4,20,84,100,164,420,484,740}; // 1764

DEVFN unsigned short f2bf(float f){
  unsigned int u = __float_as_uint(f);
  return (unsigned short)((u + 0x7fffu + ((u >> 16) & 1u)) >> 16);
}

// ---------------------------------------------------------------------------
// 1) pack conv weights into MFMA A-fragment order (bf16):
//    Wb[scale][tap][kc][nc][lane][8] = w[co=nc*16+(l&15)][ci=kc*32+8*(l>>4)+i][tap]
__global__ void k_wpack(const float* __restrict__ w0, const float* __restrict__ w1,
                        const float* __restrict__ w2, float* __restrict__ wsf){
  int gid = blockIdx.x*256 + threadIdx.x;        // 884,736 exact
  int scale = gid / 294912, r = gid % 294912;
  int tap = r >> 15, kc = (r>>10)&31, nc = (r>>6)&15, l = r&63;
  const float* w = (scale==0) ? w0 : (scale==1 ? w1 : w2);
  int co = nc*16 + (l&15);
  int ci0 = kc*32 + ((l>>4)&3)*8;
  unsigned short* o = (unsigned short*)(wsf + OFF_WB) + (size_t)gid*8;
  #pragma unroll
  for (int i=0;i<8;i++)
    o[i] = f2bf(w[((size_t)co*1024 + ci0 + i)*9 + tap]);
}

// ---------------------------------------------------------------------------
// 2) resize(align-corners)+zero-pad+channels-last+bf16 for all 3 scales
__global__ void k_inpack(const float* __restrict__ src, const float* __restrict__ trg,
                         float* __restrict__ wsf){
  int tid = blockIdx.x*256 + threadIdx.x;        // 3,235,840 exact
  int scale, q;
  if (tid < 204800)      { scale=0; q=tid; }
  else if (tid < 868352) { scale=1; q=tid-204800; }
  else                   { scale=2; q=tid-868352; }
  int S = SSARR[scale], Sp = S+2, Sp2 = Sp*Sp;
  int ci4 = q & 255; q >>= 8;
  int pos = q % Sp2, bt = q / Sp2;
  int py = pos / Sp, px = pos % Sp;
  size_t poff = scale==0?OFF_P8: scale==1?OFF_P16:OFF_P32;
  unsigned short* o = (unsigned short*)(wsf + poff) + ((size_t)bt*Sp2 + pos)*1024 + ci4*4;
  if (py==0 || py==Sp-1 || px==0 || px==Sp-1){
    o[0]=0; o[1]=0; o[2]=0; o[3]=0; return;
  }
  int oy = py-1, ox = px-1;
  float cy = (float)(oy*15)/(float)(S-1), cx = (float)(ox*15)/(float)(S-1);
  int y0 = (int)cy; if (y0>15) y0=15; int y1 = (y0+1<16)?y0+1:15; float fy = cy-(float)y0;
  int x0 = (int)cx; if (x0>15) x0=15; int x1 = (x0+1<16)?x0+1:15; float fx = cx-(float)x0;
  const float* in = ((bt>=4)? trg : src) + ((size_t)(bt&3)*1024 + ci4*4)*256;
  #pragma unroll
  for (int i=0;i<4;i++){
    const float* p = in + (size_t)i*256;
    float v = (1.f-fy)*((1.f-fx)*p[y0*16+x0] + fx*p[y0*16+x1])
            +       fy*((1.f-fx)*p[y1*16+x0] + fx*p[y1*16+x1]);
    o[i] = f2bf(v);
  }
}

// ---------------------------------------------------------------------------
// 3) conv3x3 as bf16 MFMA implicit GEMM. D[m=co][n=pos], K=(tap,ci)=9216.
//    Block=4 waves (2co x 2pos), tile 64co x (NF*32)pos.
template<int NF>
DEVFN void conv_body(const unsigned short* __restrict__ Wb,
                     const unsigned short* __restrict__ P,
                     float* __restrict__ outp, int S, int lgS, int Sp, int N,
                     int co_base, int pos_base, int l){
  const int kl = ((l>>4)&3)*8;
  int yg[NF], xg[NF];
  #pragma unroll
  for (int g=0; g<NF; ++g){
    int pos = pos_base + g*16 + (l&15);
    yg[g] = pos >> lgS; xg[g] = pos & (S-1);
  }
  const unsigned short* wb0 = Wb + ((size_t)(co_base>>4)*64 + l)*8;
  f32x4 acc[2][NF];
  #pragma unroll
  for (int f=0; f<2; ++f)
    #pragma unroll
    for (int g=0; g<NF; ++g)
      acc[f][g] = (f32x4){0.f,0.f,0.f,0.f};
  #pragma unroll 1
  for (int tap=0; tap<9; ++tap){
    int dy = tap/3, dx = tap - dy*3;
    const unsigned short* pb[NF];
    #pragma unroll
    for (int g=0; g<NF; ++g)
      pb[g] = P + (size_t)((yg[g]+dy)*Sp + xg[g]+dx)*1024 + kl;
    const unsigned short* wt = wb0 + (size_t)tap*262144;
    #pragma unroll 4
    for (int kc=0; kc<32; ++kc){
      short8v a0 = *reinterpret_cast<const short8v*>(wt + (size_t)kc*8192);
      short8v a1 = *reinterpret_cast<const short8v*>(wt + (size_t)kc*8192 + 512);
      short8v bv[NF];
      #pragma unroll
      for (int g=0; g<NF; ++g)
        bv[g] = *reinterpret_cast<const short8v*>(pb[g] + kc*32);
      #pragma unroll
      for (int g=0; g<NF; ++g){
        acc[0][g] = __builtin_amdgcn_mfma_f32_16x16x32_bf16(a0, bv[g], acc[0][g], 0,0,0);
        acc[1][g] = __builtin_amdgcn_mfma_f32_16x16x32_bf16(a1, bv[g], acc[1][g], 0,0,0);
      }
    }
  }
  const int r0 = ((l>>4)&3)*4;
  #pragma unroll
  for (int f=0; f<2; ++f){
    int co = co_base + f*16 + r0;
    #pragma unroll
    for (int g=0; g<NF; ++g){
      int pp = pos_base + g*16 + (l&15);
      float* op = outp + (size_t)co*N + pp;
      #pragma unroll
      for (int i=0;i<4;i++) op[(size_t)i*N] = acc[f][g][i];
    }
  }
}

__global__ __launch_bounds__(256) void k_conv_mfma(float* __restrict__ wsf){
  int bx = blockIdx.x;
  int t = threadIdx.x, l = t&63, w = t>>6, wm = w&1, wn = w>>1;
  int scale, bt, cot, post, S, lgS, nf;
  if (bx < 256)      { scale=2; S=32; lgS=5; nf=4; bt=bx>>5; cot=(bx>>3)&3; post=bx&7; }
  else if (bx < 320) { int r=bx-256; scale=1; S=16; lgS=4; nf=4; bt=r>>3; cot=(r>>1)&3; post=r&1; }
  else               { int r=bx-320; scale=0; S=8;  lgS=3; nf=2; bt=r>>2; cot=r&3; post=0; }
  int Sp = S+2, N = S*S;
  const unsigned short* Wb = (const unsigned short*)(wsf + OFF_WB) + (size_t)scale*2359296;
  size_t poff = scale==0?OFF_P8: scale==1?OFF_P16:OFF_P32;
  const unsigned short* P = (const unsigned short*)(wsf + poff) + (size_t)bt*Sp*Sp*1024;
  size_t obase = (scale==2) ? (bt>=4?OFF_TF32:OFF_SF32)
               : (scale==1) ? (bt>=4?OFF_TF16:OFF_SF16)
                            : (bt>=4?OFF_TF8 :OFF_SF8);
  float* outp = wsf + obase + (size_t)(bt&3)*256*N;
  int co_base = cot*64 + wm*32;
  int pos_base = post*(nf*32) + wn*(nf*16);
  if (nf==4) conv_body<4>(Wb, P, outp, S, lgS, Sp, N, co_base, pos_base, l);
  else       conv_body<2>(Wb, P, outp, S, lgS, Sp, N, co_base, pos_base, l);
}

// ---------------------------------------------------------------------------
// 4) inverse feature norms per position
__global__ void k_invnorm(float* __restrict__ ws){
  int id = blockIdx.x*256 + threadIdx.x;
  if (id >= 10752) return;
  int tsr = id / 5376, r = id % 5376;
  int P, q; size_t fbase;
  if (r < 256)     { P=64;   q=r;      fbase = tsr ? OFF_TF8  : OFF_SF8; }
  else if (r<1280) { P=256;  q=r-256;  fbase = tsr ? OFF_TF16 : OFF_SF16; }
  else             { P=1024; q=r-1280; fbase = tsr ? OFF_TF32 : OFF_SF32; }
  int b = q / P, pos = q % P;
  const float* f = ws + fbase + (size_t)b*256*P + pos;
  float s = 0.f;
  for (int ch=0; ch<256; ch++){ float v = f[(size_t)ch*P]; s = fmaf(v,v,s); }
  ws[(tsr ? OFF_INVT : OFF_INVS) + r] = 1.f/sqrtf(s);
}

// ---------------------------------------------------------------------------
// 5) all 9 normalized-correlation GEMMs (f32), 64x64 tiles, K=256
__global__ __launch_bounds__(256) void k_corr(float* __restrict__ ws){
  int bx = blockIdx.x;
  int p = (bx>=4)+(bx>=20)+(bx>=84)+(bx>=100)+(bx>=164)+(bx>=420)+(bx>=484)+(bx>=740);
  int si = p/3, ti = p%3;
  int M = SSARR[si]*SSARR[si], N = SSARR[ti]*SSARR[ti];
  int ntN = N >> 6;
  int rem = bx - PAIR_START[p];
  int b = rem & 3; rem >>= 2;
  int nt = rem % ntN, mt = rem / ntN;
  int m0 = mt*64, n0 = nt*64;
  const float* A  = ws + (si==0?OFF_SF8: si==1?OFF_SF16:OFF_SF32) + (size_t)b*256*M;
  const float* Bp = ws + (ti==0?OFF_TF8: ti==1?OFF_TF16:OFF_TF32) + (size_t)b*256*N;
  const float* iS = ws + OFF_INVS + (si==0?0: si==1?256:1280) + (size_t)b*M;
  const float* iT = ws + OFF_INVT + (ti==0?0: ti==1?256:1280) + (size_t)b*N;
  float* C = ws + PAIR_OFF[p] + (size_t)b*M*N;
  __shared__ __align__(16) float As[16][64];
  __shared__ __align__(16) float Bs[16][64];
  int t = threadIdx.x, tm = t>>4, tn = t&15;
  float acc[4][4] = {};
  #pragma unroll 1
  for (int k0=0; k0<256; k0+=16){
    __syncthreads();
    #pragma unroll
    for (int i=0;i<4;i++){
      int idx = t + i*256; int k = idx>>6, m = idx&63;
      As[k][m] = A [(size_t)(k0+k)*M + m0+m];
      Bs[k][m] = Bp[(size_t)(k0+k)*N + n0+m];
    }
    __syncthreads();
    #pragma unroll
    for (int k=0;k<16;k++){
      float4 av = *reinterpret_cast<const float4*>(&As[k][tm*4]);
      float4 bv = *reinterpret_cast<const float4*>(&Bs[k][tn*4]);
      float a4[4]={av.x,av.y,av.z,av.w}, b4[4]={bv.x,bv.y,bv.z,bv.w};
      #pragma unroll
      for (int i=0;i<4;i++)
        #pragma unroll
        for (int j=0;j<4;j++)
          acc[i][j] = fmaf(a4[i], b4[j], acc[i][j]);
    }
  }
  #pragma unroll
  for (int i=0;i<4;i++){
    float sv = iS[m0+tm*4+i];
    #pragma unroll
    for (int j=0;j<4;j++)
      C[(size_t)(m0+tm*4+i)*N + n0+tn*4+j] = acc[i][j]*sv*iT[n0+tn*4+j];
  }
}

// ---------------------------------------------------------------------------
DEVFN void cw_coord(int i, int n, int OH, int& i0, int& i1, float& f){
  float c = (float)(i*(n-1))/(float)(OH-1);
  int a = (int)c; if (a > n-1) a = n-1;
  i0 = a; i1 = (a+1 < n) ? a+1 : n-1; f = c - (float)a;
}

// 6) interpolate4d each pair to [16,16,16,16], + relu
__global__ void k_interp_pairs(float* __restrict__ ws){
  int bx = blockIdx.x;
  int p = bx >> 10;
  int local = ((bx & 1023) << 8) | threadIdx.x;
  int si = p/3, ti = p%3;
  int h1 = SSARR[si], t1 = SSARR[ti];
  int px = local & 15, py = (local>>4)&15, ox = (local>>8)&15, oy = (local>>12)&15, b = local>>16;
  int y0,y1,x0,x1,u0,u1,v0,v1; float fy,fx,fu,fv;
  cw_coord(oy,h1,16,y0,y1,fy); cw_coord(ox,h1,16,x0,x1,fx);
  cw_coord(py,t1,16,u0,u1,fu); cw_coord(px,t1,16,v0,v1,fv);
  const float* in = ws + PAIR_OFF[p] + (size_t)b*h1*h1*t1*t1;
  int ys[2]={y0,y1}, xs[2]={x0,x1}, us[2]={u0,u1}, vs[2]={v0,v1};
  float wy[2]={1.f-fy,fy}, wx[2]={1.f-fx,fx}, wu[2]={1.f-fu,fu}, wv[2]={1.f-fv,fv};
  float s = 0.f;
  #pragma unroll
  for (int ia=0; ia<2; ia++)
    #pragma unroll
    for (int ic=0; ic<2; ic++){
      float wyx = wy[ia]*wx[ic];
      const float* base = in + ((size_t)ys[ia]*h1 + xs[ic])*t1*t1;
      #pragma unroll
      for (int id_=0; id_<2; id_++)
        #pragma unroll
        for (int ie=0; ie<2; ie++)
          s += wyx*wu[id_]*wv[ie]*base[(size_t)us[id_]*t1 + vs[ie]];
    }
  ws[OFF_CORR6 + ((size_t)b*9 + p)*65536 + (local & 65535)] = fmaxf(s, 0.f);
}

// ---------------------------------------------------------------------------
// 7) direct 6D conv (3,3,5,5,5,5) + sigmoid + max over 9 pairs
__global__ __launch_bounds__(256) void k_chm6d(float* __restrict__ ws,
                                               const float* __restrict__ k6){
  const int b = blockIdx.y;
  const int sy = blockIdx.x >> 4, sx = blockIdx.x & 15;
  const int t = threadIdx.x, ty = t >> 4, tx = t & 15;
  __shared__ float sK[5625];                 // [tap(a,c,d,e)][kk] — uniform reads
  __shared__ float sP[9][20][20];
  for (int i=t; i<5625; i+=256) sK[i] = k6[(i%9)*625 + (i/9)];
  float acc[9];
  #pragma unroll
  for (int i=0;i<9;i++) acc[i]=0.f;
  const float* c6 = ws + OFF_CORR6 + (size_t)b*9*65536;
  #pragma unroll 1
  for (int a=0; a<5; a++){
    int Y = sy+a-2; if (Y<0 || Y>15) continue;
    #pragma unroll 1
    for (int c=0; c<5; c++){
      int X = sx+c-2; if (X<0 || X>15) continue;
      __syncthreads();
      for (int idx=t; idx<3600; idx+=256){
        int pr = idx/400, rem = idx%400, yy = rem/20, xx = rem%20;
        int qy = yy-2, qx = xx-2;
        float v = 0.f;
        if (qy>=0 && qy<16 && qx>=0 && qx<16)
          v = c6[(size_t)pr*65536 + (size_t)(Y*16+X)*256 + qy*16+qx];
        sP[pr][yy][xx] = v;
      }
      __syncthreads();
      int tapbase = a*125 + c*25;
      #pragma unroll 1
      for (int d=0; d<5; d++){
        #pragma unroll 1
        for (int e=0; e<5; e++){
          const float* wp = &sK[(tapbase + d*5 + e)*9];
          float w[9];
          #pragma unroll
          for (int kk=0;kk<9;kk++) w[kk] = wp[kk];
          #pragma unroll
          for (int pi=0; pi<3; pi++)
            #pragma unroll
            for (int pj=0; pj<3; pj++){
              float v = sP[pi*3+pj][ty+d][tx+e];
              #pragma unroll
              for (int ki=0; ki<3; ki++){
                int sio = pi-ki+1; if (sio<0 || sio>2) continue;
                #pragma unroll
                for (int kj=0; kj<3; kj++){
                  int sjo = pj-kj+1; if (sjo<0 || sjo>2) continue;
                  acc[sio*3+sjo] = fmaf(v, w[ki*3+kj], acc[sio*3+sjo]);
                }
              }
            }
        }
      }
    }
  }
  float m = acc[0];
  #pragma unroll
  for (int i=1;i<9;i++) m = fmaxf(m, acc[i]);
  float sig = 1.f/(1.f + expf(-m));
  ws[OFF_MAXED + ((size_t)b*256 + blockIdx.x)*256 + t] = sig;
}

// ---------------------------------------------------------------------------
// 8) interpolate4d 16^4 -> 32^4
__global__ void k_interp32(float* __restrict__ ws){
  int id = blockIdx.x*256 + threadIdx.x;
  int px = id & 31, py = (id>>5)&31, ox = (id>>10)&31, oy = (id>>15)&31, b = id>>20;
  int y0,y1,x0,x1,u0,u1,v0,v1; float fy,fx,fu,fv;
  cw_coord(oy,16,32,y0,y1,fy); cw_coord(ox,16,32,x0,x1,fx);
  cw_coord(py,16,32,u0,u1,fu); cw_coord(px,16,32,v0,v1,fv);
  const float* in = ws + OFF_MAXED + (size_t)b*65536;
  int ys[2]={y0,y1}, xs[2]={x0,x1}, us[2]={u0,u1}, vs[2]={v0,v1};
  float wy[2]={1.f-fy,fy}, wx[2]={1.f-fx,fx}, wu[2]={1.f-fu,fu}, wv[2]={1.f-fv,fv};
  float s = 0.f;
  #pragma unroll
  for (int ia=0; ia<2; ia++)
    #pragma unroll
    for (int ic=0; ic<2; ic++){
      float wyx = wy[ia]*wx[ic];
      const float* base = in + ((size_t)ys[ia]*16 + xs[ic])*256;
      #pragma unroll
      for (int id_=0; id_<2; id_++)
        #pragma unroll
        for (int ie=0; ie<2; ie++)
          s += wyx*wu[id_]*wv[ie]*base[(size_t)us[id_]*16 + vs[ie]];
    }
  ws[OFF_INT32 + id] = s;
}

// ---------------------------------------------------------------------------
// 9) fast4d 5^4 + bias + softplus -> d_out [4][1024][1024]
__global__ __launch_bounds__(256) void k_fast4d(float* __restrict__ ws,
                                                const float* __restrict__ k4,
                                                const float* __restrict__ b4,
                                                float* __restrict__ out){
  const int b = blockIdx.y;
  const int sy = blockIdx.x >> 5, sx = blockIdx.x & 31;
  const int t = threadIdx.x;
  const int ty = t >> 3, tx0 = (t & 7) << 2;
  __shared__ float sK[625];
  __shared__ __align__(16) float sQ[36*36];
  for (int i=t; i<625; i+=256) sK[i] = k4[i];
  float acc[4] = {0.f,0.f,0.f,0.f};
  const float* in = ws + OFF_INT32 + (size_t)b*1048576;
  #pragma unroll 1
  for (int a=0; a<5; a++){
    int Y = sy+a-2; if (Y<0 || Y>31) continue;
    #pragma unroll 1
    for (int c=0; c<5; c++){
      int X = sx+c-2; if (X<0 || X>31) continue;
      __syncthreads();
      for (int idx=t; idx<1296; idx+=256){
        int yy = idx/36, xx = idx%36, qy = yy-2, qx = xx-2;
        float v = 0.f;
        if (qy>=0 && qy<32 && qx>=0 && qx<32)
          v = in[(size_t)(Y*32+X)*1024 + qy*32+qx];
        sQ[idx] = v;
      }
      __syncthreads();
      const float* kb = &sK[a*125 + c*25];
      #pragma unroll 1
      for (int d=0; d<5; d++){
        const float* row = &sQ[(ty+d)*36 + tx0];
        float4 q0 = *reinterpret_cast<const float4*>(row);
        float4 q1 = *reinterpret_cast<const float4*>(row+4);
        float r[8] = {q0.x,q0.y,q0.z,q0.w,q1.x,q1.y,q1.z,q1.w};
        #pragma unroll
        for (int e=0; e<5; e++){
          float wv = kb[d*5+e];
          #pragma unroll
          for (int i=0;i<4;i++) acc[i] = fmaf(r[i+e], wv, acc[i]);
        }
      }
    }
  }
  float bias = b4[0];
  #pragma unroll
  for (int i=0;i<4;i++){
    float x = acc[i] + bias;
    float sp = fmaxf(x,0.f) + log1pf(expf(-fabsf(x)));
    out[((size_t)b*1024 + blockIdx.x)*1024 + ty*32 + tx0 + i] = sp;
  }
}

// ---------------------------------------------------------------------------
// 10-12) mutual_nn_filter
__global__ void k_rowmax(const float* __restrict__ cm, float* __restrict__ ws){
  int row = blockIdx.x;
  const float* r = cm + (size_t)row*1024;
  int t = threadIdx.x;
  float m = -1e30f;
  for (int i=t; i<1024; i+=256) m = fmaxf(m, r[i]);
  __shared__ float red[256];
  red[t] = m; __syncthreads();
  for (int off=128; off; off>>=1){
    if (t < off) red[t] = fmaxf(red[t], red[t+off]);
    __syncthreads();
  }
  if (!t) ws[OFF_SMAX + row] = red[0];
}

__global__ void k_colmax(const float* __restrict__ cm, float* __restrict__ ws){
  int id = blockIdx.x*256 + threadIdx.x;
  int b = id >> 10, c = id & 1023;
  const float* base = cm + (size_t)b*1048576 + c;
  float m = -1e30f;
  for (int s=0; s<1024; s++) m = fmaxf(m, base[(size_t)s*1024]);
  ws[OFF_TMAX + id] = m;
}

__global__ void k_mutual(float* __restrict__ cm, const float* __restrict__ ws){
  int id = blockIdx.x*256 + threadIdx.x;
  int b = id >> 20, r = (id>>10)&1023, c = id&1023;
  float v  = cm[id];
  float sm = ws[OFF_SMAX + (b<<10) + r];
  float tm = ws[OFF_TMAX + (b<<10) + c];
  sm = (sm==0.f) ? 1e-30f : sm;
  tm = (tm==0.f) ? 1e-30f : tm;
  cm[id] = v * (v/sm) * (v/tm);
}

// ---------------------------------------------------------------------------
extern "C" void kernel_launch(void* const* d_in, const int* in_sizes, int n_in,
                              void* d_out, int out_size, void* d_ws, size_t ws_size,
                              hipStream_t stream){
  const float* src = (const float*)d_in[0];
  const float* trg = (const float*)d_in[1];
  const float* w0  = (const float*)d_in[2];
  const float* w1  = (const float*)d_in[3];
  const float* w2  = (const float*)d_in[4];
  const float* k6  = (const float*)d_in[5];
  const float* k4  = (const float*)d_in[6];
  const float* b4  = (const float*)d_in[7];
  float* ws  = (float*)d_ws;    // needs WS_FLOATS*4 = 60.6 MB
  float* out = (float*)d_out;
  (void)in_sizes; (void)n_in; (void)out_size; (void)ws_size;

  k_wpack       <<<3456,  256, 0, stream>>>(w0, w1, w2, ws);
  k_inpack      <<<12640, 256, 0, stream>>>(src, trg, ws);
  k_conv_mfma   <<<352,   256, 0, stream>>>(ws);
  k_invnorm     <<<42,    256, 0, stream>>>(ws);
  k_corr        <<<1764,  256, 0, stream>>>(ws);
  k_interp_pairs<<<9216,  256, 0, stream>>>(ws);
  k_chm6d       <<<dim3(256,4),  256, 0, stream>>>(ws, k6);
  k_interp32    <<<16384, 256, 0, stream>>>(ws);
  k_fast4d      <<<dim3(1024,4), 256, 0, stream>>>(ws, k4, b4, out);
  k_rowmax      <<<4096,  256, 0, stream>>>(out, ws);
  k_colmax      <<<16,    256, 0, stream>>>(out, ws);
  k_mutual      <<<16384, 256, 0, stream>>>(out, ws);
}

// Round 3
// 1195.358 us; speedup vs baseline: 1.7966x; 1.1226x over previous
//
#include <hip/hip_runtime.h>
#include <cstdint>
#include <cstddef>

// ============================================================================
// CHMLearner forward. Conv3x3 (1024->256) bf16 MFMA implicit GEMM.
// R3: chm6d restructured (padded LDS stride 24, scalar weights from global,
//     register column reuse), coalesced colmax, conv grid split 352->608.
// ============================================================================

#define DEVFN __device__ __forceinline__

typedef __attribute__((ext_vector_type(8))) short short8v;
typedef __attribute__((ext_vector_type(4))) float f32x4;

// workspace layout (float units). Total 15,179,776 floats = 60.7 MB
constexpr size_t OFF_WB    = 0;           // bf16 packed weights, 3*2,359,296 bf16
constexpr size_t OFF_P8    = 3538944;     // bf16 padded ch-last features
constexpr size_t OFF_P16   = 3948544;
constexpr size_t OFF_P32   = 5275648;
constexpr size_t OFF_SF8   = 10010624;    // conv outputs f32 [b][256][S*S]
constexpr size_t OFF_TF8   = 10076160;
constexpr size_t OFF_SF16  = 10141696;
constexpr size_t OFF_TF16  = 10403840;
constexpr size_t OFF_SF32  = 10665984;
constexpr size_t OFF_TF32  = 11714560;
constexpr size_t OFF_INVS  = 12763136;
constexpr size_t OFF_INVT  = 12768512;
constexpr size_t OFF_SMAX  = 12773888;
constexpr size_t OFF_TMAX  = 12777984;
constexpr size_t OFF_CORR6 = 12782080;    // [4][9][16^4]
constexpr size_t OFF_K6R   = OFF_CORR6 + 2359296;   // 5625 repacked 6d weights
constexpr size_t OFF_CMAXP = OFF_K6R + 5632;        // 32768 colmax partials
constexpr size_t WS_FLOATS = OFF_CMAXP + 32768;

// aliases into [OFF_WB, OFF_WB+10,010,624) — dead after conv:
__device__ constexpr size_t PAIR_OFF[9] = {   // raw per-pair corr [4][ss^2][ts^2]
  OFF_WB + 0,       OFF_WB + 16384,   OFF_WB + 81920,
  OFF_WB + 344064,  OFF_WB + 409600,  OFF_WB + 671744,
  OFF_WB + 1720320, OFF_WB + 1982464, OFF_WB + 3031040 };
constexpr size_t OFF_MAXED = OFF_WB;              // [4][16^4] after chm6d
constexpr size_t OFF_INT32 = OFF_WB + 262144;     // [4][32^4] upsampled

__device__ constexpr int SSARR[3] = {8, 16, 32};
__device__ constexpr int PAIR_START[9] = {0,4,20,84,100,164,420,484,740}; // 1764

DEVFN unsigned short f2bf(float f){
  unsigned int u = __float_as_uint(f);
  return (unsigned short)((u + 0x7fffu + ((u >> 16) & 1u)) >> 16);
}

// ---------------------------------------------------------------------------
// 1) pack conv weights into MFMA A-fragment order (bf16)
__global__ void k_wpack(const float* __restrict__ w0, const float* __restrict__ w1,
                        const float* __restrict__ w2, float* __restrict__ wsf){
  int gid = blockIdx.x*256 + threadIdx.x;        // 884,736 exact
  int scale = gid / 294912, r = gid % 294912;
  int tap = r >> 15, kc = (r>>10)&31, nc = (r>>6)&15, l = r&63;
  const float* w = (scale==0) ? w0 : (scale==1 ? w1 : w2);
  int co = nc*16 + (l&15);
  int ci0 = kc*32 + ((l>>4)&3)*8;
  unsigned short* o = (unsigned short*)(wsf + OFF_WB) + (size_t)gid*8;
  #pragma unroll
  for (int i=0;i<8;i++)
    o[i] = f2bf(w[((size_t)co*1024 + ci0 + i)*9 + tap]);
}

// 1b) repack chm6d kernel: K6R[tap(a,c,d,e)][ki*3+kj]
__global__ void k_k6pack(const float* __restrict__ k6, float* __restrict__ ws){
  int i = blockIdx.x*256 + threadIdx.x;
  if (i >= 5625) return;
  ws[OFF_K6R + i] = k6[(i%9)*625 + (i/9)];
}

// ---------------------------------------------------------------------------
// 2) resize(align-corners)+zero-pad+channels-last+bf16 for all 3 scales
__global__ void k_inpack(const float* __restrict__ src, const float* __restrict__ trg,
                         float* __restrict__ wsf){
  int tid = blockIdx.x*256 + threadIdx.x;        // 3,235,840 exact
  int scale, q;
  if (tid < 204800)      { scale=0; q=tid; }
  else if (tid < 868352) { scale=1; q=tid-204800; }
  else                   { scale=2; q=tid-868352; }
  int S = SSARR[scale], Sp = S+2, Sp2 = Sp*Sp;
  int ci4 = q & 255; q >>= 8;
  int pos = q % Sp2, bt = q / Sp2;
  int py = pos / Sp, px = pos % Sp;
  size_t poff = scale==0?OFF_P8: scale==1?OFF_P16:OFF_P32;
  unsigned short* o = (unsigned short*)(wsf + poff) + ((size_t)bt*Sp2 + pos)*1024 + ci4*4;
  if (py==0 || py==Sp-1 || px==0 || px==Sp-1){
    o[0]=0; o[1]=0; o[2]=0; o[3]=0; return;
  }
  int oy = py-1, ox = px-1;
  float cy = (float)(oy*15)/(float)(S-1), cx = (float)(ox*15)/(float)(S-1);
  int y0 = (int)cy; if (y0>15) y0=15; int y1 = (y0+1<16)?y0+1:15; float fy = cy-(float)y0;
  int x0 = (int)cx; if (x0>15) x0=15; int x1 = (x0+1<16)?x0+1:15; float fx = cx-(float)x0;
  const float* in = ((bt>=4)? trg : src) + ((size_t)(bt&3)*1024 + ci4*4)*256;
  #pragma unroll
  for (int i=0;i<4;i++){
    const float* p = in + (size_t)i*256;
    float v = (1.f-fy)*((1.f-fx)*p[y0*16+x0] + fx*p[y0*16+x1])
            +       fy*((1.f-fx)*p[y1*16+x0] + fx*p[y1*16+x1]);
    o[i] = f2bf(v);
  }
}

// ---------------------------------------------------------------------------
// 3) conv3x3 as bf16 MFMA implicit GEMM. D[m=co][n=pos], K=(tap,ci)=9216.
template<int NF>
DEVFN void conv_body(const unsigned short* __restrict__ Wb,
                     const unsigned short* __restrict__ P,
                     float* __restrict__ outp, int S, int lgS, int Sp, int N,
                     int co_base, int pos_base, int l){
  const int kl = ((l>>4)&3)*8;
  int yg[NF], xg[NF];
  #pragma unroll
  for (int g=0; g<NF; ++g){
    int pos = pos_base + g*16 + (l&15);
    yg[g] = pos >> lgS; xg[g] = pos & (S-1);
  }
  const unsigned short* wb0 = Wb + ((size_t)(co_base>>4)*64 + l)*8;
  f32x4 acc[2][NF];
  #pragma unroll
  for (int f=0; f<2; ++f)
    #pragma unroll
    for (int g=0; g<NF; ++g)
      acc[f][g] = (f32x4){0.f,0.f,0.f,0.f};
  #pragma unroll 1
  for (int tap=0; tap<9; ++tap){
    int dy = tap/3, dx = tap - dy*3;
    const unsigned short* pb[NF];
    #pragma unroll
    for (int g=0; g<NF; ++g)
      pb[g] = P + (size_t)((yg[g]+dy)*Sp + xg[g]+dx)*1024 + kl;
    const unsigned short* wt = wb0 + (size_t)tap*262144;
    #pragma unroll 4
    for (int kc=0; kc<32; ++kc){
      short8v a0 = *reinterpret_cast<const short8v*>(wt + (size_t)kc*8192);
      short8v a1 = *reinterpret_cast<const short8v*>(wt + (size_t)kc*8192 + 512);
      short8v bv[NF];
      #pragma unroll
      for (int g=0; g<NF; ++g)
        bv[g] = *reinterpret_cast<const short8v*>(pb[g] + kc*32);
      #pragma unroll
      for (int g=0; g<NF; ++g){
        acc[0][g] = __builtin_amdgcn_mfma_f32_16x16x32_bf16(a0, bv[g], acc[0][g], 0,0,0);
        acc[1][g] = __builtin_amdgcn_mfma_f32_16x16x32_bf16(a1, bv[g], acc[1][g], 0,0,0);
      }
    }
  }
  const int r0 = ((l>>4)&3)*4;
  #pragma unroll
  for (int f=0; f<2; ++f){
    int co = co_base + f*16 + r0;
    #pragma unroll
    for (int g=0; g<NF; ++g){
      int pp = pos_base + g*16 + (l&15);
      float* op = outp + (size_t)co*N + pp;
      #pragma unroll
      for (int i=0;i<4;i++) op[(size_t)i*N] = acc[f][g][i];
    }
  }
}

__global__ __launch_bounds__(256) void k_conv_mfma(float* __restrict__ wsf){
  int bx = blockIdx.x;
  int t = threadIdx.x, l = t&63, w = t>>6, wm = w&1, wn = w>>1;
  int scale, bt, cot, post, S, lgS, nf;
  if (bx < 512)      { scale=2; S=32; lgS=5; nf=2; bt=bx>>6; cot=(bx>>4)&3; post=bx&15; }
  else if (bx < 576) { int r=bx-512; scale=1; S=16; lgS=4; nf=4; bt=r>>3; cot=(r>>1)&3; post=r&1; }
  else               { int r=bx-576; scale=0; S=8;  lgS=3; nf=2; bt=r>>2; cot=r&3; post=0; }
  int Sp = S+2, N = S*S;
  const unsigned short* Wb = (const unsigned short*)(wsf + OFF_WB) + (size_t)scale*2359296;
  size_t poff = scale==0?OFF_P8: scale==1?OFF_P16:OFF_P32;
  const unsigned short* P = (const unsigned short*)(wsf + poff) + (size_t)bt*Sp*Sp*1024;
  size_t obase = (scale==2) ? (bt>=4?OFF_TF32:OFF_SF32)
               : (scale==1) ? (bt>=4?OFF_TF16:OFF_SF16)
                            : (bt>=4?OFF_TF8 :OFF_SF8);
  float* outp = wsf + obase + (size_t)(bt&3)*256*N;
  int co_base = cot*64 + wm*32;
  int pos_base = post*(nf*32) + wn*(nf*16);
  if (nf==4) conv_body<4>(Wb, P, outp, S, lgS, Sp, N, co_base, pos_base, l);
  else       conv_body<2>(Wb, P, outp, S, lgS, Sp, N, co_base, pos_base, l);
}

// ---------------------------------------------------------------------------
// 4) inverse feature norms per position
__global__ void k_invnorm(float* __restrict__ ws){
  int id = blockIdx.x*256 + threadIdx.x;
  if (id >= 10752) return;
  int tsr = id / 5376, r = id % 5376;
  int P, q; size_t fbase;
  if (r < 256)     { P=64;   q=r;      fbase = tsr ? OFF_TF8  : OFF_SF8; }
  else if (r<1280) { P=256;  q=r-256;  fbase = tsr ? OFF_TF16 : OFF_SF16; }
  else             { P=1024; q=r-1280; fbase = tsr ? OFF_TF32 : OFF_SF32; }
  int b = q / P, pos = q % P;
  const float* f = ws + fbase + (size_t)b*256*P + pos;
  float s = 0.f;
  for (int ch=0; ch<256; ch++){ float v = f[(size_t)ch*P]; s = fmaf(v,v,s); }
  ws[(tsr ? OFF_INVT : OFF_INVS) + r] = 1.f/sqrtf(s);
}

// ---------------------------------------------------------------------------
// 5) all 9 normalized-correlation GEMMs (f32), 64x64 tiles, K=256
__global__ __launch_bounds__(256) void k_corr(float* __restrict__ ws){
  int bx = blockIdx.x;
  int p = (bx>=4)+(bx>=20)+(bx>=84)+(bx>=100)+(bx>=164)+(bx>=420)+(bx>=484)+(bx>=740);
  int si = p/3, ti = p%3;
  int M = SSARR[si]*SSARR[si], N = SSARR[ti]*SSARR[ti];
  int ntN = N >> 6;
  int rem = bx - PAIR_START[p];
  int b = rem & 3; rem >>= 2;
  int nt = rem % ntN, mt = rem / ntN;
  int m0 = mt*64, n0 = nt*64;
  const float* A  = ws + (si==0?OFF_SF8: si==1?OFF_SF16:OFF_SF32) + (size_t)b*256*M;
  const float* Bp = ws + (ti==0?OFF_TF8: ti==1?OFF_TF16:OFF_TF32) + (size_t)b*256*N;
  const float* iS = ws + OFF_INVS + (si==0?0: si==1?256:1280) + (size_t)b*M;
  const float* iT = ws + OFF_INVT + (ti==0?0: ti==1?256:1280) + (size_t)b*N;
  float* C = ws + PAIR_OFF[p] + (size_t)b*M*N;
  __shared__ __align__(16) float As[16][64];
  __shared__ __align__(16) float Bs[16][64];
  int t = threadIdx.x, tm = t>>4, tn = t&15;
  float acc[4][4] = {};
  #pragma unroll 1
  for (int k0=0; k0<256; k0+=16){
    __syncthreads();
    #pragma unroll
    for (int i=0;i<4;i++){
      int idx = t + i*256; int k = idx>>6, m = idx&63;
      As[k][m] = A [(size_t)(k0+k)*M + m0+m];
      Bs[k][m] = Bp[(size_t)(k0+k)*N + n0+m];
    }
    __syncthreads();
    #pragma unroll
    for (int k=0;k<16;k++){
      float4 av = *reinterpret_cast<const float4*>(&As[k][tm*4]);
      float4 bv = *reinterpret_cast<const float4*>(&Bs[k][tn*4]);
      float a4[4]={av.x,av.y,av.z,av.w}, b4[4]={bv.x,bv.y,bv.z,bv.w};
      #pragma unroll
      for (int i=0;i<4;i++)
        #pragma unroll
        for (int j=0;j<4;j++)
          acc[i][j] = fmaf(a4[i], b4[j], acc[i][j]);
    }
  }
  #pragma unroll
  for (int i=0;i<4;i++){
    float sv = iS[m0+tm*4+i];
    #pragma unroll
    for (int j=0;j<4;j++)
      C[(size_t)(m0+tm*4+i)*N + n0+tn*4+j] = acc[i][j]*sv*iT[n0+tn*4+j];
  }
}

// ---------------------------------------------------------------------------
DEVFN void cw_coord(int i, int n, int OH, int& i0, int& i1, float& f){
  float c = (float)(i*(n-1))/(float)(OH-1);
  int a = (int)c; if (a > n-1) a = n-1;
  i0 = a; i1 = (a+1 < n) ? a+1 : n-1; f = c - (float)a;
}

// 6) interpolate4d each pair to [16,16,16,16], + relu
__global__ void k_interp_pairs(float* __restrict__ ws){
  int bx = blockIdx.x;
  int p = bx >> 10;
  int local = ((bx & 1023) << 8) | threadIdx.x;
  int si = p/3, ti = p%3;
  int h1 = SSARR[si], t1 = SSARR[ti];
  int px = local & 15, py = (local>>4)&15, ox = (local>>8)&15, oy = (local>>12)&15, b = local>>16;
  int y0,y1,x0,x1,u0,u1,v0,v1; float fy,fx,fu,fv;
  cw_coord(oy,h1,16,y0,y1,fy); cw_coord(ox,h1,16,x0,x1,fx);
  cw_coord(py,t1,16,u0,u1,fu); cw_coord(px,t1,16,v0,v1,fv);
  const float* in = ws + PAIR_OFF[p] + (size_t)b*h1*h1*t1*t1;
  int ys[2]={y0,y1}, xs[2]={x0,x1}, us[2]={u0,u1}, vs[2]={v0,v1};
  float wy[2]={1.f-fy,fy}, wx[2]={1.f-fx,fx}, wu[2]={1.f-fu,fu}, wv[2]={1.f-fv,fv};
  float s = 0.f;
  #pragma unroll
  for (int ia=0; ia<2; ia++)
    #pragma unroll
    for (int ic=0; ic<2; ic++){
      float wyx = wy[ia]*wx[ic];
      const float* base = in + ((size_t)ys[ia]*h1 + xs[ic])*t1*t1;
      #pragma unroll
      for (int id_=0; id_<2; id_++)
        #pragma unroll
        for (int ie=0; ie<2; ie++)
          s += wyx*wu[id_]*wv[ie]*base[(size_t)us[id_]*t1 + vs[ie]];
    }
  ws[OFF_CORR6 + ((size_t)b*9 + p)*65536 + (local & 65535)] = fmaxf(s, 0.f);
}

// ---------------------------------------------------------------------------
// 7) direct 6D conv (3,3,5,5,5,5) + sigmoid + max over 9 pairs.
//    sP stride 24 (2-way-only bank aliasing); weights via uniform (scalar)
//    loads from repacked K6R; 5 cols per (pr,d) held in regs across e.
__global__ __launch_bounds__(256) void k_chm6d(float* __restrict__ ws,
                                               const float* __restrict__ k6r){
  const int b = blockIdx.y;
  const int sy = blockIdx.x >> 4, sx = blockIdx.x & 15;
  const int t = threadIdx.x, ty = t >> 4, tx = t & 15;
  __shared__ float sP[9][20][24];
  float acc[9];
  #pragma unroll
  for (int i=0;i<9;i++) acc[i]=0.f;
  const float* c6 = ws + OFF_CORR6 + (size_t)b*9*65536;
  #pragma unroll 1
  for (int a=0; a<5; a++){
    int Y = sy+a-2; if (Y<0 || Y>15) continue;
    #pragma unroll 1
    for (int c=0; c<5; c++){
      int X = sx+c-2; if (X<0 || X>15) continue;
      __syncthreads();
      for (int idx=t; idx<3600; idx+=256){
        int pr = idx/400, rem = idx%400, yy = rem/20, xx = rem%20;
        int qy = yy-2, qx = xx-2;
        float v = 0.f;
        if (qy>=0 && qy<16 && qx>=0 && qx<16)
          v = c6[(size_t)pr*65536 + (size_t)(Y*16+X)*256 + qy*16+qx];
        sP[pr][yy][xx] = v;
      }
      __syncthreads();
      const float* wt = k6r + (size_t)(a*125 + c*25)*9;    // [d][e][kikj], uniform
      #pragma unroll 1
      for (int d=0; d<5; d++){
        #pragma unroll
        for (int pr=0; pr<9; pr++){
          const int pi = pr/3, pj = pr%3;
          float col[5];
          #pragma unroll
          for (int e=0;e<5;e++) col[e] = sP[pr][ty+d][tx+e];
          #pragma unroll
          for (int e=0;e<5;e++){
            const float* we = wt + (d*5+e)*9;
            #pragma unroll
            for (int ki=0; ki<3; ki++){
              int sio = pi-ki+1; if (sio<0 || sio>2) continue;
              #pragma unroll
              for (int kj=0; kj<3; kj++){
                int sjo = pj-kj+1; if (sjo<0 || sjo>2) continue;
                acc[sio*3+sjo] = fmaf(col[e], we[ki*3+kj], acc[sio*3+sjo]);
              }
            }
          }
        }
      }
    }
  }
  float m = acc[0];
  #pragma unroll
  for (int i=1;i<9;i++) m = fmaxf(m, acc[i]);
  float sig = 1.f/(1.f + expf(-m));
  ws[OFF_MAXED + ((size_t)b*256 + blockIdx.x)*256 + t] = sig;
}

// ---------------------------------------------------------------------------
// 8) interpolate4d 16^4 -> 32^4
__global__ void k_interp32(float* __restrict__ ws){
  int id = blockIdx.x*256 + threadIdx.x;
  int px = id & 31, py = (id>>5)&31, ox = (id>>10)&31, oy = (id>>15)&31, b = id>>20;
  int y0,y1,x0,x1,u0,u1,v0,v1; float fy,fx,fu,fv;
  cw_coord(oy,16,32,y0,y1,fy); cw_coord(ox,16,32,x0,x1,fx);
  cw_coord(py,16,32,u0,u1,fu); cw_coord(px,16,32,v0,v1,fv);
  const float* in = ws + OFF_MAXED + (size_t)b*65536;
  int ys[2]={y0,y1}, xs[2]={x0,x1}, us[2]={u0,u1}, vs[2]={v0,v1};
  float wy[2]={1.f-fy,fy}, wx[2]={1.f-fx,fx}, wu[2]={1.f-fu,fu}, wv[2]={1.f-fv,fv};
  float s = 0.f;
  #pragma unroll
  for (int ia=0; ia<2; ia++)
    #pragma unroll
    for (int ic=0; ic<2; ic++){
      float wyx = wy[ia]*wx[ic];
      const float* base = in + ((size_t)ys[ia]*16 + xs[ic])*256;
      #pragma unroll
      for (int id_=0; id_<2; id_++)
        #pragma unroll
        for (int ie=0; ie<2; ie++)
          s += wyx*wu[id_]*wv[ie]*base[(size_t)us[id_]*16 + vs[ie]];
    }
  ws[OFF_INT32 + id] = s;
}

// ---------------------------------------------------------------------------
// 9) fast4d 5^4 + bias + softplus -> d_out [4][1024][1024]
__global__ __launch_bounds__(256) void k_fast4d(float* __restrict__ ws,
                                                const float* __restrict__ k4,
                                                const float* __restrict__ b4,
                                                float* __restrict__ out){
  const int b = blockIdx.y;
  const int sy = blockIdx.x >> 5, sx = blockIdx.x & 31;
  const int t = threadIdx.x;
  const int ty = t >> 3, tx0 = (t & 7) << 2;
  __shared__ float sK[625];
  __shared__ __align__(16) float sQ[36*36];
  for (int i=t; i<625; i+=256) sK[i] = k4[i];
  float acc[4] = {0.f,0.f,0.f,0.f};
  const float* in = ws + OFF_INT32 + (size_t)b*1048576;
  #pragma unroll 1
  for (int a=0; a<5; a++){
    int Y = sy+a-2; if (Y<0 || Y>31) continue;
    #pragma unroll 1
    for (int c=0; c<5; c++){
      int X = sx+c-2; if (X<0 || X>31) continue;
      __syncthreads();
      for (int idx=t; idx<1296; idx+=256){
        int yy = idx/36, xx = idx%36, qy = yy-2, qx = xx-2;
        float v = 0.f;
        if (qy>=0 && qy<32 && qx>=0 && qx<32)
          v = in[(size_t)(Y*32+X)*1024 + qy*32+qx];
        sQ[idx] = v;
      }
      __syncthreads();
      const float* kb = &sK[a*125 + c*25];
      #pragma unroll 1
      for (int d=0; d<5; d++){
        const float* row = &sQ[(ty+d)*36 + tx0];
        float4 q0 = *reinterpret_cast<const float4*>(row);
        float4 q1 = *reinterpret_cast<const float4*>(row+4);
        float r[8] = {q0.x,q0.y,q0.z,q0.w,q1.x,q1.y,q1.z,q1.w};
        #pragma unroll
        for (int e=0; e<5; e++){
          float wv = kb[d*5+e];
          #pragma unroll
          for (int i=0;i<4;i++) acc[i] = fmaf(r[i+e], wv, acc[i]);
        }
      }
    }
  }
  float bias = b4[0];
  #pragma unroll
  for (int i=0;i<4;i++){
    float x = acc[i] + bias;
    float sp = fmaxf(x,0.f) + log1pf(expf(-fabsf(x)));
    out[((size_t)b*1024 + blockIdx.x)*1024 + ty*32 + tx0 + i] = sp;
  }
}

// ---------------------------------------------------------------------------
// 10-12) mutual_nn_filter (colmax now coalesced two-stage)
__global__ void k_rowmax(const float* __restrict__ cm, float* __restrict__ ws){
  int row = blockIdx.x;
  const float* r = cm + (size_t)row*1024;
  int t = threadIdx.x;
  float m = -1e30f;
  for (int i=t; i<1024; i+=256) m = fmaxf(m, r[i]);
  __shared__ float red[256];
  red[t] = m; __syncthreads();
  for (int off=128; off; off>>=1){
    if (t < off) red[t] = fmaxf(red[t], red[t+off]);
    __syncthreads();
  }
  if (!t) ws[OFF_SMAX + row] = red[0];
}

__global__ void k_colmax_p(const float* __restrict__ cm, float* __restrict__ ws){
  int b = blockIdx.x >> 5, rg = (blockIdx.x >> 2) & 7, cg = blockIdx.x & 3;
  int c = cg*256 + threadIdx.x;
  const float* base = cm + (size_t)b*1048576 + (size_t)rg*131072 + c;
  float m = -1e30f;
  #pragma unroll 4
  for (int r=0; r<128; r++) m = fmaxf(m, base[(size_t)r*1024]);
  ws[OFF_CMAXP + (size_t)(b*8+rg)*1024 + c] = m;
}

__global__ void k_colmax_r(float* __restrict__ ws){
  int id = blockIdx.x*256 + threadIdx.x;         // 4096
  int b = id >> 10, c = id & 1023;
  float m = -1e30f;
  #pragma unroll
  for (int rg=0; rg<8; rg++)
    m = fmaxf(m, ws[OFF_CMAXP + (size_t)(b*8+rg)*1024 + c]);
  ws[OFF_TMAX + id] = m;
}

__global__ void k_mutual(float* __restrict__ cm, const float* __restrict__ ws){
  int id = blockIdx.x*256 + threadIdx.x;
  int b = id >> 20, r = (id>>10)&1023, c = id&1023;
  float v  = cm[id];
  float sm = ws[OFF_SMAX + (b<<10) + r];
  float tm = ws[OFF_TMAX + (b<<10) + c];
  sm = (sm==0.f) ? 1e-30f : sm;
  tm = (tm==0.f) ? 1e-30f : tm;
  cm[id] = v * (v/sm) * (v/tm);
}

// ---------------------------------------------------------------------------
extern "C" void kernel_launch(void* const* d_in, const int* in_sizes, int n_in,
                              void* d_out, int out_size, void* d_ws, size_t ws_size,
                              hipStream_t stream){
  const float* src = (const float*)d_in[0];
  const float* trg = (const float*)d_in[1];
  const float* w0  = (const float*)d_in[2];
  const float* w1  = (const float*)d_in[3];
  const float* w2  = (const float*)d_in[4];
  const float* k6  = (const float*)d_in[5];
  const float* k4  = (const float*)d_in[6];
  const float* b4  = (const float*)d_in[7];
  float* ws  = (float*)d_ws;    // needs WS_FLOATS*4 = 60.7 MB
  float* out = (float*)d_out;
  (void)in_sizes; (void)n_in; (void)out_size; (void)ws_size;

  k_wpack       <<<3456,  256, 0, stream>>>(w0, w1, w2, ws);
  k_k6pack      <<<22,    256, 0, stream>>>(k6, ws);
  k_inpack      <<<12640, 256, 0, stream>>>(src, trg, ws);
  k_conv_mfma   <<<608,   256, 0, stream>>>(ws);
  k_invnorm     <<<42,    256, 0, stream>>>(ws);
  k_corr        <<<1764,  256, 0, stream>>>(ws);
  k_interp_pairs<<<9216,  256, 0, stream>>>(ws);
  k_chm6d       <<<dim3(256,4),  256, 0, stream>>>(ws, ws + OFF_K6R);
  k_interp32    <<<16384, 256, 0, stream>>>(ws);
  k_fast4d      <<<dim3(1024,4), 256, 0, stream>>>(ws, k4, b4, out);
  k_rowmax      <<<4096,  256, 0, stream>>>(out, ws);
  k_colmax_p    <<<128,   256, 0, stream>>>(out, ws);
  k_colmax_r    <<<16,    256, 0, stream>>>(ws);
  k_mutual      <<<16384, 256, 0, stream>>>(out, ws);
}

// Round 4
// 938.619 us; speedup vs baseline: 2.2880x; 1.2735x over previous
//
#include <hip/hip_runtime.h>
#include <cstdint>
#include <cstddef>

// ============================================================================
// CHMLearner forward. Conv3x3 bf16 MFMA implicit GEMM.
// R4: chm6d v3 (x4 register blocking, wave-per-batch no-barrier LDS, stride-26
//     conflict-free rows, VGPR weights, (a,c)-parity split + combine);
//     inpack v2 (LDS-staged single-pass all scales).
// ============================================================================

#define DEVFN __device__ __forceinline__

typedef __attribute__((ext_vector_type(8))) short short8v;
typedef __attribute__((ext_vector_type(4))) float f32x4;

// workspace layout (float units). Total ~60.7 MB
constexpr size_t OFF_WB    = 0;           // bf16 packed weights, 3*2,359,296 bf16
constexpr size_t OFF_P8    = 3538944;     // bf16 padded ch-last features
constexpr size_t OFF_P16   = 3948544;
constexpr size_t OFF_P32   = 5275648;
constexpr size_t OFF_SF8   = 10010624;    // conv outputs f32 [b][256][S*S]
constexpr size_t OFF_TF8   = 10076160;
constexpr size_t OFF_SF16  = 10141696;
constexpr size_t OFF_TF16  = 10403840;
constexpr size_t OFF_SF32  = 10665984;
constexpr size_t OFF_TF32  = 11714560;
constexpr size_t OFF_INVS  = 12763136;
constexpr size_t OFF_INVT  = 12768512;
constexpr size_t OFF_SMAX  = 12773888;
constexpr size_t OFF_TMAX  = 12777984;
constexpr size_t OFF_CORR6 = 12782080;    // [4][9][16^4]
constexpr size_t OFF_K6R   = OFF_CORR6 + 2359296;   // 6000 repacked 6d weights
constexpr size_t OFF_CMAXP = OFF_K6R + 6016;        // 32768 colmax partials
constexpr size_t WS_FLOATS = OFF_CMAXP + 32768;

// aliases into dead regions:
__device__ constexpr size_t PAIR_OFF[9] = {   // raw per-pair corr [4][ss^2][ts^2]
  OFF_WB + 0,       OFF_WB + 16384,   OFF_WB + 81920,
  OFF_WB + 344064,  OFF_WB + 409600,  OFF_WB + 671744,
  OFF_WB + 1720320, OFF_WB + 1982464, OFF_WB + 3031040 };
constexpr size_t OFF_MAXED = OFF_WB;              // [4][16^4] after sigmax
constexpr size_t OFF_PART  = OFF_P8;              // [2g][4b][9so][16^4] chm6d partials
constexpr size_t OFF_INT32 = OFF_WB + 262144;     // [4][32^4] upsampled (after sigmax)

__device__ constexpr int SSARR[3] = {8, 16, 32};
__device__ constexpr int PAIR_START[9] = {0,4,20,84,100,164,420,484,740}; // 1764

DEVFN unsigned short f2bf(float f){
  unsigned int u = __float_as_uint(f);
  return (unsigned short)((u + 0x7fffu + ((u >> 16) & 1u)) >> 16);
}

// ---------------------------------------------------------------------------
// 1) pack conv weights into MFMA A-fragment order (bf16)
__global__ void k_wpack(const float* __restrict__ w0, const float* __restrict__ w1,
                        const float* __restrict__ w2, float* __restrict__ wsf){
  int gid = blockIdx.x*256 + threadIdx.x;        // 884,736 exact
  int scale = gid / 294912, r = gid % 294912;
  int tap = r >> 15, kc = (r>>10)&31, nc = (r>>6)&15, l = r&63;
  const float* w = (scale==0) ? w0 : (scale==1 ? w1 : w2);
  int co = nc*16 + (l&15);
  int ci0 = kc*32 + ((l>>4)&3)*8;
  unsigned short* o = (unsigned short*)(wsf + OFF_WB) + (size_t)gid*8;
  #pragma unroll
  for (int i=0;i<8;i++)
    o[i] = f2bf(w[((size_t)co*1024 + ci0 + i)*9 + tap]);
}

// 1b) repack chm6d kernel: K6R[(a*5+c)*5+d][48: e*9+ki*3+kj]
__global__ void k_k6rp(const float* __restrict__ k6, float* __restrict__ ws){
  int o = blockIdx.x*256 + threadIdx.x;
  if (o >= 6000) return;
  int tap = o/48, r = o%48;
  float v = 0.f;
  if (r < 45){
    int e = r/9, kikj = r%9;
    int d = tap%5, ac = tap/5, a = ac/5, c = ac%5;
    v = k6[(((kikj*5 + a)*5 + c)*5 + d)*5 + e];
  }
  ws[OFF_K6R + o] = v;
}

// ---------------------------------------------------------------------------
// 2) inpack v2: stage 16 channels' 16x16 planes in LDS; emit all 3 scales
//    (resize align-corners + zero-pad + channels-last bf16). 512 blocks.
__global__ __launch_bounds__(256) void k_inpack(const float* __restrict__ src,
                                                const float* __restrict__ trg,
                                                float* __restrict__ wsf){
  int bt = blockIdx.x >> 6, cg = blockIdx.x & 63;
  int chbase = cg*16;
  int t = threadIdx.x;
  __shared__ float sIn[16][257];
  const float* gin = ((bt>=4)? trg : src) + ((size_t)(bt&3)*1024 + chbase)*256;
  #pragma unroll
  for (int i=0;i<16;i++){
    int idx = t + i*256; int ch = idx>>8, pos = idx&255;
    sIn[ch][pos] = gin[(size_t)ch*256 + pos];
  }
  __syncthreads();
  int ch = t & 15, pw = t >> 4;
  #pragma unroll 1
  for (int s=0; s<3; s++){
    int S = SSARR[s], Sp = S+2, Sp2 = Sp*Sp;
    size_t poff = (s==0)?OFF_P8 : (s==1)?OFF_P16 : OFF_P32;
    unsigned short* o = (unsigned short*)(wsf + poff) + (size_t)bt*Sp2*1024 + chbase + ch;
    float rs = 15.f/(float)(S-1);
    for (int i = pw; i < Sp2; i += 16){
      int py = i / Sp, px = i % Sp;
      float v = 0.f;
      if (py>0 && py<Sp-1 && px>0 && px<Sp-1){
        float cy = (float)(py-1)*rs, cx = (float)(px-1)*rs;
        int y0 = (int)cy; if (y0>15) y0=15; int y1 = (y0+1<16)?y0+1:15; float fy = cy-(float)y0;
        int x0 = (int)cx; if (x0>15) x0=15; int x1 = (x0+1<16)?x0+1:15; float fx = cx-(float)x0;
        v = (1.f-fy)*((1.f-fx)*sIn[ch][y0*16+x0] + fx*sIn[ch][y0*16+x1])
          +       fy*((1.f-fx)*sIn[ch][y1*16+x0] + fx*sIn[ch][y1*16+x1]);
      }
      o[(size_t)i*1024] = f2bf(v);
    }
  }
}

// ---------------------------------------------------------------------------
// 3) conv3x3 as bf16 MFMA implicit GEMM. D[m=co][n=pos], K=(tap,ci)=9216.
template<int NF>
DEVFN void conv_body(const unsigned short* __restrict__ Wb,
                     const unsigned short* __restrict__ P,
                     float* __restrict__ outp, int S, int lgS, int Sp, int N,
                     int co_base, int pos_base, int l){
  const int kl = ((l>>4)&3)*8;
  int yg[NF], xg[NF];
  #pragma unroll
  for (int g=0; g<NF; ++g){
    int pos = pos_base + g*16 + (l&15);
    yg[g] = pos >> lgS; xg[g] = pos & (S-1);
  }
  const unsigned short* wb0 = Wb + ((size_t)(co_base>>4)*64 + l)*8;
  f32x4 acc[2][NF];
  #pragma unroll
  for (int f=0; f<2; ++f)
    #pragma unroll
    for (int g=0; g<NF; ++g)
      acc[f][g] = (f32x4){0.f,0.f,0.f,0.f};
  #pragma unroll 1
  for (int tap=0; tap<9; ++tap){
    int dy = tap/3, dx = tap - dy*3;
    const unsigned short* pb[NF];
    #pragma unroll
    for (int g=0; g<NF; ++g)
      pb[g] = P + (size_t)((yg[g]+dy)*Sp + xg[g]+dx)*1024 + kl;
    const unsigned short* wt = wb0 + (size_t)tap*262144;
    #pragma unroll 4
    for (int kc=0; kc<32; ++kc){
      short8v a0 = *reinterpret_cast<const short8v*>(wt + (size_t)kc*8192);
      short8v a1 = *reinterpret_cast<const short8v*>(wt + (size_t)kc*8192 + 512);
      short8v bv[NF];
      #pragma unroll
      for (int g=0; g<NF; ++g)
        bv[g] = *reinterpret_cast<const short8v*>(pb[g] + kc*32);
      #pragma unroll
      for (int g=0; g<NF; ++g){
        acc[0][g] = __builtin_amdgcn_mfma_f32_16x16x32_bf16(a0, bv[g], acc[0][g], 0,0,0);
        acc[1][g] = __builtin_amdgcn_mfma_f32_16x16x32_bf16(a1, bv[g], acc[1][g], 0,0,0);
      }
    }
  }
  const int r0 = ((l>>4)&3)*4;
  #pragma unroll
  for (int f=0; f<2; ++f){
    int co = co_base + f*16 + r0;
    #pragma unroll
    for (int g=0; g<NF; ++g){
      int pp = pos_base + g*16 + (l&15);
      float* op = outp + (size_t)co*N + pp;
      #pragma unroll
      for (int i=0;i<4;i++) op[(size_t)i*N] = acc[f][g][i];
    }
  }
}

__global__ __launch_bounds__(256) void k_conv_mfma(float* __restrict__ wsf){
  int bx = blockIdx.x;
  int t = threadIdx.x, l = t&63, w = t>>6, wm = w&1, wn = w>>1;
  int scale, bt, cot, post, S, lgS, nf;
  if (bx < 512)      { scale=2; S=32; lgS=5; nf=2; bt=bx>>6; cot=(bx>>4)&3; post=bx&15; }
  else if (bx < 576) { int r=bx-512; scale=1; S=16; lgS=4; nf=4; bt=r>>3; cot=(r>>1)&3; post=r&1; }
  else               { int r=bx-576; scale=0; S=8;  lgS=3; nf=2; bt=r>>2; cot=r&3; post=0; }
  int Sp = S+2, N = S*S;
  const unsigned short* Wb = (const unsigned short*)(wsf + OFF_WB) + (size_t)scale*2359296;
  size_t poff = scale==0?OFF_P8: scale==1?OFF_P16:OFF_P32;
  const unsigned short* P = (const unsigned short*)(wsf + poff) + (size_t)bt*Sp*Sp*1024;
  size_t obase = (scale==2) ? (bt>=4?OFF_TF32:OFF_SF32)
               : (scale==1) ? (bt>=4?OFF_TF16:OFF_SF16)
                            : (bt>=4?OFF_TF8 :OFF_SF8);
  float* outp = wsf + obase + (size_t)(bt&3)*256*N;
  int co_base = cot*64 + wm*32;
  int pos_base = post*(nf*32) + wn*(nf*16);
  if (nf==4) conv_body<4>(Wb, P, outp, S, lgS, Sp, N, co_base, pos_base, l);
  else       conv_body<2>(Wb, P, outp, S, lgS, Sp, N, co_base, pos_base, l);
}

// ---------------------------------------------------------------------------
// 4) inverse feature norms per position
__global__ void k_invnorm(float* __restrict__ ws){
  int id = blockIdx.x*256 + threadIdx.x;
  if (id >= 10752) return;
  int tsr = id / 5376, r = id % 5376;
  int P, q; size_t fbase;
  if (r < 256)     { P=64;   q=r;      fbase = tsr ? OFF_TF8  : OFF_SF8; }
  else if (r<1280) { P=256;  q=r-256;  fbase = tsr ? OFF_TF16 : OFF_SF16; }
  else             { P=1024; q=r-1280; fbase = tsr ? OFF_TF32 : OFF_SF32; }
  int b = q / P, pos = q % P;
  const float* f = ws + fbase + (size_t)b*256*P + pos;
  float s = 0.f;
  for (int ch=0; ch<256; ch++){ float v = f[(size_t)ch*P]; s = fmaf(v,v,s); }
  ws[(tsr ? OFF_INVT : OFF_INVS) + r] = 1.f/sqrtf(s);
}

// ---------------------------------------------------------------------------
// 5) all 9 normalized-correlation GEMMs (f32), 64x64 tiles, K=256
__global__ __launch_bounds__(256) void k_corr(float* __restrict__ ws){
  int bx = blockIdx.x;
  int p = (bx>=4)+(bx>=20)+(bx>=84)+(bx>=100)+(bx>=164)+(bx>=420)+(bx>=484)+(bx>=740);
  int si = p/3, ti = p%3;
  int M = SSARR[si]*SSARR[si], N = SSARR[ti]*SSARR[ti];
  int ntN = N >> 6;
  int rem = bx - PAIR_START[p];
  int b = rem & 3; rem >>= 2;
  int nt = rem % ntN, mt = rem / ntN;
  int m0 = mt*64, n0 = nt*64;
  const float* A  = ws + (si==0?OFF_SF8: si==1?OFF_SF16:OFF_SF32) + (size_t)b*256*M;
  const float* Bp = ws + (ti==0?OFF_TF8: ti==1?OFF_TF16:OFF_TF32) + (size_t)b*256*N;
  const float* iS = ws + OFF_INVS + (si==0?0: si==1?256:1280) + (size_t)b*M;
  const float* iT = ws + OFF_INVT + (ti==0?0: ti==1?256:1280) + (size_t)b*N;
  float* C = ws + PAIR_OFF[p] + (size_t)b*M*N;
  __shared__ __align__(16) float As[16][64];
  __shared__ __align__(16) float Bs[16][64];
  int t = threadIdx.x, tm = t>>4, tn = t&15;
  float acc[4][4] = {};
  #pragma unroll 1
  for (int k0=0; k0<256; k0+=16){
    __syncthreads();
    #pragma unroll
    for (int i=0;i<4;i++){
      int idx = t + i*256; int k = idx>>6, m = idx&63;
      As[k][m] = A [(size_t)(k0+k)*M + m0+m];
      Bs[k][m] = Bp[(size_t)(k0+k)*N + n0+m];
    }
    __syncthreads();
    #pragma unroll
    for (int k=0;k<16;k++){
      float4 av = *reinterpret_cast<const float4*>(&As[k][tm*4]);
      float4 bv = *reinterpret_cast<const float4*>(&Bs[k][tn*4]);
      float a4[4]={av.x,av.y,av.z,av.w}, b4[4]={bv.x,bv.y,bv.z,bv.w};
      #pragma unroll
      for (int i=0;i<4;i++)
        #pragma unroll
        for (int j=0;j<4;j++)
          acc[i][j] = fmaf(a4[i], b4[j], acc[i][j]);
    }
  }
  #pragma unroll
  for (int i=0;i<4;i++){
    float sv = iS[m0+tm*4+i];
    #pragma unroll
    for (int j=0;j<4;j++)
      C[(size_t)(m0+tm*4+i)*N + n0+tn*4+j] = acc[i][j]*sv*iT[n0+tn*4+j];
  }
}

// ---------------------------------------------------------------------------
DEVFN void cw_coord(int i, int n, int OH, int& i0, int& i1, float& f){
  float c = (float)(i*(n-1))/(float)(OH-1);
  int a = (int)c; if (a > n-1) a = n-1;
  i0 = a; i1 = (a+1 < n) ? a+1 : n-1; f = c - (float)a;
}

// 6) interpolate4d each pair to [16,16,16,16], + relu
__global__ void k_interp_pairs(float* __restrict__ ws){
  int bx = blockIdx.x;
  int p = bx >> 10;
  int local = ((bx & 1023) << 8) | threadIdx.x;
  int si = p/3, ti = p%3;
  int h1 = SSARR[si], t1 = SSARR[ti];
  int px = local & 15, py = (local>>4)&15, ox = (local>>8)&15, oy = (local>>12)&15, b = local>>16;
  int y0,y1,x0,x1,u0,u1,v0,v1; float fy,fx,fu,fv;
  cw_coord(oy,h1,16,y0,y1,fy); cw_coord(ox,h1,16,x0,x1,fx);
  cw_coord(py,t1,16,u0,u1,fu); cw_coord(px,t1,16,v0,v1,fv);
  const float* in = ws + PAIR_OFF[p] + (size_t)b*h1*h1*t1*t1;
  int ys[2]={y0,y1}, xs[2]={x0,x1}, us[2]={u0,u1}, vs[2]={v0,v1};
  float wy[2]={1.f-fy,fy}, wx[2]={1.f-fx,fx}, wu[2]={1.f-fu,fu}, wv[2]={1.f-fv,fv};
  float s = 0.f;
  #pragma unroll
  for (int ia=0; ia<2; ia++)
    #pragma unroll
    for (int ic=0; ic<2; ic++){
      float wyx = wy[ia]*wx[ic];
      const float* base = in + ((size_t)ys[ia]*h1 + xs[ic])*t1*t1;
      #pragma unroll
      for (int id_=0; id_<2; id_++)
        #pragma unroll
        for (int ie=0; ie<2; ie++)
          s += wyx*wu[id_]*wv[ie]*base[(size_t)us[id_]*t1 + vs[ie]];
    }
  ws[OFF_CORR6 + ((size_t)b*9 + p)*65536 + (local & 65535)] = fmaxf(s, 0.f);
}

// ---------------------------------------------------------------------------
// 7) chm6d v3: direct 6D conv (3,3,5,5,5,5), zero-pad. 512 blocks =
//    (g parity of (a,c)) x (sy,sx). 4 waves/block, wave bq = batch bq with a
//    private LDS slice (no barriers). Thread (ty,tx4) computes 4 x-outputs
//    for all 9 so. Writes linear partials; k_sigmax combines.
__global__ __launch_bounds__(256) void k_chm6d(float* __restrict__ ws,
                                               const float* __restrict__ k6rp){
  const int bx = blockIdx.x;
  const int g = bx >> 8, sy = (bx>>4)&15, sx = bx&15;
  const int t = threadIdx.x;
  const int bq = t>>6, l = t&63, ty = l>>2, tx = l&3;
  __shared__ float sP[4][9][20][26];          // 74,880 B
  float* myP = &sP[bq][0][0][0];
  // zero the borders of this wave's 9 planes once (interior rewritten per tap)
  for (int i = l; i < 9*20*26; i += 64){
    int r = i % 520, rr = r/26, cc = r%26;
    if (rr<2 || rr>17 || cc<4 || cc>19) myP[i] = 0.f;
  }
  f32x4 acc[9];
  #pragma unroll
  for (int i=0;i<9;i++) acc[i] = (f32x4){0.f,0.f,0.f,0.f};
  const float* c6 = ws + OFF_CORR6 + (size_t)bq*9*65536 + l*4;
  #pragma unroll 1
  for (int a=0; a<5; a++){
    int Y = sy+a-2; if (Y<0 || Y>15) continue;
    #pragma unroll 1
    for (int c=0; c<5; c++){
      if (((a*5+c)&1) != g) continue;
      int X = sx+c-2; if (X<0 || X>15) continue;
      // stage 9 planes: lane l moves floats [4l..4l+3] of the 256-float plane
      #pragma unroll
      for (int pr=0; pr<9; pr++){
        float4 v = *reinterpret_cast<const float4*>(c6 + (size_t)pr*65536 + (size_t)(Y*16+X)*256);
        float* wp = myP + (pr*20 + 2 + (l>>2))*26 + 4 + 4*(l&3);
        *reinterpret_cast<float2*>(wp)   = make_float2(v.x, v.y);
        *reinterpret_cast<float2*>(wp+2) = make_float2(v.z, v.w);
      }
      const float* wt = k6rp + (size_t)(a*5+c)*5*48;
      #pragma unroll 1
      for (int d=0; d<5; d++){
        float4 wv[12];
        const float4* wt4 = reinterpret_cast<const float4*>(wt + d*48);
        #pragma unroll
        for (int i=0;i<12;i++) wv[i] = wt4[i];
        #pragma unroll
        for (int pr=0; pr<9; pr++){
          const int pi = pr/3, pj = pr%3;
          const float* rp = myP + (pr*20 + ty + d)*26 + 4*tx + 2;
          float r8[8];
          #pragma unroll
          for (int i=0;i<4;i++){
            float2 u = *reinterpret_cast<const float2*>(rp + 2*i);
            r8[2*i] = u.x; r8[2*i+1] = u.y;
          }
          #pragma unroll
          for (int e=0;e<5;e++){
            #pragma unroll
            for (int ki=0; ki<3; ki++){
              const int sio = pi-ki+1; if (sio<0 || sio>2) continue;
              #pragma unroll
              for (int kj=0; kj<3; kj++){
                const int sjo = pj-kj+1; if (sjo<0 || sjo>2) continue;
                const int wi = e*9 + ki*3 + kj;
                const float w = ((const float*)&wv[wi>>2])[wi&3];
                #pragma unroll
                for (int xi=0; xi<4; xi++)
                  acc[sio*3+sjo][xi] = fmaf(r8[e+xi], w, acc[sio*3+sjo][xi]);
              }
            }
          }
        }
      }
    }
  }
  float* po = ws + OFF_PART + ((size_t)(g*4+bq)*9)*65536
            + (size_t)(sy*16+sx)*256 + ty*16 + tx*4;
  #pragma unroll
  for (int so=0; so<9; so++)
    *reinterpret_cast<f32x4*>(po + (size_t)so*65536) = acc[so];
}

// 7b) combine partials + sigmoid + max over 9 so
__global__ void k_sigmax(float* __restrict__ ws){
  int id = blockIdx.x*256 + threadIdx.x;        // 4*65536
  int b = id >> 16, pos = id & 65535;
  const float* p0 = ws + OFF_PART + (size_t)b*9*65536 + pos;
  const float* p1 = p0 + (size_t)4*9*65536;
  float m = -1e30f;
  #pragma unroll
  for (int so=0; so<9; so++)
    m = fmaxf(m, p0[(size_t)so*65536] + p1[(size_t)so*65536]);
  ws[OFF_MAXED + (size_t)b*65536 + pos] = 1.f/(1.f + expf(-m));
}

// ---------------------------------------------------------------------------
// 8) interpolate4d 16^4 -> 32^4
__global__ void k_interp32(float* __restrict__ ws){
  int id = blockIdx.x*256 + threadIdx.x;
  int px = id & 31, py = (id>>5)&31, ox = (id>>10)&31, oy = (id>>15)&31, b = id>>20;
  int y0,y1,x0,x1,u0,u1,v0,v1; float fy,fx,fu,fv;
  cw_coord(oy,16,32,y0,y1,fy); cw_coord(ox,16,32,x0,x1,fx);
  cw_coord(py,16,32,u0,u1,fu); cw_coord(px,16,32,v0,v1,fv);
  const float* in = ws + OFF_MAXED + (size_t)b*65536;
  int ys[2]={y0,y1}, xs[2]={x0,x1}, us[2]={u0,u1}, vs[2]={v0,v1};
  float wy[2]={1.f-fy,fy}, wx[2]={1.f-fx,fx}, wu[2]={1.f-fu,fu}, wv[2]={1.f-fv,fv};
  float s = 0.f;
  #pragma unroll
  for (int ia=0; ia<2; ia++)
    #pragma unroll
    for (int ic=0; ic<2; ic++){
      float wyx = wy[ia]*wx[ic];
      const float* base = in + ((size_t)ys[ia]*16 + xs[ic])*256;
      #pragma unroll
      for (int id_=0; id_<2; id_++)
        #pragma unroll
        for (int ie=0; ie<2; ie++)
          s += wyx*wu[id_]*wv[ie]*base[(size_t)us[id_]*16 + vs[ie]];
    }
  ws[OFF_INT32 + id] = s;
}

// ---------------------------------------------------------------------------
// 9) fast4d 5^4 + bias + softplus -> d_out [4][1024][1024]
__global__ __launch_bounds__(256) void k_fast4d(float* __restrict__ ws,
                                                const float* __restrict__ k4,
                                                const float* __restrict__ b4,
                                                float* __restrict__ out){
  const int b = blockIdx.y;
  const int sy = blockIdx.x >> 5, sx = blockIdx.x & 31;
  const int t = threadIdx.x;
  const int ty = t >> 3, tx0 = (t & 7) << 2;
  __shared__ float sK[625];
  __shared__ __align__(16) float sQ[36*36];
  for (int i=t; i<625; i+=256) sK[i] = k4[i];
  float acc[4] = {0.f,0.f,0.f,0.f};
  const float* in = ws + OFF_INT32 + (size_t)b*1048576;
  #pragma unroll 1
  for (int a=0; a<5; a++){
    int Y = sy+a-2; if (Y<0 || Y>31) continue;
    #pragma unroll 1
    for (int c=0; c<5; c++){
      int X = sx+c-2; if (X<0 || X>31) continue;
      __syncthreads();
      for (int idx=t; idx<1296; idx+=256){
        int yy = idx/36, xx = idx%36, qy = yy-2, qx = xx-2;
        float v = 0.f;
        if (qy>=0 && qy<32 && qx>=0 && qx<32)
          v = in[(size_t)(Y*32+X)*1024 + qy*32+qx];
        sQ[idx] = v;
      }
      __syncthreads();
      const float* kb = &sK[a*125 + c*25];
      #pragma unroll 1
      for (int d=0; d<5; d++){
        const float* row = &sQ[(ty+d)*36 + tx0];
        float4 q0 = *reinterpret_cast<const float4*>(row);
        float4 q1 = *reinterpret_cast<const float4*>(row+4);
        float r[8] = {q0.x,q0.y,q0.z,q0.w,q1.x,q1.y,q1.z,q1.w};
        #pragma unroll
        for (int e=0; e<5; e++){
          float wv = kb[d*5+e];
          #pragma unroll
          for (int i=0;i<4;i++) acc[i] = fmaf(r[i+e], wv, acc[i]);
        }
      }
    }
  }
  float bias = b4[0];
  #pragma unroll
  for (int i=0;i<4;i++){
    float x = acc[i] + bias;
    float sp = fmaxf(x,0.f) + log1pf(expf(-fabsf(x)));
    out[((size_t)b*1024 + blockIdx.x)*1024 + ty*32 + tx0 + i] = sp;
  }
}

// ---------------------------------------------------------------------------
// 10-12) mutual_nn_filter
__global__ void k_rowmax(const float* __restrict__ cm, float* __restrict__ ws){
  int row = blockIdx.x;
  const float* r = cm + (size_t)row*1024;
  int t = threadIdx.x;
  float m = -1e30f;
  for (int i=t; i<1024; i+=256) m = fmaxf(m, r[i]);
  __shared__ float red[256];
  red[t] = m; __syncthreads();
  for (int off=128; off; off>>=1){
    if (t < off) red[t] = fmaxf(red[t], red[t+off]);
    __syncthreads();
  }
  if (!t) ws[OFF_SMAX + row] = red[0];
}

__global__ void k_colmax_p(const float* __restrict__ cm, float* __restrict__ ws){
  int b = blockIdx.x >> 5, rg = (blockIdx.x >> 2) & 7, cg = blockIdx.x & 3;
  int c = cg*256 + threadIdx.x;
  const float* base = cm + (size_t)b*1048576 + (size_t)rg*131072 + c;
  float m = -1e30f;
  #pragma unroll 4
  for (int r=0; r<128; r++) m = fmaxf(m, base[(size_t)r*1024]);
  ws[OFF_CMAXP + (size_t)(b*8+rg)*1024 + c] = m;
}

__global__ void k_colmax_r(float* __restrict__ ws){
  int id = blockIdx.x*256 + threadIdx.x;         // 4096
  int b = id >> 10, c = id & 1023;
  float m = -1e30f;
  #pragma unroll
  for (int rg=0; rg<8; rg++)
    m = fmaxf(m, ws[OFF_CMAXP + (size_t)(b*8+rg)*1024 + c]);
  ws[OFF_TMAX + id] = m;
}

__global__ void k_mutual(float* __restrict__ cm, const float* __restrict__ ws){
  int id = blockIdx.x*256 + threadIdx.x;
  int b = id >> 20, r = (id>>10)&1023, c = id&1023;
  float v  = cm[id];
  float sm = ws[OFF_SMAX + (b<<10) + r];
  float tm = ws[OFF_TMAX + (b<<10) + c];
  sm = (sm==0.f) ? 1e-30f : sm;
  tm = (tm==0.f) ? 1e-30f : tm;
  cm[id] = v * (v/sm) * (v/tm);
}

// ---------------------------------------------------------------------------
extern "C" void kernel_launch(void* const* d_in, const int* in_sizes, int n_in,
                              void* d_out, int out_size, void* d_ws, size_t ws_size,
                              hipStream_t stream){
  const float* src = (const float*)d_in[0];
  const float* trg = (const float*)d_in[1];
  const float* w0  = (const float*)d_in[2];
  const float* w1  = (const float*)d_in[3];
  const float* w2  = (const float*)d_in[4];
  const float* k6  = (const float*)d_in[5];
  const float* k4  = (const float*)d_in[6];
  const float* b4  = (const float*)d_in[7];
  float* ws  = (float*)d_ws;    // needs WS_FLOATS*4 = ~60.7 MB
  float* out = (float*)d_out;
  (void)in_sizes; (void)n_in; (void)out_size; (void)ws_size;

  k_wpack       <<<3456,  256, 0, stream>>>(w0, w1, w2, ws);
  k_k6rp        <<<24,    256, 0, stream>>>(k6, ws);
  k_inpack      <<<512,   256, 0, stream>>>(src, trg, ws);
  k_conv_mfma   <<<608,   256, 0, stream>>>(ws);
  k_invnorm     <<<42,    256, 0, stream>>>(ws);
  k_corr        <<<1764,  256, 0, stream>>>(ws);
  k_interp_pairs<<<9216,  256, 0, stream>>>(ws);
  k_chm6d       <<<512,   256, 0, stream>>>(ws, ws + OFF_K6R);
  k_sigmax      <<<1024,  256, 0, stream>>>(ws);
  k_interp32    <<<16384, 256, 0, stream>>>(ws);
  k_fast4d      <<<dim3(1024,4), 256, 0, stream>>>(ws, k4, b4, out);
  k_rowmax      <<<4096,  256, 0, stream>>>(out, ws);
  k_colmax_p    <<<128,   256, 0, stream>>>(out, ws);
  k_colmax_r    <<<16,    256, 0, stream>>>(ws);
  k_mutual      <<<16384, 256, 0, stream>>>(out, ws);
}

// Round 5
// 756.764 us; speedup vs baseline: 2.8378x; 1.2403x over previous
//
#include <hip/hip_runtime.h>
#include <cstdint>
#include <cstddef>

// ============================================================================
// CHMLearner forward. R5: conv3x3 rebuilt as LDS-double-buffered bf16 MFMA
// GEMM (global_load_lds staging, 2-phase pipeline). chm6d v3 from R4 kept.
// ============================================================================

#define DEVFN __device__ __forceinline__

typedef __attribute__((ext_vector_type(8))) short short8v;
typedef __attribute__((ext_vector_type(4))) float f32x4;
typedef unsigned int u32;

DEVFN void gl_lds16(const void* g, void* l){
  __builtin_amdgcn_global_load_lds(
      (const __attribute__((address_space(1))) u32*)g,
      (__attribute__((address_space(3))) u32*)l, 16, 0, 0);
}

// workspace layout (float units). Total ~60.7 MB
constexpr size_t OFF_WB    = 0;           // bf16 packed weights, 3*2,359,296 bf16
constexpr size_t OFF_P8    = 3538944;     // bf16 padded ch-last features
constexpr size_t OFF_P16   = 3948544;
constexpr size_t OFF_P32   = 5275648;
constexpr size_t OFF_SF8   = 10010624;    // conv outputs f32 [b][256][S*S]
constexpr size_t OFF_TF8   = 10076160;
constexpr size_t OFF_SF16  = 10141696;
constexpr size_t OFF_TF16  = 10403840;
constexpr size_t OFF_SF32  = 10665984;
constexpr size_t OFF_TF32  = 11714560;
constexpr size_t OFF_INVS  = 12763136;
constexpr size_t OFF_INVT  = 12768512;
constexpr size_t OFF_SMAX  = 12773888;
constexpr size_t OFF_TMAX  = 12777984;
constexpr size_t OFF_CORR6 = 12782080;    // [4][9][16^4]
constexpr size_t OFF_K6R   = OFF_CORR6 + 2359296;   // 6000 repacked 6d weights
constexpr size_t OFF_CMAXP = OFF_K6R + 6016;        // 32768 colmax partials
constexpr size_t WS_FLOATS = OFF_CMAXP + 32768;

// aliases into dead regions:
__device__ constexpr size_t PAIR_OFF[9] = {   // raw per-pair corr [4][ss^2][ts^2]
  OFF_WB + 0,       OFF_WB + 16384,   OFF_WB + 81920,
  OFF_WB + 344064,  OFF_WB + 409600,  OFF_WB + 671744,
  OFF_WB + 1720320, OFF_WB + 1982464, OFF_WB + 3031040 };
constexpr size_t OFF_MAXED = OFF_WB;              // [4][16^4] after sigmax
constexpr size_t OFF_PART  = OFF_P8;              // [2g][4b][9so][16^4] chm6d partials
constexpr size_t OFF_INT32 = OFF_WB + 262144;     // [4][32^4] upsampled (after sigmax)

__device__ constexpr int SSARR[3] = {8, 16, 32};
__device__ constexpr int PAIR_START[9] = {0,4,20,84,100,164,420,484,740}; // 1764

DEVFN unsigned short f2bf(float f){
  unsigned int u = __float_as_uint(f);
  return (unsigned short)((u + 0x7fffu + ((u >> 16) & 1u)) >> 16);
}

// ---------------------------------------------------------------------------
// 1) pack conv weights into MFMA A-fragment order (bf16):
//    Wb[scale][tap][kc][nc][l][8] = w[co=nc*16+(l&15)][ci=kc*32+8*(l>>4)+i][tap]
__global__ void k_wpack(const float* __restrict__ w0, const float* __restrict__ w1,
                        const float* __restrict__ w2, float* __restrict__ wsf){
  int gid = blockIdx.x*256 + threadIdx.x;        // 884,736 exact
  int scale = gid / 294912, r = gid % 294912;
  int tap = r >> 15, kc = (r>>10)&31, nc = (r>>6)&15, l = r&63;
  const float* w = (scale==0) ? w0 : (scale==1 ? w1 : w2);
  int co = nc*16 + (l&15);
  int ci0 = kc*32 + ((l>>4)&3)*8;
  unsigned short* o = (unsigned short*)(wsf + OFF_WB) + (size_t)gid*8;
  #pragma unroll
  for (int i=0;i<8;i++)
    o[i] = f2bf(w[((size_t)co*1024 + ci0 + i)*9 + tap]);
}

// 1b) repack chm6d kernel: K6R[(a*5+c)*5+d][48: e*9+ki*3+kj]
__global__ void k_k6rp(const float* __restrict__ k6, float* __restrict__ ws){
  int o = blockIdx.x*256 + threadIdx.x;
  if (o >= 6000) return;
  int tap = o/48, r = o%48;
  float v = 0.f;
  if (r < 45){
    int e = r/9, kikj = r%9;
    int d = tap%5, ac = tap/5, a = ac/5, c = ac%5;
    v = k6[(((kikj*5 + a)*5 + c)*5 + d)*5 + e];
  }
  ws[OFF_K6R + o] = v;
}

// ---------------------------------------------------------------------------
// 2) inpack: stage 16 channels' 16x16 planes in LDS; emit all 3 scales
__global__ __launch_bounds__(256) void k_inpack(const float* __restrict__ src,
                                                const float* __restrict__ trg,
                                                float* __restrict__ wsf){
  int bt = blockIdx.x >> 6, cg = blockIdx.x & 63;
  int chbase = cg*16;
  int t = threadIdx.x;
  __shared__ float sIn[16][257];
  const float* gin = ((bt>=4)? trg : src) + ((size_t)(bt&3)*1024 + chbase)*256;
  #pragma unroll
  for (int i=0;i<16;i++){
    int idx = t + i*256; int ch = idx>>8, pos = idx&255;
    sIn[ch][pos] = gin[(size_t)ch*256 + pos];
  }
  __syncthreads();
  int ch = t & 15, pw = t >> 4;
  #pragma unroll 1
  for (int s=0; s<3; s++){
    int S = SSARR[s], Sp = S+2, Sp2 = Sp*Sp;
    size_t poff = (s==0)?OFF_P8 : (s==1)?OFF_P16 : OFF_P32;
    unsigned short* o = (unsigned short*)(wsf + poff) + (size_t)bt*Sp2*1024 + chbase + ch;
    float rs = 15.f/(float)(S-1);
    for (int i = pw; i < Sp2; i += 16){
      int py = i / Sp, px = i % Sp;
      float v = 0.f;
      if (py>0 && py<Sp-1 && px>0 && px<Sp-1){
        float cy = (float)(py-1)*rs, cx = (float)(px-1)*rs;
        int y0 = (int)cy; if (y0>15) y0=15; int y1 = (y0+1<16)?y0+1:15; float fy = cy-(float)y0;
        int x0 = (int)cx; if (x0>15) x0=15; int x1 = (x0+1<16)?x0+1:15; float fx = cx-(float)x0;
        v = (1.f-fy)*((1.f-fx)*sIn[ch][y0*16+x0] + fx*sIn[ch][y0*16+x1])
          +       fy*((1.f-fx)*sIn[ch][y1*16+x0] + fx*sIn[ch][y1*16+x1]);
      }
      o[(size_t)i*1024] = f2bf(v);
    }
  }
}

// ---------------------------------------------------------------------------
// 3) conv3x3 as bf16 MFMA GEMM with LDS double-buffer + global_load_lds.
//    Block: 4 waves (2m x 2n), tile 128co x 64pos, BK=64, K=9216 (144 iters).
__global__ __launch_bounds__(256) void k_conv_mfma(float* __restrict__ wsf){
  int bx = blockIdx.x;
  int scale, bt, cot, post, S, lgS;
  if (bx < 256)      { scale=2; S=32; lgS=5; bt=bx>>5; cot=(bx>>4)&1; post=bx&15; }
  else if (bx < 320) { int r=bx-256; scale=1; S=16; lgS=4; bt=r>>3; cot=(r>>2)&1; post=r&3; }
  else               { int r=bx-320; scale=0; S=8;  lgS=3; bt=r>>1; cot=r&1; post=0; }
  const int Sp = S+2, N = S*S;
  const unsigned short* WbS = (const unsigned short*)(wsf + OFF_WB) + (size_t)scale*2359296;
  size_t poff = scale==0?OFF_P8: scale==1?OFF_P16:OFF_P32;
  const unsigned short* Pb = (const unsigned short*)(wsf + poff) + (size_t)bt*Sp*Sp*1024;
  size_t obase = (scale==2) ? (bt>=4?OFF_TF32:OFF_SF32)
               : (scale==1) ? (bt>=4?OFF_TF16:OFF_SF16)
                            : (bt>=4?OFF_TF8 :OFF_SF8);
  float* outp = wsf + obase + (size_t)(bt&3)*256*N;

  const int t = threadIdx.x, l = t&63, w = t>>6, wm = w&1, wn = w>>1;
  const int nc_base = cot*8;
  const int pos0 = post*64;

  // LDS: A [buf][kc2][nc8][lane64][8]  B [buf][kc2][np4][lane64][8]
  __shared__ __align__(16) unsigned short Ab[2][8192];   // 32 KB
  __shared__ __align__(16) unsigned short Bb[2][4096];   // 16 KB

  f32x4 acc[4][2];
  #pragma unroll
  for (int i=0;i<4;i++)
    #pragma unroll
    for (int j=0;j<2;j++) acc[i][j] = (f32x4){0.f,0.f,0.f,0.f};

  auto STAGE = [&](int buf, int it){
    int tap = it>>4, kq = it&15;
    int dy = tap/3, dx = tap - dy*3;
    #pragma unroll
    for (int j=0;j<4;++j){                       // A chunks: this wave's 4 of 16
      int c = w + j*4;
      int kc = c>>3, nc = c&7;
      const unsigned short* src =
        WbS + ((((size_t)tap*32 + kq*2 + kc)*16 + nc_base + nc)*64 + l)*8;
      gl_lds16(src, &Ab[buf][c*512]);
    }
    #pragma unroll
    for (int j=0;j<2;++j){                       // B chunks: this wave's 2 of 8
      int c = w + j*4;
      int kc = c>>2, np = c&3;
      int pos = pos0 + np*16 + (l&15);
      int y = pos>>lgS, x = pos&(S-1);
      int row = (y+dy)*Sp + (x+dx);
      int ci = kq*64 + kc*32 + ((l>>4)<<3);
      gl_lds16(Pb + (size_t)row*1024 + ci, &Bb[buf][c*512]);
    }
  };

  STAGE(0, 0);
  __syncthreads();
  int buf = 0;
  #pragma unroll 1
  for (int it=0; it<144; ++it){
    if (it+1 < 144) STAGE(buf^1, it+1);
    #pragma unroll
    for (int kc=0; kc<2; ++kc){
      short8v a0 = *(const short8v*)&Ab[buf][((kc*8 + wm*4 + 0)*64 + l)*8];
      short8v a1 = *(const short8v*)&Ab[buf][((kc*8 + wm*4 + 1)*64 + l)*8];
      short8v a2 = *(const short8v*)&Ab[buf][((kc*8 + wm*4 + 2)*64 + l)*8];
      short8v a3 = *(const short8v*)&Ab[buf][((kc*8 + wm*4 + 3)*64 + l)*8];
      short8v b0 = *(const short8v*)&Bb[buf][((kc*4 + wn*2 + 0)*64 + l)*8];
      short8v b1 = *(const short8v*)&Bb[buf][((kc*4 + wn*2 + 1)*64 + l)*8];
      acc[0][0] = __builtin_amdgcn_mfma_f32_16x16x32_bf16(a0, b0, acc[0][0], 0,0,0);
      acc[1][0] = __builtin_amdgcn_mfma_f32_16x16x32_bf16(a1, b0, acc[1][0], 0,0,0);
      acc[2][0] = __builtin_amdgcn_mfma_f32_16x16x32_bf16(a2, b0, acc[2][0], 0,0,0);
      acc[3][0] = __builtin_amdgcn_mfma_f32_16x16x32_bf16(a3, b0, acc[3][0], 0,0,0);
      acc[0][1] = __builtin_amdgcn_mfma_f32_16x16x32_bf16(a0, b1, acc[0][1], 0,0,0);
      acc[1][1] = __builtin_amdgcn_mfma_f32_16x16x32_bf16(a1, b1, acc[1][1], 0,0,0);
      acc[2][1] = __builtin_amdgcn_mfma_f32_16x16x32_bf16(a2, b1, acc[2][1], 0,0,0);
      acc[3][1] = __builtin_amdgcn_mfma_f32_16x16x32_bf16(a3, b1, acc[3][1], 0,0,0);
    }
    __syncthreads();        // compiler drains vmcnt+lgkmcnt here: buf^1 ready
    buf ^= 1;
  }

  const int r0 = (l>>4)*4, cl = l&15;
  float* ob = outp + (size_t)(cot*128 + wm*64)*N + pos0 + wn*32 + cl;
  #pragma unroll
  for (int mf=0; mf<4; ++mf)
    #pragma unroll
    for (int nf=0; nf<2; ++nf){
      float* op = ob + (size_t)(mf*16 + r0)*N + nf*16;
      #pragma unroll
      for (int i=0;i<4;++i) op[(size_t)i*N] = acc[mf][nf][i];
    }
}

// ---------------------------------------------------------------------------
// 4) inverse feature norms per position
__global__ void k_invnorm(float* __restrict__ ws){
  int id = blockIdx.x*256 + threadIdx.x;
  if (id >= 10752) return;
  int tsr = id / 5376, r = id % 5376;
  int P, q; size_t fbase;
  if (r < 256)     { P=64;   q=r;      fbase = tsr ? OFF_TF8  : OFF_SF8; }
  else if (r<1280) { P=256;  q=r-256;  fbase = tsr ? OFF_TF16 : OFF_SF16; }
  else             { P=1024; q=r-1280; fbase = tsr ? OFF_TF32 : OFF_SF32; }
  int b = q / P, pos = q % P;
  const float* f = ws + fbase + (size_t)b*256*P + pos;
  float s = 0.f;
  for (int ch=0; ch<256; ch++){ float v = f[(size_t)ch*P]; s = fmaf(v,v,s); }
  ws[(tsr ? OFF_INVT : OFF_INVS) + r] = 1.f/sqrtf(s);
}

// ---------------------------------------------------------------------------
// 5) all 9 normalized-correlation GEMMs (f32), 64x64 tiles, K=256
__global__ __launch_bounds__(256) void k_corr(float* __restrict__ ws){
  int bx = blockIdx.x;
  int p = (bx>=4)+(bx>=20)+(bx>=84)+(bx>=100)+(bx>=164)+(bx>=420)+(bx>=484)+(bx>=740);
  int si = p/3, ti = p%3;
  int M = SSARR[si]*SSARR[si], N = SSARR[ti]*SSARR[ti];
  int ntN = N >> 6;
  int rem = bx - PAIR_START[p];
  int b = rem & 3; rem >>= 2;
  int nt = rem % ntN, mt = rem / ntN;
  int m0 = mt*64, n0 = nt*64;
  const float* A  = ws + (si==0?OFF_SF8: si==1?OFF_SF16:OFF_SF32) + (size_t)b*256*M;
  const float* Bp = ws + (ti==0?OFF_TF8: ti==1?OFF_TF16:OFF_TF32) + (size_t)b*256*N;
  const float* iS = ws + OFF_INVS + (si==0?0: si==1?256:1280) + (size_t)b*M;
  const float* iT = ws + OFF_INVT + (ti==0?0: ti==1?256:1280) + (size_t)b*N;
  float* C = ws + PAIR_OFF[p] + (size_t)b*M*N;
  __shared__ __align__(16) float As[16][64];
  __shared__ __align__(16) float Bs[16][64];
  int t = threadIdx.x, tm = t>>4, tn = t&15;
  float acc[4][4] = {};
  #pragma unroll 1
  for (int k0=0; k0<256; k0+=16){
    __syncthreads();
    #pragma unroll
    for (int i=0;i<4;i++){
      int idx = t + i*256; int k = idx>>6, m = idx&63;
      As[k][m] = A [(size_t)(k0+k)*M + m0+m];
      Bs[k][m] = Bp[(size_t)(k0+k)*N + n0+m];
    }
    __syncthreads();
    #pragma unroll
    for (int k=0;k<16;k++){
      float4 av = *reinterpret_cast<const float4*>(&As[k][tm*4]);
      float4 bv = *reinterpret_cast<const float4*>(&Bs[k][tn*4]);
      float a4[4]={av.x,av.y,av.z,av.w}, b4[4]={bv.x,bv.y,bv.z,bv.w};
      #pragma unroll
      for (int i=0;i<4;i++)
        #pragma unroll
        for (int j=0;j<4;j++)
          acc[i][j] = fmaf(a4[i], b4[j], acc[i][j]);
    }
  }
  #pragma unroll
  for (int i=0;i<4;i++){
    float sv = iS[m0+tm*4+i];
    #pragma unroll
    for (int j=0;j<4;j++)
      C[(size_t)(m0+tm*4+i)*N + n0+tn*4+j] = acc[i][j]*sv*iT[n0+tn*4+j];
  }
}

// ---------------------------------------------------------------------------
DEVFN void cw_coord(int i, int n, int OH, int& i0, int& i1, float& f){
  float c = (float)(i*(n-1))/(float)(OH-1);
  int a = (int)c; if (a > n-1) a = n-1;
  i0 = a; i1 = (a+1 < n) ? a+1 : n-1; f = c - (float)a;
}

// 6) interpolate4d each pair to [16,16,16,16], + relu
__global__ void k_interp_pairs(float* __restrict__ ws){
  int bx = blockIdx.x;
  int p = bx >> 10;
  int local = ((bx & 1023) << 8) | threadIdx.x;
  int si = p/3, ti = p%3;
  int h1 = SSARR[si], t1 = SSARR[ti];
  int px = local & 15, py = (local>>4)&15, ox = (local>>8)&15, oy = (local>>12)&15, b = local>>16;
  int y0,y1,x0,x1,u0,u1,v0,v1; float fy,fx,fu,fv;
  cw_coord(oy,h1,16,y0,y1,fy); cw_coord(ox,h1,16,x0,x1,fx);
  cw_coord(py,t1,16,u0,u1,fu); cw_coord(px,t1,16,v0,v1,fv);
  const float* in = ws + PAIR_OFF[p] + (size_t)b*h1*h1*t1*t1;
  int ys[2]={y0,y1}, xs[2]={x0,x1}, us[2]={u0,u1}, vs[2]={v0,v1};
  float wy[2]={1.f-fy,fy}, wx[2]={1.f-fx,fx}, wu[2]={1.f-fu,fu}, wv[2]={1.f-fv,fv};
  float s = 0.f;
  #pragma unroll
  for (int ia=0; ia<2; ia++)
    #pragma unroll
    for (int ic=0; ic<2; ic++){
      float wyx = wy[ia]*wx[ic];
      const float* base = in + ((size_t)ys[ia]*h1 + xs[ic])*t1*t1;
      #pragma unroll
      for (int id_=0; id_<2; id_++)
        #pragma unroll
        for (int ie=0; ie<2; ie++)
          s += wyx*wu[id_]*wv[ie]*base[(size_t)us[id_]*t1 + vs[ie]];
    }
  ws[OFF_CORR6 + ((size_t)b*9 + p)*65536 + (local & 65535)] = fmaxf(s, 0.f);
}

// ---------------------------------------------------------------------------
// 7) chm6d v3 (R4): wave-per-batch, stride-26 LDS, (a,c)-parity split
__global__ __launch_bounds__(256) void k_chm6d(float* __restrict__ ws,
                                               const float* __restrict__ k6rp){
  const int bx = blockIdx.x;
  const int g = bx >> 8, sy = (bx>>4)&15, sx = bx&15;
  const int t = threadIdx.x;
  const int bq = t>>6, l = t&63, ty = l>>2, tx = l&3;
  __shared__ float sP[4][9][20][26];
  float* myP = &sP[bq][0][0][0];
  for (int i = l; i < 9*20*26; i += 64){
    int r = i % 520, rr = r/26, cc = r%26;
    if (rr<2 || rr>17 || cc<4 || cc>19) myP[i] = 0.f;
  }
  f32x4 acc[9];
  #pragma unroll
  for (int i=0;i<9;i++) acc[i] = (f32x4){0.f,0.f,0.f,0.f};
  const float* c6 = ws + OFF_CORR6 + (size_t)bq*9*65536 + l*4;
  #pragma unroll 1
  for (int a=0; a<5; a++){
    int Y = sy+a-2; if (Y<0 || Y>15) continue;
    #pragma unroll 1
    for (int c=0; c<5; c++){
      if (((a*5+c)&1) != g) continue;
      int X = sx+c-2; if (X<0 || X>15) continue;
      #pragma unroll
      for (int pr=0; pr<9; pr++){
        float4 v = *reinterpret_cast<const float4*>(c6 + (size_t)pr*65536 + (size_t)(Y*16+X)*256);
        float* wp = myP + (pr*20 + 2 + (l>>2))*26 + 4 + 4*(l&3);
        *reinterpret_cast<float2*>(wp)   = make_float2(v.x, v.y);
        *reinterpret_cast<float2*>(wp+2) = make_float2(v.z, v.w);
      }
      const float* wt = k6rp + (size_t)(a*5+c)*5*48;
      #pragma unroll 1
      for (int d=0; d<5; d++){
        float4 wv[12];
        const float4* wt4 = reinterpret_cast<const float4*>(wt + d*48);
        #pragma unroll
        for (int i=0;i<12;i++) wv[i] = wt4[i];
        #pragma unroll
        for (int pr=0; pr<9; pr++){
          const int pi = pr/3, pj = pr%3;
          const float* rp = myP + (pr*20 + ty + d)*26 + 4*tx + 2;
          float r8[8];
          #pragma unroll
          for (int i=0;i<4;i++){
            float2 u = *reinterpret_cast<const float2*>(rp + 2*i);
            r8[2*i] = u.x; r8[2*i+1] = u.y;
          }
          #pragma unroll
          for (int e=0;e<5;e++){
            #pragma unroll
            for (int ki=0; ki<3; ki++){
              const int sio = pi-ki+1; if (sio<0 || sio>2) continue;
              #pragma unroll
              for (int kj=0; kj<3; kj++){
                const int sjo = pj-kj+1; if (sjo<0 || sjo>2) continue;
                const int wi = e*9 + ki*3 + kj;
                const float w = ((const float*)&wv[wi>>2])[wi&3];
                #pragma unroll
                for (int xi=0; xi<4; xi++)
                  acc[sio*3+sjo][xi] = fmaf(r8[e+xi], w, acc[sio*3+sjo][xi]);
              }
            }
          }
        }
      }
    }
  }
  float* po = ws + OFF_PART + ((size_t)(g*4+bq)*9)*65536
            + (size_t)(sy*16+sx)*256 + ty*16 + tx*4;
  #pragma unroll
  for (int so=0; so<9; so++)
    *reinterpret_cast<f32x4*>(po + (size_t)so*65536) = acc[so];
}

// 7b) combine partials + sigmoid + max over 9 so
__global__ void k_sigmax(float* __restrict__ ws){
  int id = blockIdx.x*256 + threadIdx.x;        // 4*65536
  int b = id >> 16, pos = id & 65535;
  const float* p0 = ws + OFF_PART + (size_t)b*9*65536 + pos;
  const float* p1 = p0 + (size_t)4*9*65536;
  float m = -1e30f;
  #pragma unroll
  for (int so=0; so<9; so++)
    m = fmaxf(m, p0[(size_t)so*65536] + p1[(size_t)so*65536]);
  ws[OFF_MAXED + (size_t)b*65536 + pos] = 1.f/(1.f + expf(-m));
}

// ---------------------------------------------------------------------------
// 8) interpolate4d 16^4 -> 32^4
__global__ void k_interp32(float* __restrict__ ws){
  int id = blockIdx.x*256 + threadIdx.x;
  int px = id & 31, py = (id>>5)&31, ox = (id>>10)&31, oy = (id>>15)&31, b = id>>20;
  int y0,y1,x0,x1,u0,u1,v0,v1; float fy,fx,fu,fv;
  cw_coord(oy,16,32,y0,y1,fy); cw_coord(ox,16,32,x0,x1,fx);
  cw_coord(py,16,32,u0,u1,fu); cw_coord(px,16,32,v0,v1,fv);
  const float* in = ws + OFF_MAXED + (size_t)b*65536;
  int ys[2]={y0,y1}, xs[2]={x0,x1}, us[2]={u0,u1}, vs[2]={v0,v1};
  float wy[2]={1.f-fy,fy}, wx[2]={1.f-fx,fx}, wu[2]={1.f-fu,fu}, wv[2]={1.f-fv,fv};
  float s = 0.f;
  #pragma unroll
  for (int ia=0; ia<2; ia++)
    #pragma unroll
    for (int ic=0; ic<2; ic++){
      float wyx = wy[ia]*wx[ic];
      const float* base = in + ((size_t)ys[ia]*16 + xs[ic])*256;
      #pragma unroll
      for (int id_=0; id_<2; id_++)
        #pragma unroll
        for (int ie=0; ie<2; ie++)
          s += wyx*wu[id_]*wv[ie]*base[(size_t)us[id_]*16 + vs[ie]];
    }
  ws[OFF_INT32 + id] = s;
}

// ---------------------------------------------------------------------------
// 9) fast4d 5^4 + bias + softplus -> d_out [4][1024][1024]
__global__ __launch_bounds__(256) void k_fast4d(float* __restrict__ ws,
                                                const float* __restrict__ k4,
                                                const float* __restrict__ b4,
                                                float* __restrict__ out){
  const int b = blockIdx.y;
  const int sy = blockIdx.x >> 5, sx = blockIdx.x & 31;
  const int t = threadIdx.x;
  const int ty = t >> 3, tx0 = (t & 7) << 2;
  __shared__ float sK[625];
  __shared__ __align__(16) float sQ[36*36];
  for (int i=t; i<625; i+=256) sK[i] = k4[i];
  float acc[4] = {0.f,0.f,0.f,0.f};
  const float* in = ws + OFF_INT32 + (size_t)b*1048576;
  #pragma unroll 1
  for (int a=0; a<5; a++){
    int Y = sy+a-2; if (Y<0 || Y>31) continue;
    #pragma unroll 1
    for (int c=0; c<5; c++){
      int X = sx+c-2; if (X<0 || X>31) continue;
      __syncthreads();
      for (int idx=t; idx<1296; idx+=256){
        int yy = idx/36, xx = idx%36, qy = yy-2, qx = xx-2;
        float v = 0.f;
        if (qy>=0 && qy<32 && qx>=0 && qx<32)
          v = in[(size_t)(Y*32+X)*1024 + qy*32+qx];
        sQ[idx] = v;
      }
      __syncthreads();
      const float* kb = &sK[a*125 + c*25];
      #pragma unroll 1
      for (int d=0; d<5; d++){
        const float* row = &sQ[(ty+d)*36 + tx0];
        float4 q0 = *reinterpret_cast<const float4*>(row);
        float4 q1 = *reinterpret_cast<const float4*>(row+4);
        float r[8] = {q0.x,q0.y,q0.z,q0.w,q1.x,q1.y,q1.z,q1.w};
        #pragma unroll
        for (int e=0; e<5; e++){
          float wv = kb[d*5+e];
          #pragma unroll
          for (int i=0;i<4;i++) acc[i] = fmaf(r[i+e], wv, acc[i]);
        }
      }
    }
  }
  float bias = b4[0];
  #pragma unroll
  for (int i=0;i<4;i++){
    float x = acc[i] + bias;
    float sp = fmaxf(x,0.f) + log1pf(expf(-fabsf(x)));
    out[((size_t)b*1024 + blockIdx.x)*1024 + ty*32 + tx0 + i] = sp;
  }
}

// ---------------------------------------------------------------------------
// 10-12) mutual_nn_filter
__global__ void k_rowmax(const float* __restrict__ cm, float* __restrict__ ws){
  int row = blockIdx.x;
  const float* r = cm + (size_t)row*1024;
  int t = threadIdx.x;
  float m = -1e30f;
  for (int i=t; i<1024; i+=256) m = fmaxf(m, r[i]);
  __shared__ float red[256];
  red[t] = m; __syncthreads();
  for (int off=128; off; off>>=1){
    if (t < off) red[t] = fmaxf(red[t], red[t+off]);
    __syncthreads();
  }
  if (!t) ws[OFF_SMAX + row] = red[0];
}

__global__ void k_colmax_p(const float* __restrict__ cm, float* __restrict__ ws){
  int b = blockIdx.x >> 5, rg = (blockIdx.x >> 2) & 7, cg = blockIdx.x & 3;
  int c = cg*256 + threadIdx.x;
  const float* base = cm + (size_t)b*1048576 + (size_t)rg*131072 + c;
  float m = -1e30f;
  #pragma unroll 4
  for (int r=0; r<128; r++) m = fmaxf(m, base[(size_t)r*1024]);
  ws[OFF_CMAXP + (size_t)(b*8+rg)*1024 + c] = m;
}

__global__ void k_colmax_r(float* __restrict__ ws){
  int id = blockIdx.x*256 + threadIdx.x;         // 4096
  int b = id >> 10, c = id & 1023;
  float m = -1e30f;
  #pragma unroll
  for (int rg=0; rg<8; rg++)
    m = fmaxf(m, ws[OFF_CMAXP + (size_t)(b*8+rg)*1024 + c]);
  ws[OFF_TMAX + id] = m;
}

__global__ void k_mutual(float* __restrict__ cm, const float* __restrict__ ws){
  int id = blockIdx.x*256 + threadIdx.x;
  int b = id >> 20, r = (id>>10)&1023, c = id&1023;
  float v  = cm[id];
  float sm = ws[OFF_SMAX + (b<<10) + r];
  float tm = ws[OFF_TMAX + (b<<10) + c];
  sm = (sm==0.f) ? 1e-30f : sm;
  tm = (tm==0.f) ? 1e-30f : tm;
  cm[id] = v * (v/sm) * (v/tm);
}

// ---------------------------------------------------------------------------
extern "C" void kernel_launch(void* const* d_in, const int* in_sizes, int n_in,
                              void* d_out, int out_size, void* d_ws, size_t ws_size,
                              hipStream_t stream){
  const float* src = (const float*)d_in[0];
  const float* trg = (const float*)d_in[1];
  const float* w0  = (const float*)d_in[2];
  const float* w1  = (const float*)d_in[3];
  const float* w2  = (const float*)d_in[4];
  const float* k6  = (const float*)d_in[5];
  const float* k4  = (const float*)d_in[6];
  const float* b4  = (const float*)d_in[7];
  float* ws  = (float*)d_ws;    // needs WS_FLOATS*4 = ~60.7 MB
  float* out = (float*)d_out;
  (void)in_sizes; (void)n_in; (void)out_size; (void)ws_size;

  k_wpack       <<<3456,  256, 0, stream>>>(w0, w1, w2, ws);
  k_k6rp        <<<24,    256, 0, stream>>>(k6, ws);
  k_inpack      <<<512,   256, 0, stream>>>(src, trg, ws);
  k_conv_mfma   <<<336,   256, 0, stream>>>(ws);
  k_invnorm     <<<42,    256, 0, stream>>>(ws);
  k_corr        <<<1764,  256, 0, stream>>>(ws);
  k_interp_pairs<<<9216,  256, 0, stream>>>(ws);
  k_chm6d       <<<512,   256, 0, stream>>>(ws, ws + OFF_K6R);
  k_sigmax      <<<1024,  256, 0, stream>>>(ws);
  k_interp32    <<<16384, 256, 0, stream>>>(ws);
  k_fast4d      <<<dim3(1024,4), 256, 0, stream>>>(ws, k4, b4, out);
  k_rowmax      <<<4096,  256, 0, stream>>>(out, ws);
  k_colmax_p    <<<128,   256, 0, stream>>>(out, ws);
  k_colmax_r    <<<16,    256, 0, stream>>>(ws);
  k_mutual      <<<16384, 256, 0, stream>>>(out, ws);
}

// Round 6
// 681.145 us; speedup vs baseline: 3.1528x; 1.1110x over previous
//
#include <hip/hip_runtime.h>
#include <cstdint>
#include <cstddef>

// ============================================================================
// CHMLearner forward. R6: fast4d v2 (stride-48 LDS, coalesced float4 staging,
// no div/mod, unrolled taps); interp_pairs v2 (LDS-staged corner planes).
// Conv MFMA pipeline (R5) and chm6d v3 (R4) kept.
// ============================================================================

#define DEVFN __device__ __forceinline__

typedef __attribute__((ext_vector_type(8))) short short8v;
typedef __attribute__((ext_vector_type(4))) float f32x4;
typedef unsigned int u32;

DEVFN void gl_lds16(const void* g, void* l){
  __builtin_amdgcn_global_load_lds(
      (const __attribute__((address_space(1))) u32*)g,
      (__attribute__((address_space(3))) u32*)l, 16, 0, 0);
}

// workspace layout (float units). Total ~60.7 MB
constexpr size_t OFF_WB    = 0;           // bf16 packed weights, 3*2,359,296 bf16
constexpr size_t OFF_P8    = 3538944;     // bf16 padded ch-last features
constexpr size_t OFF_P16   = 3948544;
constexpr size_t OFF_P32   = 5275648;
constexpr size_t OFF_SF8   = 10010624;    // conv outputs f32 [b][256][S*S]
constexpr size_t OFF_TF8   = 10076160;
constexpr size_t OFF_SF16  = 10141696;
constexpr size_t OFF_TF16  = 10403840;
constexpr size_t OFF_SF32  = 10665984;
constexpr size_t OFF_TF32  = 11714560;
constexpr size_t OFF_INVS  = 12763136;
constexpr size_t OFF_INVT  = 12768512;
constexpr size_t OFF_SMAX  = 12773888;
constexpr size_t OFF_TMAX  = 12777984;
constexpr size_t OFF_CORR6 = 12782080;    // [4][9][16^4]
constexpr size_t OFF_K6R   = OFF_CORR6 + 2359296;   // 6000 repacked 6d weights
constexpr size_t OFF_CMAXP = OFF_K6R + 6016;        // 32768 colmax partials
constexpr size_t WS_FLOATS = OFF_CMAXP + 32768;

// aliases into dead regions:
__device__ constexpr size_t PAIR_OFF[9] = {   // raw per-pair corr [4][ss^2][ts^2]
  OFF_WB + 0,       OFF_WB + 16384,   OFF_WB + 81920,
  OFF_WB + 344064,  OFF_WB + 409600,  OFF_WB + 671744,
  OFF_WB + 1720320, OFF_WB + 1982464, OFF_WB + 3031040 };
constexpr size_t OFF_MAXED = OFF_WB;              // [4][16^4] after sigmax
constexpr size_t OFF_PART  = OFF_P8;              // [2g][4b][9so][16^4] chm6d partials
constexpr size_t OFF_INT32 = OFF_WB + 262144;     // [4][32^4] upsampled (after sigmax)

__device__ constexpr int SSARR[3] = {8, 16, 32};
__device__ constexpr int PAIR_START[9] = {0,4,20,84,100,164,420,484,740}; // 1764

DEVFN unsigned short f2bf(float f){
  unsigned int u = __float_as_uint(f);
  return (unsigned short)((u + 0x7fffu + ((u >> 16) & 1u)) >> 16);
}

// ---------------------------------------------------------------------------
// 1) pack conv weights into MFMA A-fragment order (bf16)
__global__ void k_wpack(const float* __restrict__ w0, const float* __restrict__ w1,
                        const float* __restrict__ w2, float* __restrict__ wsf){
  int gid = blockIdx.x*256 + threadIdx.x;        // 884,736 exact
  int scale = gid / 294912, r = gid % 294912;
  int tap = r >> 15, kc = (r>>10)&31, nc = (r>>6)&15, l = r&63;
  const float* w = (scale==0) ? w0 : (scale==1 ? w1 : w2);
  int co = nc*16 + (l&15);
  int ci0 = kc*32 + ((l>>4)&3)*8;
  unsigned short* o = (unsigned short*)(wsf + OFF_WB) + (size_t)gid*8;
  #pragma unroll
  for (int i=0;i<8;i++)
    o[i] = f2bf(w[((size_t)co*1024 + ci0 + i)*9 + tap]);
}

// 1b) repack chm6d kernel: K6R[(a*5+c)*5+d][48: e*9+ki*3+kj]
__global__ void k_k6rp(const float* __restrict__ k6, float* __restrict__ ws){
  int o = blockIdx.x*256 + threadIdx.x;
  if (o >= 6000) return;
  int tap = o/48, r = o%48;
  float v = 0.f;
  if (r < 45){
    int e = r/9, kikj = r%9;
    int d = tap%5, ac = tap/5, a = ac/5, c = ac%5;
    v = k6[(((kikj*5 + a)*5 + c)*5 + d)*5 + e];
  }
  ws[OFF_K6R + o] = v;
}

// ---------------------------------------------------------------------------
// 2) inpack: stage 16 channels' 16x16 planes in LDS; emit all 3 scales
__global__ __launch_bounds__(256) void k_inpack(const float* __restrict__ src,
                                                const float* __restrict__ trg,
                                                float* __restrict__ wsf){
  int bt = blockIdx.x >> 6, cg = blockIdx.x & 63;
  int chbase = cg*16;
  int t = threadIdx.x;
  __shared__ float sIn[16][257];
  const float* gin = ((bt>=4)? trg : src) + ((size_t)(bt&3)*1024 + chbase)*256;
  #pragma unroll
  for (int i=0;i<16;i++){
    int idx = t + i*256; int ch = idx>>8, pos = idx&255;
    sIn[ch][pos] = gin[(size_t)ch*256 + pos];
  }
  __syncthreads();
  int ch = t & 15, pw = t >> 4;
  #pragma unroll 1
  for (int s=0; s<3; s++){
    int S = SSARR[s], Sp = S+2, Sp2 = Sp*Sp;
    size_t poff = (s==0)?OFF_P8 : (s==1)?OFF_P16 : OFF_P32;
    unsigned short* o = (unsigned short*)(wsf + poff) + (size_t)bt*Sp2*1024 + chbase + ch;
    float rs = 15.f/(float)(S-1);
    for (int i = pw; i < Sp2; i += 16){
      int py = i / Sp, px = i % Sp;
      float v = 0.f;
      if (py>0 && py<Sp-1 && px>0 && px<Sp-1){
        float cy = (float)(py-1)*rs, cx = (float)(px-1)*rs;
        int y0 = (int)cy; if (y0>15) y0=15; int y1 = (y0+1<16)?y0+1:15; float fy = cy-(float)y0;
        int x0 = (int)cx; if (x0>15) x0=15; int x1 = (x0+1<16)?x0+1:15; float fx = cx-(float)x0;
        v = (1.f-fy)*((1.f-fx)*sIn[ch][y0*16+x0] + fx*sIn[ch][y0*16+x1])
          +       fy*((1.f-fx)*sIn[ch][y1*16+x0] + fx*sIn[ch][y1*16+x1]);
      }
      o[(size_t)i*1024] = f2bf(v);
    }
  }
}

// ---------------------------------------------------------------------------
// 3) conv3x3 as bf16 MFMA GEMM with LDS double-buffer + global_load_lds.
__global__ __launch_bounds__(256) void k_conv_mfma(float* __restrict__ wsf){
  int bx = blockIdx.x;
  int scale, bt, cot, post, S, lgS;
  if (bx < 256)      { scale=2; S=32; lgS=5; bt=bx>>5; cot=(bx>>4)&1; post=bx&15; }
  else if (bx < 320) { int r=bx-256; scale=1; S=16; lgS=4; bt=r>>3; cot=(r>>2)&1; post=r&3; }
  else               { int r=bx-320; scale=0; S=8;  lgS=3; bt=r>>1; cot=r&1; post=0; }
  const int Sp = S+2, N = S*S;
  const unsigned short* WbS = (const unsigned short*)(wsf + OFF_WB) + (size_t)scale*2359296;
  size_t poff = scale==0?OFF_P8: scale==1?OFF_P16:OFF_P32;
  const unsigned short* Pb = (const unsigned short*)(wsf + poff) + (size_t)bt*Sp*Sp*1024;
  size_t obase = (scale==2) ? (bt>=4?OFF_TF32:OFF_SF32)
               : (scale==1) ? (bt>=4?OFF_TF16:OFF_SF16)
                            : (bt>=4?OFF_TF8 :OFF_SF8);
  float* outp = wsf + obase + (size_t)(bt&3)*256*N;

  const int t = threadIdx.x, l = t&63, w = t>>6, wm = w&1, wn = w>>1;
  const int nc_base = cot*8;
  const int pos0 = post*64;

  __shared__ __align__(16) unsigned short Ab[2][8192];   // 32 KB
  __shared__ __align__(16) unsigned short Bb[2][4096];   // 16 KB

  f32x4 acc[4][2];
  #pragma unroll
  for (int i=0;i<4;i++)
    #pragma unroll
    for (int j=0;j<2;j++) acc[i][j] = (f32x4){0.f,0.f,0.f,0.f};

  auto STAGE = [&](int buf, int it){
    int tap = it>>4, kq = it&15;
    int dy = tap/3, dx = tap - dy*3;
    #pragma unroll
    for (int j=0;j<4;++j){                       // A chunks: this wave's 4 of 16
      int c = w + j*4;
      int kc = c>>3, nc = c&7;
      const unsigned short* src =
        WbS + ((((size_t)tap*32 + kq*2 + kc)*16 + nc_base + nc)*64 + l)*8;
      gl_lds16(src, &Ab[buf][c*512]);
    }
    #pragma unroll
    for (int j=0;j<2;++j){                       // B chunks: this wave's 2 of 8
      int c = w + j*4;
      int kc = c>>2, np = c&3;
      int pos = pos0 + np*16 + (l&15);
      int y = pos>>lgS, x = pos&(S-1);
      int row = (y+dy)*Sp + (x+dx);
      int ci = kq*64 + kc*32 + ((l>>4)<<3);
      gl_lds16(Pb + (size_t)row*1024 + ci, &Bb[buf][c*512]);
    }
  };

  STAGE(0, 0);
  __syncthreads();
  int buf = 0;
  #pragma unroll 1
  for (int it=0; it<144; ++it){
    if (it+1 < 144) STAGE(buf^1, it+1);
    #pragma unroll
    for (int kc=0; kc<2; ++kc){
      short8v a0 = *(const short8v*)&Ab[buf][((kc*8 + wm*4 + 0)*64 + l)*8];
      short8v a1 = *(const short8v*)&Ab[buf][((kc*8 + wm*4 + 1)*64 + l)*8];
      short8v a2 = *(const short8v*)&Ab[buf][((kc*8 + wm*4 + 2)*64 + l)*8];
      short8v a3 = *(const short8v*)&Ab[buf][((kc*8 + wm*4 + 3)*64 + l)*8];
      short8v b0 = *(const short8v*)&Bb[buf][((kc*4 + wn*2 + 0)*64 + l)*8];
      short8v b1 = *(const short8v*)&Bb[buf][((kc*4 + wn*2 + 1)*64 + l)*8];
      acc[0][0] = __builtin_amdgcn_mfma_f32_16x16x32_bf16(a0, b0, acc[0][0], 0,0,0);
      acc[1][0] = __builtin_amdgcn_mfma_f32_16x16x32_bf16(a1, b0, acc[1][0], 0,0,0);
      acc[2][0] = __builtin_amdgcn_mfma_f32_16x16x32_bf16(a2, b0, acc[2][0], 0,0,0);
      acc[3][0] = __builtin_amdgcn_mfma_f32_16x16x32_bf16(a3, b0, acc[3][0], 0,0,0);
      acc[0][1] = __builtin_amdgcn_mfma_f32_16x16x32_bf16(a0, b1, acc[0][1], 0,0,0);
      acc[1][1] = __builtin_amdgcn_mfma_f32_16x16x32_bf16(a1, b1, acc[1][1], 0,0,0);
      acc[2][1] = __builtin_amdgcn_mfma_f32_16x16x32_bf16(a2, b1, acc[2][1], 0,0,0);
      acc[3][1] = __builtin_amdgcn_mfma_f32_16x16x32_bf16(a3, b1, acc[3][1], 0,0,0);
    }
    __syncthreads();
    buf ^= 1;
  }

  const int r0 = (l>>4)*4, cl = l&15;
  float* ob = outp + (size_t)(cot*128 + wm*64)*N + pos0 + wn*32 + cl;
  #pragma unroll
  for (int mf=0; mf<4; ++mf)
    #pragma unroll
    for (int nf=0; nf<2; ++nf){
      float* op = ob + (size_t)(mf*16 + r0)*N + nf*16;
      #pragma unroll
      for (int i=0;i<4;++i) op[(size_t)i*N] = acc[mf][nf][i];
    }
}

// ---------------------------------------------------------------------------
// 4) inverse feature norms per position
__global__ void k_invnorm(float* __restrict__ ws){
  int id = blockIdx.x*256 + threadIdx.x;
  if (id >= 10752) return;
  int tsr = id / 5376, r = id % 5376;
  int P, q; size_t fbase;
  if (r < 256)     { P=64;   q=r;      fbase = tsr ? OFF_TF8  : OFF_SF8; }
  else if (r<1280) { P=256;  q=r-256;  fbase = tsr ? OFF_TF16 : OFF_SF16; }
  else             { P=1024; q=r-1280; fbase = tsr ? OFF_TF32 : OFF_SF32; }
  int b = q / P, pos = q % P;
  const float* f = ws + fbase + (size_t)b*256*P + pos;
  float s = 0.f;
  for (int ch=0; ch<256; ch++){ float v = f[(size_t)ch*P]; s = fmaf(v,v,s); }
  ws[(tsr ? OFF_INVT : OFF_INVS) + r] = 1.f/sqrtf(s);
}

// ---------------------------------------------------------------------------
// 5) all 9 normalized-correlation GEMMs (f32), 64x64 tiles, K=256
__global__ __launch_bounds__(256) void k_corr(float* __restrict__ ws){
  int bx = blockIdx.x;
  int p = (bx>=4)+(bx>=20)+(bx>=84)+(bx>=100)+(bx>=164)+(bx>=420)+(bx>=484)+(bx>=740);
  int si = p/3, ti = p%3;
  int M = SSARR[si]*SSARR[si], N = SSARR[ti]*SSARR[ti];
  int ntN = N >> 6;
  int rem = bx - PAIR_START[p];
  int b = rem & 3; rem >>= 2;
  int nt = rem % ntN, mt = rem / ntN;
  int m0 = mt*64, n0 = nt*64;
  const float* A  = ws + (si==0?OFF_SF8: si==1?OFF_SF16:OFF_SF32) + (size_t)b*256*M;
  const float* Bp = ws + (ti==0?OFF_TF8: ti==1?OFF_TF16:OFF_TF32) + (size_t)b*256*N;
  const float* iS = ws + OFF_INVS + (si==0?0: si==1?256:1280) + (size_t)b*M;
  const float* iT = ws + OFF_INVT + (ti==0?0: ti==1?256:1280) + (size_t)b*N;
  float* C = ws + PAIR_OFF[p] + (size_t)b*M*N;
  __shared__ __align__(16) float As[16][64];
  __shared__ __align__(16) float Bs[16][64];
  int t = threadIdx.x, tm = t>>4, tn = t&15;
  float acc[4][4] = {};
  #pragma unroll 1
  for (int k0=0; k0<256; k0+=16){
    __syncthreads();
    #pragma unroll
    for (int i=0;i<4;i++){
      int idx = t + i*256; int k = idx>>6, m = idx&63;
      As[k][m] = A [(size_t)(k0+k)*M + m0+m];
      Bs[k][m] = Bp[(size_t)(k0+k)*N + n0+m];
    }
    __syncthreads();
    #pragma unroll
    for (int k=0;k<16;k++){
      float4 av = *reinterpret_cast<const float4*>(&As[k][tm*4]);
      float4 bv = *reinterpret_cast<const float4*>(&Bs[k][tn*4]);
      float a4[4]={av.x,av.y,av.z,av.w}, b4[4]={bv.x,bv.y,bv.z,bv.w};
      #pragma unroll
      for (int i=0;i<4;i++)
        #pragma unroll
        for (int j=0;j<4;j++)
          acc[i][j] = fmaf(a4[i], b4[j], acc[i][j]);
    }
  }
  #pragma unroll
  for (int i=0;i<4;i++){
    float sv = iS[m0+tm*4+i];
    #pragma unroll
    for (int j=0;j<4;j++)
      C[(size_t)(m0+tm*4+i)*N + n0+tn*4+j] = acc[i][j]*sv*iT[n0+tn*4+j];
  }
}

// ---------------------------------------------------------------------------
DEVFN void cw_coord(int i, int n, int OH, int& i0, int& i1, float& f){
  float c = (float)(i*(n-1))/(float)(OH-1);
  int a = (int)c; if (a > n-1) a = n-1;
  i0 = a; i1 = (a+1 < n) ? a+1 : n-1; f = c - (float)a;
}

// 6) interp_pairs v2: block = (p,b,oy,ox); stage 4 corner (y,x) planes in LDS,
//    gather bilinear from LDS, +relu.
__global__ __launch_bounds__(256) void k_interp_pairs(float* __restrict__ ws){
  int bx = blockIdx.x;
  int p = bx >> 10;
  int bl = bx & 1023;                    // [b:2][oy:4][ox:4]
  int b = bl >> 8, oy = (bl >> 4) & 15, ox = bl & 15;
  int si = p/3, ti = p%3;
  int h1 = SSARR[si], t1 = SSARR[ti], t12 = t1*t1;
  int y0,y1,x0,x1; float fy,fx;
  cw_coord(oy,h1,16,y0,y1,fy); cw_coord(ox,h1,16,x0,x1,fx);
  const float* in = ws + PAIR_OFF[p] + (size_t)b*h1*h1*t12;
  __shared__ float sPl[4][1024];
  const int t = threadIdx.x;
  {
    const float* pl0 = in + (size_t)(y0*h1+x0)*t12;
    const float* pl1 = in + (size_t)(y0*h1+x1)*t12;
    const float* pl2 = in + (size_t)(y1*h1+x0)*t12;
    const float* pl3 = in + (size_t)(y1*h1+x1)*t12;
    for (int i=t; i<t12; i+=256){
      sPl[0][i] = pl0[i]; sPl[1][i] = pl1[i];
      sPl[2][i] = pl2[i]; sPl[3][i] = pl3[i];
    }
  }
  __syncthreads();
  int px = t & 15, py = t >> 4;
  int u0,u1,v0,v1; float fu,fv;
  cw_coord(py,t1,16,u0,u1,fu); cw_coord(px,t1,16,v0,v1,fv);
  float wY[2]={1.f-fy,fy}, wX[2]={1.f-fx,fx};
  float wU[2]={1.f-fu,fu}, wV[2]={1.f-fv,fv};
  int us[2]={u0,u1}, vs[2]={v0,v1};
  float s = 0.f;
  #pragma unroll
  for (int qa=0; qa<2; qa++)
    #pragma unroll
    for (int qc=0; qc<2; qc++){
      float wyx = wY[qa]*wX[qc];
      const float* base = sPl[qa*2+qc];
      #pragma unroll
      for (int qu=0; qu<2; qu++)
        #pragma unroll
        for (int qv=0; qv<2; qv++)
          s += wyx*wU[qu]*wV[qv]*base[us[qu]*t1 + vs[qv]];
    }
  ws[OFF_CORR6 + ((size_t)b*9 + p)*65536 + ((size_t)(oy*16+ox)<<8) + t] = fmaxf(s, 0.f);
}

// ---------------------------------------------------------------------------
// 7) chm6d v3 (R4): wave-per-batch, stride-26 LDS, (a,c)-parity split
__global__ __launch_bounds__(256) void k_chm6d(float* __restrict__ ws,
                                               const float* __restrict__ k6rp){
  const int bx = blockIdx.x;
  const int g = bx >> 8, sy = (bx>>4)&15, sx = bx&15;
  const int t = threadIdx.x;
  const int bq = t>>6, l = t&63, ty = l>>2, tx = l&3;
  __shared__ float sP[4][9][20][26];
  float* myP = &sP[bq][0][0][0];
  for (int i = l; i < 9*20*26; i += 64){
    int r = i % 520, rr = r/26, cc = r%26;
    if (rr<2 || rr>17 || cc<4 || cc>19) myP[i] = 0.f;
  }
  f32x4 acc[9];
  #pragma unroll
  for (int i=0;i<9;i++) acc[i] = (f32x4){0.f,0.f,0.f,0.f};
  const float* c6 = ws + OFF_CORR6 + (size_t)bq*9*65536 + l*4;
  #pragma unroll 1
  for (int a=0; a<5; a++){
    int Y = sy+a-2; if (Y<0 || Y>15) continue;
    #pragma unroll 1
    for (int c=0; c<5; c++){
      if (((a*5+c)&1) != g) continue;
      int X = sx+c-2; if (X<0 || X>15) continue;
      #pragma unroll
      for (int pr=0; pr<9; pr++){
        float4 v = *reinterpret_cast<const float4*>(c6 + (size_t)pr*65536 + (size_t)(Y*16+X)*256);
        float* wp = myP + (pr*20 + 2 + (l>>2))*26 + 4 + 4*(l&3);
        *reinterpret_cast<float2*>(wp)   = make_float2(v.x, v.y);
        *reinterpret_cast<float2*>(wp+2) = make_float2(v.z, v.w);
      }
      const float* wt = k6rp + (size_t)(a*5+c)*5*48;
      #pragma unroll 1
      for (int d=0; d<5; d++){
        float4 wv[12];
        const float4* wt4 = reinterpret_cast<const float4*>(wt + d*48);
        #pragma unroll
        for (int i=0;i<12;i++) wv[i] = wt4[i];
        #pragma unroll
        for (int pr=0; pr<9; pr++){
          const int pi = pr/3, pj = pr%3;
          const float* rp = myP + (pr*20 + ty + d)*26 + 4*tx + 2;
          float r8[8];
          #pragma unroll
          for (int i=0;i<4;i++){
            float2 u = *reinterpret_cast<const float2*>(rp + 2*i);
            r8[2*i] = u.x; r8[2*i+1] = u.y;
          }
          #pragma unroll
          for (int e=0;e<5;e++){
            #pragma unroll
            for (int ki=0; ki<3; ki++){
              const int sio = pi-ki+1; if (sio<0 || sio>2) continue;
              #pragma unroll
              for (int kj=0; kj<3; kj++){
                const int sjo = pj-kj+1; if (sjo<0 || sjo>2) continue;
                const int wi = e*9 + ki*3 + kj;
                const float w = ((const float*)&wv[wi>>2])[wi&3];
                #pragma unroll
                for (int xi=0; xi<4; xi++)
                  acc[sio*3+sjo][xi] = fmaf(r8[e+xi], w, acc[sio*3+sjo][xi]);
              }
            }
          }
        }
      }
    }
  }
  float* po = ws + OFF_PART + ((size_t)(g*4+bq)*9)*65536
            + (size_t)(sy*16+sx)*256 + ty*16 + tx*4;
  #pragma unroll
  for (int so=0; so<9; so++)
    *reinterpret_cast<f32x4*>(po + (size_t)so*65536) = acc[so];
}

// 7b) combine partials + sigmoid + max over 9 so
__global__ void k_sigmax(float* __restrict__ ws){
  int id = blockIdx.x*256 + threadIdx.x;        // 4*65536
  int b = id >> 16, pos = id & 65535;
  const float* p0 = ws + OFF_PART + (size_t)b*9*65536 + pos;
  const float* p1 = p0 + (size_t)4*9*65536;
  float m = -1e30f;
  #pragma unroll
  for (int so=0; so<9; so++)
    m = fmaxf(m, p0[(size_t)so*65536] + p1[(size_t)so*65536]);
  ws[OFF_MAXED + (size_t)b*65536 + pos] = 1.f/(1.f + expf(-m));
}

// ---------------------------------------------------------------------------
// 8) interpolate4d 16^4 -> 32^4
__global__ void k_interp32(float* __restrict__ ws){
  int id = blockIdx.x*256 + threadIdx.x;
  int px = id & 31, py = (id>>5)&31, ox = (id>>10)&31, oy = (id>>15)&31, b = id>>20;
  int y0,y1,x0,x1,u0,u1,v0,v1; float fy,fx,fu,fv;
  cw_coord(oy,16,32,y0,y1,fy); cw_coord(ox,16,32,x0,x1,fx);
  cw_coord(py,16,32,u0,u1,fu); cw_coord(px,16,32,v0,v1,fv);
  const float* in = ws + OFF_MAXED + (size_t)b*65536;
  int ys[2]={y0,y1}, xs[2]={x0,x1}, us[2]={u0,u1}, vs[2]={v0,v1};
  float wy[2]={1.f-fy,fy}, wx[2]={1.f-fx,fx}, wu[2]={1.f-fu,fu}, wv[2]={1.f-fv,fv};
  float s = 0.f;
  #pragma unroll
  for (int ia=0; ia<2; ia++)
    #pragma unroll
    for (int ic=0; ic<2; ic++){
      float wyx = wy[ia]*wx[ic];
      const float* base = in + ((size_t)ys[ia]*16 + xs[ic])*256;
      #pragma unroll
      for (int id_=0; id_<2; id_++)
        #pragma unroll
        for (int ie=0; ie<2; ie++)
          s += wyx*wu[id_]*wv[ie]*base[(size_t)us[id_]*16 + vs[ie]];
    }
  ws[OFF_INT32 + id] = s;
}

// ---------------------------------------------------------------------------
// 9) fast4d v2: stride-48 LDS rows (2-way-only aliasing), one coalesced
//    float4 stage per thread per (a,c), unrolled taps. + bias + softplus.
__global__ __launch_bounds__(256) void k_fast4d(float* __restrict__ ws,
                                                const float* __restrict__ k4,
                                                const float* __restrict__ b4,
                                                float* __restrict__ out){
  const int b = blockIdx.y;
  const int sy = blockIdx.x >> 5, sx = blockIdx.x & 31;
  const int t = threadIdx.x;
  const int y = t >> 3, x0 = (t & 7) << 2;
  __shared__ float sK[625];
  __shared__ __align__(16) float sQ[36*48];
  for (int i=t; i<625; i+=256) sK[i] = k4[i];
  for (int i=t; i<1728; i+=256) sQ[i] = 0.f;     // borders stay zero forever
  float acc[4] = {0.f,0.f,0.f,0.f};
  const float* in = ws + OFF_INT32 + (size_t)b*1048576;
  // staging addresses (no div/mod): thread t moves float4 at plane + 4t
  const int srow = t >> 3, scol4 = (t & 7) << 2;
  float* wp = &sQ[(2+srow)*48 + 2 + scol4];
  #pragma unroll 1
  for (int a=0; a<5; a++){
    int Y = sy+a-2; if (Y<0 || Y>31) continue;
    #pragma unroll 1
    for (int c=0; c<5; c++){
      int X = sx+c-2; if (X<0 || X>31) continue;
      __syncthreads();                            // prior reads done
      float4 v = *reinterpret_cast<const float4*>(in + (size_t)(Y*32+X)*1024 + t*4);
      *reinterpret_cast<float2*>(wp)   = make_float2(v.x, v.y);
      *reinterpret_cast<float2*>(wp+2) = make_float2(v.z, v.w);
      __syncthreads();                            // tile published
      const float* kb = &sK[a*125 + c*25];
      #pragma unroll
      for (int d=0; d<5; d++){
        const float* row = &sQ[(y+d)*48 + x0];
        float4 q0 = *reinterpret_cast<const float4*>(row);
        float4 q1 = *reinterpret_cast<const float4*>(row+4);
        float r8[8] = {q0.x,q0.y,q0.z,q0.w,q1.x,q1.y,q1.z,q1.w};
        #pragma unroll
        for (int e=0; e<5; e++){
          float wv = kb[d*5+e];
          #pragma unroll
          for (int i=0;i<4;i++) acc[i] = fmaf(r8[i+e], wv, acc[i]);
        }
      }
    }
  }
  float bias = b4[0];
  #pragma unroll
  for (int i=0;i<4;i++){
    float xv = acc[i] + bias;
    float sp = fmaxf(xv,0.f) + log1pf(expf(-fabsf(xv)));
    out[((size_t)b*1024 + blockIdx.x)*1024 + y*32 + x0 + i] = sp;
  }
}

// ---------------------------------------------------------------------------
// 10-12) mutual_nn_filter
__global__ void k_rowmax(const float* __restrict__ cm, float* __restrict__ ws){
  int row = blockIdx.x;
  const float* r = cm + (size_t)row*1024;
  int t = threadIdx.x;
  float m = -1e30f;
  for (int i=t; i<1024; i+=256) m = fmaxf(m, r[i]);
  __shared__ float red[256];
  red[t] = m; __syncthreads();
  for (int off=128; off; off>>=1){
    if (t < off) red[t] = fmaxf(red[t], red[t+off]);
    __syncthreads();
  }
  if (!t) ws[OFF_SMAX + row] = red[0];
}

__global__ void k_colmax_p(const float* __restrict__ cm, float* __restrict__ ws){
  int b = blockIdx.x >> 5, rg = (blockIdx.x >> 2) & 7, cg = blockIdx.x & 3;
  int c = cg*256 + threadIdx.x;
  const float* base = cm + (size_t)b*1048576 + (size_t)rg*131072 + c;
  float m = -1e30f;
  #pragma unroll 4
  for (int r=0; r<128; r++) m = fmaxf(m, base[(size_t)r*1024]);
  ws[OFF_CMAXP + (size_t)(b*8+rg)*1024 + c] = m;
}

__global__ void k_colmax_r(float* __restrict__ ws){
  int id = blockIdx.x*256 + threadIdx.x;         // 4096
  int b = id >> 10, c = id & 1023;
  float m = -1e30f;
  #pragma unroll
  for (int rg=0; rg<8; rg++)
    m = fmaxf(m, ws[OFF_CMAXP + (size_t)(b*8+rg)*1024 + c]);
  ws[OFF_TMAX + id] = m;
}

__global__ void k_mutual(float* __restrict__ cm, const float* __restrict__ ws){
  int id = blockIdx.x*256 + threadIdx.x;
  int b = id >> 20, r = (id>>10)&1023, c = id&1023;
  float v  = cm[id];
  float sm = ws[OFF_SMAX + (b<<10) + r];
  float tm = ws[OFF_TMAX + (b<<10) + c];
  sm = (sm==0.f) ? 1e-30f : sm;
  tm = (tm==0.f) ? 1e-30f : tm;
  cm[id] = v * (v/sm) * (v/tm);
}

// ---------------------------------------------------------------------------
extern "C" void kernel_launch(void* const* d_in, const int* in_sizes, int n_in,
                              void* d_out, int out_size, void* d_ws, size_t ws_size,
                              hipStream_t stream){
  const float* src = (const float*)d_in[0];
  const float* trg = (const float*)d_in[1];
  const float* w0  = (const float*)d_in[2];
  const float* w1  = (const float*)d_in[3];
  const float* w2  = (const float*)d_in[4];
  const float* k6  = (const float*)d_in[5];
  const float* k4  = (const float*)d_in[6];
  const float* b4  = (const float*)d_in[7];
  float* ws  = (float*)d_ws;    // needs WS_FLOATS*4 = ~60.7 MB
  float* out = (float*)d_out;
  (void)in_sizes; (void)n_in; (void)out_size; (void)ws_size;

  k_wpack       <<<3456,  256, 0, stream>>>(w0, w1, w2, ws);
  k_k6rp        <<<24,    256, 0, stream>>>(k6, ws);
  k_inpack      <<<512,   256, 0, stream>>>(src, trg, ws);
  k_conv_mfma   <<<336,   256, 0, stream>>>(ws);
  k_invnorm     <<<42,    256, 0, stream>>>(ws);
  k_corr        <<<1764,  256, 0, stream>>>(ws);
  k_interp_pairs<<<9216,  256, 0, stream>>>(ws);
  k_chm6d       <<<512,   256, 0, stream>>>(ws, ws + OFF_K6R);
  k_sigmax      <<<1024,  256, 0, stream>>>(ws);
  k_interp32    <<<16384, 256, 0, stream>>>(ws);
  k_fast4d      <<<dim3(1024,4), 256, 0, stream>>>(ws, k4, b4, out);
  k_rowmax      <<<4096,  256, 0, stream>>>(out, ws);
  k_colmax_p    <<<128,   256, 0, stream>>>(out, ws);
  k_colmax_r    <<<16,    256, 0, stream>>>(ws);
  k_mutual      <<<16384, 256, 0, stream>>>(out, ws);
}

// Round 7
// 595.552 us; speedup vs baseline: 3.6060x; 1.1437x over previous
//
#include <hip/hip_runtime.h>
#include <cstdint>
#include <cstddef>

// ============================================================================
// CHMLearner forward. R7: fast4d v3 (4 sx-outputs/block, shared d-row reads,
// double-buffered plane staging w/ reg-prefetch, scalar weights, 1 barrier per
// plane). Conv MFMA pipeline (R5), chm6d v3 (R4), interp_pairs v2 (R6) kept.
// ============================================================================

#define DEVFN __device__ __forceinline__

typedef __attribute__((ext_vector_type(8))) short short8v;
typedef __attribute__((ext_vector_type(4))) float f32x4;
typedef unsigned int u32;

DEVFN void gl_lds16(const void* g, void* l){
  __builtin_amdgcn_global_load_lds(
      (const __attribute__((address_space(1))) u32*)g,
      (__attribute__((address_space(3))) u32*)l, 16, 0, 0);
}

// workspace layout (float units). Total ~60.7 MB
constexpr size_t OFF_WB    = 0;           // bf16 packed weights, 3*2,359,296 bf16
constexpr size_t OFF_P8    = 3538944;     // bf16 padded ch-last features
constexpr size_t OFF_P16   = 3948544;
constexpr size_t OFF_P32   = 5275648;
constexpr size_t OFF_SF8   = 10010624;    // conv outputs f32 [b][256][S*S]
constexpr size_t OFF_TF8   = 10076160;
constexpr size_t OFF_SF16  = 10141696;
constexpr size_t OFF_TF16  = 10403840;
constexpr size_t OFF_SF32  = 10665984;
constexpr size_t OFF_TF32  = 11714560;
constexpr size_t OFF_INVS  = 12763136;
constexpr size_t OFF_INVT  = 12768512;
constexpr size_t OFF_SMAX  = 12773888;
constexpr size_t OFF_TMAX  = 12777984;
constexpr size_t OFF_CORR6 = 12782080;    // [4][9][16^4]
constexpr size_t OFF_K6R   = OFF_CORR6 + 2359296;   // 6000 repacked 6d weights
constexpr size_t OFF_CMAXP = OFF_K6R + 6016;        // 32768 colmax partials
constexpr size_t WS_FLOATS = OFF_CMAXP + 32768;

// aliases into dead regions:
__device__ constexpr size_t PAIR_OFF[9] = {   // raw per-pair corr [4][ss^2][ts^2]
  OFF_WB + 0,       OFF_WB + 16384,   OFF_WB + 81920,
  OFF_WB + 344064,  OFF_WB + 409600,  OFF_WB + 671744,
  OFF_WB + 1720320, OFF_WB + 1982464, OFF_WB + 3031040 };
constexpr size_t OFF_MAXED = OFF_WB;              // [4][16^4] after sigmax
constexpr size_t OFF_PART  = OFF_P8;              // [2g][4b][9so][16^4] chm6d partials
constexpr size_t OFF_INT32 = OFF_WB + 262144;     // [4][32^4] upsampled (after sigmax)

__device__ constexpr int SSARR[3] = {8, 16, 32};
__device__ constexpr int PAIR_START[9] = {0,4,20,84,100,164,420,484,740}; // 1764

DEVFN unsigned short f2bf(float f){
  unsigned int u = __float_as_uint(f);
  return (unsigned short)((u + 0x7fffu + ((u >> 16) & 1u)) >> 16);
}

// ---------------------------------------------------------------------------
// 1) pack conv weights into MFMA A-fragment order (bf16)
__global__ void k_wpack(const float* __restrict__ w0, const float* __restrict__ w1,
                        const float* __restrict__ w2, float* __restrict__ wsf){
  int gid = blockIdx.x*256 + threadIdx.x;        // 884,736 exact
  int scale = gid / 294912, r = gid % 294912;
  int tap = r >> 15, kc = (r>>10)&31, nc = (r>>6)&15, l = r&63;
  const float* w = (scale==0) ? w0 : (scale==1 ? w1 : w2);
  int co = nc*16 + (l&15);
  int ci0 = kc*32 + ((l>>4)&3)*8;
  unsigned short* o = (unsigned short*)(wsf + OFF_WB) + (size_t)gid*8;
  #pragma unroll
  for (int i=0;i<8;i++)
    o[i] = f2bf(w[((size_t)co*1024 + ci0 + i)*9 + tap]);
}

// 1b) repack chm6d kernel: K6R[(a*5+c)*5+d][48: e*9+ki*3+kj]
__global__ void k_k6rp(const float* __restrict__ k6, float* __restrict__ ws){
  int o = blockIdx.x*256 + threadIdx.x;
  if (o >= 6000) return;
  int tap = o/48, r = o%48;
  float v = 0.f;
  if (r < 45){
    int e = r/9, kikj = r%9;
    int d = tap%5, ac = tap/5, a = ac/5, c = ac%5;
    v = k6[(((kikj*5 + a)*5 + c)*5 + d)*5 + e];
  }
  ws[OFF_K6R + o] = v;
}

// ---------------------------------------------------------------------------
// 2) inpack: stage 16 channels' 16x16 planes in LDS; emit all 3 scales
__global__ __launch_bounds__(256) void k_inpack(const float* __restrict__ src,
                                                const float* __restrict__ trg,
                                                float* __restrict__ wsf){
  int bt = blockIdx.x >> 6, cg = blockIdx.x & 63;
  int chbase = cg*16;
  int t = threadIdx.x;
  __shared__ float sIn[16][257];
  const float* gin = ((bt>=4)? trg : src) + ((size_t)(bt&3)*1024 + chbase)*256;
  #pragma unroll
  for (int i=0;i<16;i++){
    int idx = t + i*256; int ch = idx>>8, pos = idx&255;
    sIn[ch][pos] = gin[(size_t)ch*256 + pos];
  }
  __syncthreads();
  int ch = t & 15, pw = t >> 4;
  #pragma unroll 1
  for (int s=0; s<3; s++){
    int S = SSARR[s], Sp = S+2, Sp2 = Sp*Sp;
    size_t poff = (s==0)?OFF_P8 : (s==1)?OFF_P16 : OFF_P32;
    unsigned short* o = (unsigned short*)(wsf + poff) + (size_t)bt*Sp2*1024 + chbase + ch;
    float rs = 15.f/(float)(S-1);
    for (int i = pw; i < Sp2; i += 16){
      int py = i / Sp, px = i % Sp;
      float v = 0.f;
      if (py>0 && py<Sp-1 && px>0 && px<Sp-1){
        float cy = (float)(py-1)*rs, cx = (float)(px-1)*rs;
        int y0 = (int)cy; if (y0>15) y0=15; int y1 = (y0+1<16)?y0+1:15; float fy = cy-(float)y0;
        int x0 = (int)cx; if (x0>15) x0=15; int x1 = (x0+1<16)?x0+1:15; float fx = cx-(float)x0;
        v = (1.f-fy)*((1.f-fx)*sIn[ch][y0*16+x0] + fx*sIn[ch][y0*16+x1])
          +       fy*((1.f-fx)*sIn[ch][y1*16+x0] + fx*sIn[ch][y1*16+x1]);
      }
      o[(size_t)i*1024] = f2bf(v);
    }
  }
}

// ---------------------------------------------------------------------------
// 3) conv3x3 as bf16 MFMA GEMM with LDS double-buffer + global_load_lds.
__global__ __launch_bounds__(256) void k_conv_mfma(float* __restrict__ wsf){
  int bx = blockIdx.x;
  int scale, bt, cot, post, S, lgS;
  if (bx < 256)      { scale=2; S=32; lgS=5; bt=bx>>5; cot=(bx>>4)&1; post=bx&15; }
  else if (bx < 320) { int r=bx-256; scale=1; S=16; lgS=4; bt=r>>3; cot=(r>>2)&1; post=r&3; }
  else               { int r=bx-320; scale=0; S=8;  lgS=3; bt=r>>1; cot=r&1; post=0; }
  const int Sp = S+2, N = S*S;
  const unsigned short* WbS = (const unsigned short*)(wsf + OFF_WB) + (size_t)scale*2359296;
  size_t poff = scale==0?OFF_P8: scale==1?OFF_P16:OFF_P32;
  const unsigned short* Pb = (const unsigned short*)(wsf + poff) + (size_t)bt*Sp*Sp*1024;
  size_t obase = (scale==2) ? (bt>=4?OFF_TF32:OFF_SF32)
               : (scale==1) ? (bt>=4?OFF_TF16:OFF_SF16)
                            : (bt>=4?OFF_TF8 :OFF_SF8);
  float* outp = wsf + obase + (size_t)(bt&3)*256*N;

  const int t = threadIdx.x, l = t&63, w = t>>6, wm = w&1, wn = w>>1;
  const int nc_base = cot*8;
  const int pos0 = post*64;

  __shared__ __align__(16) unsigned short Ab[2][8192];   // 32 KB
  __shared__ __align__(16) unsigned short Bb[2][4096];   // 16 KB

  f32x4 acc[4][2];
  #pragma unroll
  for (int i=0;i<4;i++)
    #pragma unroll
    for (int j=0;j<2;j++) acc[i][j] = (f32x4){0.f,0.f,0.f,0.f};

  auto STAGE = [&](int buf, int it){
    int tap = it>>4, kq = it&15;
    int dy = tap/3, dx = tap - dy*3;
    #pragma unroll
    for (int j=0;j<4;++j){                       // A chunks: this wave's 4 of 16
      int c = w + j*4;
      int kc = c>>3, nc = c&7;
      const unsigned short* src =
        WbS + ((((size_t)tap*32 + kq*2 + kc)*16 + nc_base + nc)*64 + l)*8;
      gl_lds16(src, &Ab[buf][c*512]);
    }
    #pragma unroll
    for (int j=0;j<2;++j){                       // B chunks: this wave's 2 of 8
      int c = w + j*4;
      int kc = c>>2, np = c&3;
      int pos = pos0 + np*16 + (l&15);
      int y = pos>>lgS, x = pos&(S-1);
      int row = (y+dy)*Sp + (x+dx);
      int ci = kq*64 + kc*32 + ((l>>4)<<3);
      gl_lds16(Pb + (size_t)row*1024 + ci, &Bb[buf][c*512]);
    }
  };

  STAGE(0, 0);
  __syncthreads();
  int buf = 0;
  #pragma unroll 1
  for (int it=0; it<144; ++it){
    if (it+1 < 144) STAGE(buf^1, it+1);
    #pragma unroll
    for (int kc=0; kc<2; ++kc){
      short8v a0 = *(const short8v*)&Ab[buf][((kc*8 + wm*4 + 0)*64 + l)*8];
      short8v a1 = *(const short8v*)&Ab[buf][((kc*8 + wm*4 + 1)*64 + l)*8];
      short8v a2 = *(const short8v*)&Ab[buf][((kc*8 + wm*4 + 2)*64 + l)*8];
      short8v a3 = *(const short8v*)&Ab[buf][((kc*8 + wm*4 + 3)*64 + l)*8];
      short8v b0 = *(const short8v*)&Bb[buf][((kc*4 + wn*2 + 0)*64 + l)*8];
      short8v b1 = *(const short8v*)&Bb[buf][((kc*4 + wn*2 + 1)*64 + l)*8];
      acc[0][0] = __builtin_amdgcn_mfma_f32_16x16x32_bf16(a0, b0, acc[0][0], 0,0,0);
      acc[1][0] = __builtin_amdgcn_mfma_f32_16x16x32_bf16(a1, b0, acc[1][0], 0,0,0);
      acc[2][0] = __builtin_amdgcn_mfma_f32_16x16x32_bf16(a2, b0, acc[2][0], 0,0,0);
      acc[3][0] = __builtin_amdgcn_mfma_f32_16x16x32_bf16(a3, b0, acc[3][0], 0,0,0);
      acc[0][1] = __builtin_amdgcn_mfma_f32_16x16x32_bf16(a0, b1, acc[0][1], 0,0,0);
      acc[1][1] = __builtin_amdgcn_mfma_f32_16x16x32_bf16(a1, b1, acc[1][1], 0,0,0);
      acc[2][1] = __builtin_amdgcn_mfma_f32_16x16x32_bf16(a2, b1, acc[2][1], 0,0,0);
      acc[3][1] = __builtin_amdgcn_mfma_f32_16x16x32_bf16(a3, b1, acc[3][1], 0,0,0);
    }
    __syncthreads();
    buf ^= 1;
  }

  const int r0 = (l>>4)*4, cl = l&15;
  float* ob = outp + (size_t)(cot*128 + wm*64)*N + pos0 + wn*32 + cl;
  #pragma unroll
  for (int mf=0; mf<4; ++mf)
    #pragma unroll
    for (int nf=0; nf<2; ++nf){
      float* op = ob + (size_t)(mf*16 + r0)*N + nf*16;
      #pragma unroll
      for (int i=0;i<4;++i) op[(size_t)i*N] = acc[mf][nf][i];
    }
}

// ---------------------------------------------------------------------------
// 4) inverse feature norms per position
__global__ void k_invnorm(float* __restrict__ ws){
  int id = blockIdx.x*256 + threadIdx.x;
  if (id >= 10752) return;
  int tsr = id / 5376, r = id % 5376;
  int P, q; size_t fbase;
  if (r < 256)     { P=64;   q=r;      fbase = tsr ? OFF_TF8  : OFF_SF8; }
  else if (r<1280) { P=256;  q=r-256;  fbase = tsr ? OFF_TF16 : OFF_SF16; }
  else             { P=1024; q=r-1280; fbase = tsr ? OFF_TF32 : OFF_SF32; }
  int b = q / P, pos = q % P;
  const float* f = ws + fbase + (size_t)b*256*P + pos;
  float s = 0.f;
  for (int ch=0; ch<256; ch++){ float v = f[(size_t)ch*P]; s = fmaf(v,v,s); }
  ws[(tsr ? OFF_INVT : OFF_INVS) + r] = 1.f/sqrtf(s);
}

// ---------------------------------------------------------------------------
// 5) all 9 normalized-correlation GEMMs (f32), 64x64 tiles, K=256
__global__ __launch_bounds__(256) void k_corr(float* __restrict__ ws){
  int bx = blockIdx.x;
  int p = (bx>=4)+(bx>=20)+(bx>=84)+(bx>=100)+(bx>=164)+(bx>=420)+(bx>=484)+(bx>=740);
  int si = p/3, ti = p%3;
  int M = SSARR[si]*SSARR[si], N = SSARR[ti]*SSARR[ti];
  int ntN = N >> 6;
  int rem = bx - PAIR_START[p];
  int b = rem & 3; rem >>= 2;
  int nt = rem % ntN, mt = rem / ntN;
  int m0 = mt*64, n0 = nt*64;
  const float* A  = ws + (si==0?OFF_SF8: si==1?OFF_SF16:OFF_SF32) + (size_t)b*256*M;
  const float* Bp = ws + (ti==0?OFF_TF8: ti==1?OFF_TF16:OFF_TF32) + (size_t)b*256*N;
  const float* iS = ws + OFF_INVS + (si==0?0: si==1?256:1280) + (size_t)b*M;
  const float* iT = ws + OFF_INVT + (ti==0?0: ti==1?256:1280) + (size_t)b*N;
  float* C = ws + PAIR_OFF[p] + (size_t)b*M*N;
  __shared__ __align__(16) float As[16][64];
  __shared__ __align__(16) float Bs[16][64];
  int t = threadIdx.x, tm = t>>4, tn = t&15;
  float acc[4][4] = {};
  #pragma unroll 1
  for (int k0=0; k0<256; k0+=16){
    __syncthreads();
    #pragma unroll
    for (int i=0;i<4;i++){
      int idx = t + i*256; int k = idx>>6, m = idx&63;
      As[k][m] = A [(size_t)(k0+k)*M + m0+m];
      Bs[k][m] = Bp[(size_t)(k0+k)*N + n0+m];
    }
    __syncthreads();
    #pragma unroll
    for (int k=0;k<16;k++){
      float4 av = *reinterpret_cast<const float4*>(&As[k][tm*4]);
      float4 bv = *reinterpret_cast<const float4*>(&Bs[k][tn*4]);
      float a4[4]={av.x,av.y,av.z,av.w}, b4[4]={bv.x,bv.y,bv.z,bv.w};
      #pragma unroll
      for (int i=0;i<4;i++)
        #pragma unroll
        for (int j=0;j<4;j++)
          acc[i][j] = fmaf(a4[i], b4[j], acc[i][j]);
    }
  }
  #pragma unroll
  for (int i=0;i<4;i++){
    float sv = iS[m0+tm*4+i];
    #pragma unroll
    for (int j=0;j<4;j++)
      C[(size_t)(m0+tm*4+i)*N + n0+tn*4+j] = acc[i][j]*sv*iT[n0+tn*4+j];
  }
}

// ---------------------------------------------------------------------------
DEVFN void cw_coord(int i, int n, int OH, int& i0, int& i1, float& f){
  float c = (float)(i*(n-1))/(float)(OH-1);
  int a = (int)c; if (a > n-1) a = n-1;
  i0 = a; i1 = (a+1 < n) ? a+1 : n-1; f = c - (float)a;
}

// 6) interp_pairs v2: block = (p,b,oy,ox); stage 4 corner (y,x) planes in LDS
__global__ __launch_bounds__(256) void k_interp_pairs(float* __restrict__ ws){
  int bx = blockIdx.x;
  int p = bx >> 10;
  int bl = bx & 1023;                    // [b:2][oy:4][ox:4]
  int b = bl >> 8, oy = (bl >> 4) & 15, ox = bl & 15;
  int si = p/3, ti = p%3;
  int h1 = SSARR[si], t1 = SSARR[ti], t12 = t1*t1;
  int y0,y1,x0,x1; float fy,fx;
  cw_coord(oy,h1,16,y0,y1,fy); cw_coord(ox,h1,16,x0,x1,fx);
  const float* in = ws + PAIR_OFF[p] + (size_t)b*h1*h1*t12;
  __shared__ float sPl[4][1024];
  const int t = threadIdx.x;
  {
    const float* pl0 = in + (size_t)(y0*h1+x0)*t12;
    const float* pl1 = in + (size_t)(y0*h1+x1)*t12;
    const float* pl2 = in + (size_t)(y1*h1+x0)*t12;
    const float* pl3 = in + (size_t)(y1*h1+x1)*t12;
    for (int i=t; i<t12; i+=256){
      sPl[0][i] = pl0[i]; sPl[1][i] = pl1[i];
      sPl[2][i] = pl2[i]; sPl[3][i] = pl3[i];
    }
  }
  __syncthreads();
  int px = t & 15, py = t >> 4;
  int u0,u1,v0,v1; float fu,fv;
  cw_coord(py,t1,16,u0,u1,fu); cw_coord(px,t1,16,v0,v1,fv);
  float wY[2]={1.f-fy,fy}, wX[2]={1.f-fx,fx};
  float wU[2]={1.f-fu,fu}, wV[2]={1.f-fv,fv};
  int us[2]={u0,u1}, vs[2]={v0,v1};
  float s = 0.f;
  #pragma unroll
  for (int qa=0; qa<2; qa++)
    #pragma unroll
    for (int qc=0; qc<2; qc++){
      float wyx = wY[qa]*wX[qc];
      const float* base = sPl[qa*2+qc];
      #pragma unroll
      for (int qu=0; qu<2; qu++)
        #pragma unroll
        for (int qv=0; qv<2; qv++)
          s += wyx*wU[qu]*wV[qv]*base[us[qu]*t1 + vs[qv]];
    }
  ws[OFF_CORR6 + ((size_t)b*9 + p)*65536 + ((size_t)(oy*16+ox)<<8) + t] = fmaxf(s, 0.f);
}

// ---------------------------------------------------------------------------
// 7) chm6d v3 (R4): wave-per-batch, stride-26 LDS, (a,c)-parity split
__global__ __launch_bounds__(256) void k_chm6d(float* __restrict__ ws,
                                               const float* __restrict__ k6rp){
  const int bx = blockIdx.x;
  const int g = bx >> 8, sy = (bx>>4)&15, sx = bx&15;
  const int t = threadIdx.x;
  const int bq = t>>6, l = t&63, ty = l>>2, tx = l&3;
  __shared__ float sP[4][9][20][26];
  float* myP = &sP[bq][0][0][0];
  for (int i = l; i < 9*20*26; i += 64){
    int r = i % 520, rr = r/26, cc = r%26;
    if (rr<2 || rr>17 || cc<4 || cc>19) myP[i] = 0.f;
  }
  f32x4 acc[9];
  #pragma unroll
  for (int i=0;i<9;i++) acc[i] = (f32x4){0.f,0.f,0.f,0.f};
  const float* c6 = ws + OFF_CORR6 + (size_t)bq*9*65536 + l*4;
  #pragma unroll 1
  for (int a=0; a<5; a++){
    int Y = sy+a-2; if (Y<0 || Y>15) continue;
    #pragma unroll 1
    for (int c=0; c<5; c++){
      if (((a*5+c)&1) != g) continue;
      int X = sx+c-2; if (X<0 || X>15) continue;
      #pragma unroll
      for (int pr=0; pr<9; pr++){
        float4 v = *reinterpret_cast<const float4*>(c6 + (size_t)pr*65536 + (size_t)(Y*16+X)*256);
        float* wp = myP + (pr*20 + 2 + (l>>2))*26 + 4 + 4*(l&3);
        *reinterpret_cast<float2*>(wp)   = make_float2(v.x, v.y);
        *reinterpret_cast<float2*>(wp+2) = make_float2(v.z, v.w);
      }
      const float* wt = k6rp + (size_t)(a*5+c)*5*48;
      #pragma unroll 1
      for (int d=0; d<5; d++){
        float4 wv[12];
        const float4* wt4 = reinterpret_cast<const float4*>(wt + d*48);
        #pragma unroll
        for (int i=0;i<12;i++) wv[i] = wt4[i];
        #pragma unroll
        for (int pr=0; pr<9; pr++){
          const int pi = pr/3, pj = pr%3;
          const float* rp = myP + (pr*20 + ty + d)*26 + 4*tx + 2;
          float r8[8];
          #pragma unroll
          for (int i=0;i<4;i++){
            float2 u = *reinterpret_cast<const float2*>(rp + 2*i);
            r8[2*i] = u.x; r8[2*i+1] = u.y;
          }
          #pragma unroll
          for (int e=0;e<5;e++){
            #pragma unroll
            for (int ki=0; ki<3; ki++){
              const int sio = pi-ki+1; if (sio<0 || sio>2) continue;
              #pragma unroll
              for (int kj=0; kj<3; kj++){
                const int sjo = pj-kj+1; if (sjo<0 || sjo>2) continue;
                const int wi = e*9 + ki*3 + kj;
                const float w = ((const float*)&wv[wi>>2])[wi&3];
                #pragma unroll
                for (int xi=0; xi<4; xi++)
                  acc[sio*3+sjo][xi] = fmaf(r8[e+xi], w, acc[sio*3+sjo][xi]);
              }
            }
          }
        }
      }
    }
  }
  float* po = ws + OFF_PART + ((size_t)(g*4+bq)*9)*65536
            + (size_t)(sy*16+sx)*256 + ty*16 + tx*4;
  #pragma unroll
  for (int so=0; so<9; so++)
    *reinterpret_cast<f32x4*>(po + (size_t)so*65536) = acc[so];
}

// 7b) combine partials + sigmoid + max over 9 so
__global__ void k_sigmax(float* __restrict__ ws){
  int id = blockIdx.x*256 + threadIdx.x;        // 4*65536
  int b = id >> 16, pos = id & 65535;
  const float* p0 = ws + OFF_PART + (size_t)b*9*65536 + pos;
  const float* p1 = p0 + (size_t)4*9*65536;
  float m = -1e30f;
  #pragma unroll
  for (int so=0; so<9; so++)
    m = fmaxf(m, p0[(size_t)so*65536] + p1[(size_t)so*65536]);
  ws[OFF_MAXED + (size_t)b*65536 + pos] = 1.f/(1.f + expf(-m));
}

// ---------------------------------------------------------------------------
// 8) interpolate4d 16^4 -> 32^4
__global__ void k_interp32(float* __restrict__ ws){
  int id = blockIdx.x*256 + threadIdx.x;
  int px = id & 31, py = (id>>5)&31, ox = (id>>10)&31, oy = (id>>15)&31, b = id>>20;
  int y0,y1,x0,x1,u0,u1,v0,v1; float fy,fx,fu,fv;
  cw_coord(oy,16,32,y0,y1,fy); cw_coord(ox,16,32,x0,x1,fx);
  cw_coord(py,16,32,u0,u1,fu); cw_coord(px,16,32,v0,v1,fv);
  const float* in = ws + OFF_MAXED + (size_t)b*65536;
  int ys[2]={y0,y1}, xs[2]={x0,x1}, us[2]={u0,u1}, vs[2]={v0,v1};
  float wy[2]={1.f-fy,fy}, wx[2]={1.f-fx,fx}, wu[2]={1.f-fu,fu}, wv[2]={1.f-fv,fv};
  float s = 0.f;
  #pragma unroll
  for (int ia=0; ia<2; ia++)
    #pragma unroll
    for (int ic=0; ic<2; ic++){
      float wyx = wy[ia]*wx[ic];
      const float* base = in + ((size_t)ys[ia]*16 + xs[ic])*256;
      #pragma unroll
      for (int id_=0; id_<2; id_++)
        #pragma unroll
        for (int ie=0; ie<2; ie++)
          s += wyx*wu[id_]*wv[ie]*base[(size_t)us[id_]*16 + vs[ie]];
    }
  ws[OFF_INT32 + id] = s;
}

// ---------------------------------------------------------------------------
// 9) fast4d v3: block computes 4 consecutive sx output planes. Staged planes
//    shared across outputs (d-row reads amortized 2.5x); double-buffered LDS,
//    reg-prefetch of next plane, 1 barrier/plane; weights via uniform global
//    (scalar) loads. + bias + softplus -> d_out [4][1024][1024]
__global__ __launch_bounds__(256) void k_fast4d(float* __restrict__ ws,
                                                const float* __restrict__ k4,
                                                const float* __restrict__ b4,
                                                float* __restrict__ out){
  const int b = blockIdx.y;
  const int sy = blockIdx.x >> 3, sx0 = (blockIdx.x & 7) << 2;
  const int t = threadIdx.x;
  const int y = t >> 3, x0 = (t & 7) << 2;
  __shared__ __align__(16) float sQ[2][36*48];
  for (int i=t; i<1728; i+=256){ sQ[0][i]=0.f; sQ[1][i]=0.f; }
  __syncthreads();                                   // guards visible
  const float* in = ws + OFF_INT32 + (size_t)b*1048576;
  float acc[4][4] = {};

  // plane index idx in [0,40): a = idx>>3 (row tap), Xi = idx&7 (X = sx0-2+Xi)
  int i0 = 0;
  for (; i0 < 40; ++i0){
    int Y = sy + (i0>>3) - 2, X = sx0 - 2 + (i0&7);
    if (Y>=0 && Y<=31 && X>=0 && X<=31) break;
  }
  float4 pf = make_float4(0.f,0.f,0.f,0.f);
  if (i0 < 40){
    int Y = sy + (i0>>3) - 2, X = sx0 - 2 + (i0&7);
    pf = *reinterpret_cast<const float4*>(in + (size_t)(Y*32+X)*1024 + t*4);
  }
  int cur = 0, i = i0;
  const int srow = t >> 3, scol4 = (t & 7) << 2;
  #pragma unroll 1
  while (i < 40){
    int nx = i+1;
    for (; nx < 40; ++nx){
      int Y = sy + (nx>>3) - 2, X = sx0 - 2 + (nx&7);
      if (Y>=0 && Y<=31 && X>=0 && X<=31) break;
    }
    // publish current plane
    float* wp = &sQ[cur][(2+srow)*48 + 2 + scol4];
    wp[0]=pf.x; wp[1]=pf.y; wp[2]=pf.z; wp[3]=pf.w;
    if (nx < 40){                                     // prefetch next (hides under compute)
      int Y = sy + (nx>>3) - 2, X = sx0 - 2 + (nx&7);
      pf = *reinterpret_cast<const float4*>(in + (size_t)(Y*32+X)*1024 + t*4);
    }
    __syncthreads();
    const int a = i>>3, Xi = i&7;
    const float* ka = k4 + a*125;                     // uniform -> scalar loads
    #pragma unroll
    for (int d=0; d<5; d++){
      const float* row = &sQ[cur][(y+d)*48 + x0];
      float4 q0 = *reinterpret_cast<const float4*>(row);
      float4 q1 = *reinterpret_cast<const float4*>(row+4);
      float r8[8] = {q0.x,q0.y,q0.z,q0.w,q1.x,q1.y,q1.z,q1.w};
      #pragma unroll
      for (int j=0; j<4; j++){
        const int c = Xi - j;
        if (c >= 0 && c <= 4){                        // wave-uniform predicate
          const float* kc = ka + c*25 + d*5;
          #pragma unroll
          for (int e=0; e<5; e++){
            float wv = kc[e];
            #pragma unroll
            for (int xi=0; xi<4; xi++)
              acc[j][xi] = fmaf(r8[xi+e], wv, acc[j][xi]);
          }
        }
      }
    }
    cur ^= 1; i = nx;                                 // 1 barrier/plane (dbuf)
  }
  float bias = b4[0];
  #pragma unroll
  for (int j=0; j<4; j++){
    float4 o;
    float* po = &o.x;
    #pragma unroll
    for (int xi=0; xi<4; xi++){
      float xv = acc[j][xi] + bias;
      po[xi] = fmaxf(xv,0.f) + log1pf(expf(-fabsf(xv)));
    }
    *reinterpret_cast<float4*>(
      out + ((size_t)b*1024 + sy*32 + sx0 + j)*1024 + y*32 + x0) = o;
  }
}

// ---------------------------------------------------------------------------
// 10-12) mutual_nn_filter
__global__ void k_rowmax(const float* __restrict__ cm, float* __restrict__ ws){
  int row = blockIdx.x;
  const float* r = cm + (size_t)row*1024;
  int t = threadIdx.x;
  float m = -1e30f;
  for (int i=t; i<1024; i+=256) m = fmaxf(m, r[i]);
  __shared__ float red[256];
  red[t] = m; __syncthreads();
  for (int off=128; off; off>>=1){
    if (t < off) red[t] = fmaxf(red[t], red[t+off]);
    __syncthreads();
  }
  if (!t) ws[OFF_SMAX + row] = red[0];
}

__global__ void k_colmax_p(const float* __restrict__ cm, float* __restrict__ ws){
  int b = blockIdx.x >> 5, rg = (blockIdx.x >> 2) & 7, cg = blockIdx.x & 3;
  int c = cg*256 + threadIdx.x;
  const float* base = cm + (size_t)b*1048576 + (size_t)rg*131072 + c;
  float m = -1e30f;
  #pragma unroll 4
  for (int r=0; r<128; r++) m = fmaxf(m, base[(size_t)r*1024]);
  ws[OFF_CMAXP + (size_t)(b*8+rg)*1024 + c] = m;
}

__global__ void k_colmax_r(float* __restrict__ ws){
  int id = blockIdx.x*256 + threadIdx.x;         // 4096
  int b = id >> 10, c = id & 1023;
  float m = -1e30f;
  #pragma unroll
  for (int rg=0; rg<8; rg++)
    m = fmaxf(m, ws[OFF_CMAXP + (size_t)(b*8+rg)*1024 + c]);
  ws[OFF_TMAX + id] = m;
}

__global__ void k_mutual(float* __restrict__ cm, const float* __restrict__ ws){
  int id = blockIdx.x*256 + threadIdx.x;
  int b = id >> 20, r = (id>>10)&1023, c = id&1023;
  float v  = cm[id];
  float sm = ws[OFF_SMAX + (b<<10) + r];
  float tm = ws[OFF_TMAX + (b<<10) + c];
  sm = (sm==0.f) ? 1e-30f : sm;
  tm = (tm==0.f) ? 1e-30f : tm;
  cm[id] = v * (v/sm) * (v/tm);
}

// ---------------------------------------------------------------------------
extern "C" void kernel_launch(void* const* d_in, const int* in_sizes, int n_in,
                              void* d_out, int out_size, void* d_ws, size_t ws_size,
                              hipStream_t stream){
  const float* src = (const float*)d_in[0];
  const float* trg = (const float*)d_in[1];
  const float* w0  = (const float*)d_in[2];
  const float* w1  = (const float*)d_in[3];
  const float* w2  = (const float*)d_in[4];
  const float* k6  = (const float*)d_in[5];
  const float* k4  = (const float*)d_in[6];
  const float* b4  = (const float*)d_in[7];
  float* ws  = (float*)d_ws;    // needs WS_FLOATS*4 = ~60.7 MB
  float* out = (float*)d_out;
  (void)in_sizes; (void)n_in; (void)out_size; (void)ws_size;

  k_wpack       <<<3456,  256, 0, stream>>>(w0, w1, w2, ws);
  k_k6rp        <<<24,    256, 0, stream>>>(k6, ws);
  k_inpack      <<<512,   256, 0, stream>>>(src, trg, ws);
  k_conv_mfma   <<<336,   256, 0, stream>>>(ws);
  k_invnorm     <<<42,    256, 0, stream>>>(ws);
  k_corr        <<<1764,  256, 0, stream>>>(ws);
  k_interp_pairs<<<9216,  256, 0, stream>>>(ws);
  k_chm6d       <<<512,   256, 0, stream>>>(ws, ws + OFF_K6R);
  k_sigmax      <<<1024,  256, 0, stream>>>(ws);
  k_interp32    <<<16384, 256, 0, stream>>>(ws);
  k_fast4d      <<<dim3(256,4),  256, 0, stream>>>(ws, k4, b4, out);
  k_rowmax      <<<4096,  256, 0, stream>>>(out, ws);
  k_colmax_p    <<<128,   256, 0, stream>>>(out, ws);
  k_colmax_r    <<<16,    256, 0, stream>>>(ws);
  k_mutual      <<<16384, 256, 0, stream>>>(out, ws);
}